// Round 2
// baseline (1883.035 us; speedup 1.0000x reference)
//
#include <hip/hip_runtime.h>

#define NN 50000
#define NE 400000
#define HD 128
#define ND 64
#define GG 16
#define EPSV 1e-5f

#define SLEN (2 * GG * HD + GG)   // 4112 floats: [sum 2048 | sumsq 2048 | cnt 16]
#define PSTRIDE 4352              // partial-set stride (floats), non-pow2
#define EP 512                    // estats stage-1 blocks
#define HP 256                    // hstats stage-1 blocks

typedef unsigned short u16;
typedef unsigned int   u32;
typedef unsigned char  u8;

__device__ __forceinline__ float us2f(u16 u) { return __uint_as_float(((u32)u) << 16); }
__device__ __forceinline__ u16 f2us(float f) {
    u32 u = __float_as_uint(f);
    u += 0x7fffu + ((u >> 16) & 1u);   // RNE
    return (u16)(u >> 16);
}
__device__ __forceinline__ float sigmoidf_(float x) { return 1.f / (1.f + __expf(-x)); }

// ---------------------------------------------------------------------------
// K1: fq/fr/fu/fv = features @ {Wq,Wr,Wu,Wv} + b   (bf16 out)
// ---------------------------------------------------------------------------
__global__ __launch_bounds__(256) void proj4_kernel(
    const float* __restrict__ feat,
    const float* __restrict__ Wq, const float* __restrict__ bq,
    const float* __restrict__ Wr, const float* __restrict__ br,
    const float* __restrict__ Wu, const float* __restrict__ bu,
    const float* __restrict__ Wv, const float* __restrict__ bv,
    u16* __restrict__ fq, u16* __restrict__ fr,
    u16* __restrict__ fu, u16* __restrict__ fv)
{
    __shared__ float xs[32][HD];
    const int t = threadIdx.x;
    const int gbase = blockIdx.x * 32;
    #pragma unroll
    for (int i = 0; i < 8; ++i) {
        int idx2 = t + i * 256;          // float2 index, 0..2047
        int row = idx2 >> 6;
        int c2 = (idx2 & 63) * 2;
        float2 v = make_float2(0.f, 0.f);
        int grow = gbase + row;
        if (grow < NN) v = *reinterpret_cast<const float2*>(&feat[(size_t)grow * HD + c2]);
        xs[row][c2] = v.x; xs[row][c2 + 1] = v.y;
    }
    __syncthreads();
    const int w = t >> 6, lane = t & 63;
    const int c0 = lane * 2, r0 = w * 8;
    const float* Ws[4] = {Wq, Wr, Wu, Wv};
    const float* Bs[4] = {bq, br, bu, bv};
    u16* Os[4] = {fq, fr, fu, fv};
    #pragma unroll
    for (int m = 0; m < 4; ++m) {
        const float* W = Ws[m];
        float acc[8][2];
        #pragma unroll
        for (int r = 0; r < 8; ++r) { acc[r][0] = 0.f; acc[r][1] = 0.f; }
        for (int k = 0; k < HD; k += 2) {
            float2 w0 = *reinterpret_cast<const float2*>(&W[k * HD + c0]);
            float2 w1 = *reinterpret_cast<const float2*>(&W[(k + 1) * HD + c0]);
            #pragma unroll
            for (int r = 0; r < 8; ++r) {
                float2 xv = *reinterpret_cast<const float2*>(&xs[r0 + r][k]);
                acc[r][0] = fmaf(xv.x, w0.x, fmaf(xv.y, w1.x, acc[r][0]));
                acc[r][1] = fmaf(xv.x, w0.y, fmaf(xv.y, w1.y, acc[r][1]));
            }
        }
        float2 b2 = *reinterpret_cast<const float2*>(&Bs[m][c0]);
        #pragma unroll
        for (int r = 0; r < 8; ++r) {
            int grow = gbase + r0 + r;
            if (grow < NN) {
                u32 o = (u32)f2us(acc[r][0] + b2.x) | ((u32)f2us(acc[r][1] + b2.y) << 16);
                *reinterpret_cast<u32*>(&Os[m][(size_t)grow * HD + c0]) = o;
            }
        }
    }
}

// ---------------------------------------------------------------------------
// K2: nme = noise @ We + be   (f32, written directly into e-output region)
// ---------------------------------------------------------------------------
__global__ __launch_bounds__(256) void nme_kernel(
    const float* __restrict__ noise, const float* __restrict__ We,
    const float* __restrict__ be, float* __restrict__ nme_out)
{
    __shared__ float xs[32][ND];
    const int t = threadIdx.x;
    const int gbase = blockIdx.x * 32;
    #pragma unroll
    for (int i = 0; i < 4; ++i) {
        int idx2 = t + i * 256;          // 0..1023
        int row = idx2 >> 5;
        int c2 = (idx2 & 31) * 2;
        float2 v = *reinterpret_cast<const float2*>(&noise[(size_t)(gbase + row) * ND + c2]);
        xs[row][c2] = v.x; xs[row][c2 + 1] = v.y;
    }
    __syncthreads();
    const int w = t >> 6, lane = t & 63;
    const int c0 = lane * 2, r0 = w * 8;
    float acc[8][2];
    #pragma unroll
    for (int r = 0; r < 8; ++r) { acc[r][0] = 0.f; acc[r][1] = 0.f; }
    for (int k = 0; k < ND; k += 2) {
        float2 w0 = *reinterpret_cast<const float2*>(&We[k * HD + c0]);
        float2 w1 = *reinterpret_cast<const float2*>(&We[(k + 1) * HD + c0]);
        #pragma unroll
        for (int r = 0; r < 8; ++r) {
            float2 xv = *reinterpret_cast<const float2*>(&xs[r0 + r][k]);
            acc[r][0] = fmaf(xv.x, w0.x, fmaf(xv.y, w1.x, acc[r][0]));
            acc[r][1] = fmaf(xv.x, w0.y, fmaf(xv.y, w1.y, acc[r][1]));
        }
    }
    float2 b2 = *reinterpret_cast<const float2*>(&be[c0]);
    #pragma unroll
    for (int r = 0; r < 8; ++r) {
        int e = gbase + r0 + r;
        *reinterpret_cast<float2*>(&nme_out[(size_t)e * HD + c0]) =
            make_float2(acc[r][0] + b2.x, acc[r][1] + b2.y);
    }
}

// ---------------------------------------------------------------------------
// K3: e_hat = nme@Wp + bp + fq[src] + fr[dst]; gates=sigmoid; aggr atomics;
//     also writes g8[e] = batch[src[e]]
// ---------------------------------------------------------------------------
__global__ __launch_bounds__(256) void ehat_kernel(
    const float* __restrict__ nme, const float* __restrict__ Wp, const float* __restrict__ bp,
    const u16* __restrict__ fq, const u16* __restrict__ fr, const u16* __restrict__ fv,
    const int* __restrict__ srcArr, const int* __restrict__ dstArr,
    const int* __restrict__ batch,
    u16* __restrict__ ehat, float* aggr, u8* __restrict__ g8)
{
    __shared__ float xs[32][HD];
    const int t = threadIdx.x;
    const int gbase = blockIdx.x * 32;
    #pragma unroll
    for (int i = 0; i < 8; ++i) {
        int idx2 = t + i * 256;
        int row = idx2 >> 6;
        int c2 = (idx2 & 63) * 2;
        float2 v = *reinterpret_cast<const float2*>(&nme[(size_t)(gbase + row) * HD + c2]);
        xs[row][c2] = v.x; xs[row][c2 + 1] = v.y;
    }
    __syncthreads();
    const int w = t >> 6, lane = t & 63;
    const int c0 = lane * 2, r0 = w * 8;
    float acc[8][2];
    #pragma unroll
    for (int r = 0; r < 8; ++r) { acc[r][0] = 0.f; acc[r][1] = 0.f; }
    for (int k = 0; k < HD; k += 2) {
        float2 w0 = *reinterpret_cast<const float2*>(&Wp[k * HD + c0]);
        float2 w1 = *reinterpret_cast<const float2*>(&Wp[(k + 1) * HD + c0]);
        #pragma unroll
        for (int r = 0; r < 8; ++r) {
            float2 xv = *reinterpret_cast<const float2*>(&xs[r0 + r][k]);
            acc[r][0] = fmaf(xv.x, w0.x, fmaf(xv.y, w1.x, acc[r][0]));
            acc[r][1] = fmaf(xv.x, w0.y, fmaf(xv.y, w1.y, acc[r][1]));
        }
    }
    float2 bp2 = *reinterpret_cast<const float2*>(&bp[c0]);
    #pragma unroll
    for (int r = 0; r < 8; ++r) {
        int e = gbase + r0 + r;
        int s = srcArr[e], d = dstArr[e];
        if (c0 == 0) g8[e] = (u8)batch[s];
        u32 qv = *reinterpret_cast<const u32*>(&fq[(size_t)s * HD + c0]);
        u32 rv = *reinterpret_cast<const u32*>(&fr[(size_t)d * HD + c0]);
        float e0 = acc[r][0] + bp2.x + us2f((u16)qv) + us2f((u16)rv);
        float e1 = acc[r][1] + bp2.y + us2f((u16)(qv >> 16)) + us2f((u16)(rv >> 16));
        *reinterpret_cast<u32*>(&ehat[(size_t)e * HD + c0]) =
            (u32)f2us(e0) | ((u32)f2us(e1) << 16);
        u32 vv = *reinterpret_cast<const u32*>(&fv[(size_t)d * HD + c0]);
        unsafeAtomicAdd(&aggr[(size_t)s * HD + c0],     sigmoidf_(e0) * us2f((u16)vv));
        unsafeAtomicAdd(&aggr[(size_t)s * HD + c0 + 1], sigmoidf_(e1) * us2f((u16)(vv >> 16)));
    }
}

// ---------------------------------------------------------------------------
// K4: per-graph sum/sumsq of x = fu + aggr (batch sorted -> register accum),
//     flush to per-block partial slice (NO global atomics)
// ---------------------------------------------------------------------------
__global__ __launch_bounds__(256) void hstats_part_kernel(
    const u16* __restrict__ fu, const float* __restrict__ aggr,
    const int* __restrict__ batch, float* __restrict__ hpart)
{
    __shared__ float sm[SLEN];        // [sum 2048 | sumsq 2048 | cnt 16]
    const int t = threadIdx.x;
    for (int i = t; i < SLEN; i += 256) sm[i] = 0.f;
    __syncthreads();
    const int nb = gridDim.x;
    const int chunk = (NN + nb - 1) / nb;
    const int rstart = blockIdx.x * chunk;
    const int rend = min(NN, rstart + chunk);
    const int c = t & 127, half = t >> 7;
    float a1 = 0.f, a2 = 0.f, ac = 0.f; int curg = -1;
    for (int row = rstart + half; row < rend; row += 2) {
        int g = batch[row];
        if (g != curg) {
            if (curg >= 0) {
                unsafeAtomicAdd(&sm[curg * HD + c], a1);
                unsafeAtomicAdd(&sm[2048 + curg * HD + c], a2);
                if (c == 0) unsafeAtomicAdd(&sm[4096 + curg], ac);
            }
            curg = g; a1 = a2 = ac = 0.f;
        }
        float x = us2f(fu[(size_t)row * HD + c]) + aggr[(size_t)row * HD + c];
        a1 += x; a2 += x * x; ac += 1.f;
    }
    if (curg >= 0) {
        unsafeAtomicAdd(&sm[curg * HD + c], a1);
        unsafeAtomicAdd(&sm[2048 + curg * HD + c], a2);
        if (c == 0) unsafeAtomicAdd(&sm[4096 + curg], ac);
    }
    __syncthreads();
    float* dst = hpart + (size_t)blockIdx.x * PSTRIDE;
    for (int i = t; i < SLEN; i += 256) dst[i] = sm[i];
}

// ---------------------------------------------------------------------------
// K5: per-graph sum/sumsq of e_hat (eseg = g8, unsorted -> LDS atomics),
//     flush to per-block partial slice
// ---------------------------------------------------------------------------
__global__ __launch_bounds__(512) void estats_part_kernel(
    const u16* __restrict__ ehat, const u8* __restrict__ g8,
    float* __restrict__ epart)
{
    __shared__ float sm[SLEN];
    const int t = threadIdx.x;
    for (int i = t; i < SLEN; i += 512) sm[i] = 0.f;
    __syncthreads();
    const int c = t & 127, q = t >> 7;        // 4 rows per iteration
    for (int row = blockIdx.x * 4 + q; row < NE; row += EP * 4) {
        int g = g8[row];
        float x = us2f(ehat[(size_t)row * HD + c]);
        unsafeAtomicAdd(&sm[g * HD + c], x);
        unsafeAtomicAdd(&sm[2048 + g * HD + c], x * x);
        if (c == 0) unsafeAtomicAdd(&sm[4096 + g], 1.f);
    }
    __syncthreads();
    float* dst = epart + (size_t)blockIdx.x * PSTRIDE;
    for (int i = t; i < SLEN; i += 512) dst[i] = sm[i];
}

// ---------------------------------------------------------------------------
// K5b: reduce P partial slices -> stats [sum 2048 | sumsq 2048 | cnt 16]
// ---------------------------------------------------------------------------
__global__ __launch_bounds__(256) void reduce_part_kernel(
    const float* __restrict__ part, int P, float* __restrict__ out)
{
    int j = blockIdx.x * 256 + threadIdx.x;
    if (j >= SLEN) return;
    float a = 0.f;
    for (int p = 0; p < P; ++p) a += part[(size_t)p * PSTRIDE + j];
    out[j] = a;
}

// ---------------------------------------------------------------------------
// K6: stats -> (off = mean*ms, istd);  var = E[x^2] - 2*off*mean + off^2
// ---------------------------------------------------------------------------
__global__ __launch_bounds__(256) void finstats_kernel(
    const float* __restrict__ statsH, const float* __restrict__ statsE,
    const float* __restrict__ gnh_ms, const float* __restrict__ gne_ms,
    float* off_h, float* istd_h, float* off_e, float* istd_e)
{
    for (int i = threadIdx.x; i < GG * HD; i += 256) {
        int g = i >> 7, c = i & 127;
        {
            float cnt = fmaxf(statsH[4096 + g], 1.f);
            float mean = statsH[i] / cnt;
            float ex2 = statsH[2048 + i] / cnt;
            float off = mean * gnh_ms[c];
            float var = ex2 - 2.f * off * mean + off * off;
            off_h[i] = off;
            istd_h[i] = rsqrtf(var + EPSV);
        }
        {
            float cnt = fmaxf(statsE[4096 + g], 1.f);
            float mean = statsE[i] / cnt;
            float ex2 = statsE[2048 + i] / cnt;
            float off = mean * gne_ms[c];
            float var = ex2 - 2.f * off * mean + off * off;
            off_e[i] = off;
            istd_e[i] = rsqrtf(var + EPSV);
        }
    }
}

// ---------------------------------------------------------------------------
// K7: tproj = relu(time_emb) @ Wt + bt   [16 x 128]
// ---------------------------------------------------------------------------
__global__ __launch_bounds__(256) void tproj_kernel(
    const float* __restrict__ time_emb, const float* __restrict__ Wt,
    const float* __restrict__ bt, float* __restrict__ tproj)
{
    __shared__ float te[GG][HD];
    const int t = threadIdx.x;
    for (int i = t; i < GG * HD; i += 256) te[i >> 7][i & 127] = fmaxf(time_emb[i], 0.f);
    __syncthreads();
    const int c = t & 127, rb = t >> 7;
    float acc[8];
    #pragma unroll
    for (int j = 0; j < 8; ++j) acc[j] = 0.f;
    for (int k = 0; k < HD; ++k) {
        float wv = Wt[k * HD + c];
        #pragma unroll
        for (int j = 0; j < 8; ++j) acc[j] = fmaf(te[rb + 2 * j][k], wv, acc[j]);
    }
    float b = bt[c];
    #pragma unroll
    for (int j = 0; j < 8; ++j) tproj[(rb + 2 * j) * HD + c] = acc[j] + b;
}

// ---------------------------------------------------------------------------
// K8: h = features + relu(graphnorm_h(fu + aggr));  aggr lives in hout (in-place)
// ---------------------------------------------------------------------------
__global__ __launch_bounds__(256) void hfinal_kernel(
    const float* __restrict__ feat, const u16* __restrict__ fu,
    const int* __restrict__ batch,
    const float* __restrict__ off_h, const float* __restrict__ istd_h,
    const float* __restrict__ gnh_w, const float* __restrict__ gnh_b,
    float* hout_aggr)
{
    int i = blockIdx.x * 256 + threadIdx.x;
    size_t base = (size_t)i * 4;
    if (base >= (size_t)NN * HD) return;
    int row = (int)(base >> 7), c0 = (int)(base & 127);
    int g = batch[row];
    float4 fe = *reinterpret_cast<const float4*>(&feat[base]);
    float4 ag = *reinterpret_cast<const float4*>(&hout_aggr[base]);
    uint2 fv2 = *reinterpret_cast<const uint2*>(&fu[base]);
    float xv[4] = { us2f((u16)fv2.x) + ag.x, us2f((u16)(fv2.x >> 16)) + ag.y,
                    us2f((u16)fv2.y) + ag.z, us2f((u16)(fv2.y >> 16)) + ag.w };
    float4 ou;
    float* op = &ou.x;
    const float* fp = &fe.x;
    #pragma unroll
    for (int j = 0; j < 4; ++j) {
        int idx = g * HD + c0 + j;
        float out = xv[j] - off_h[idx];
        float v = gnh_w[c0 + j] * out * istd_h[idx] + gnh_b[c0 + j];
        op[j] = fp[j] + fmaxf(v, 0.f);
    }
    *reinterpret_cast<float4*>(&hout_aggr[base]) = ou;
}

// ---------------------------------------------------------------------------
// K9: e = nme + silu(LN(relu(graphnorm_e(e_hat)) + tproj[g8])) @ Wo + bo
// ---------------------------------------------------------------------------
__global__ __launch_bounds__(256) void efinal_kernel(
    const u16* __restrict__ ehat, const u8* __restrict__ g8,
    const float* __restrict__ off_e, const float* __restrict__ istd_e,
    const float* __restrict__ gne_w, const float* __restrict__ gne_b,
    const float* __restrict__ tproj,
    const float* __restrict__ ln_w, const float* __restrict__ ln_b,
    const float* __restrict__ Wo, const float* __restrict__ bo,
    float* eout)
{
    __shared__ float ss[32][HD];
    const int t = threadIdx.x;
    const int gbase = blockIdx.x * 32;
    const int w = t >> 6, lane = t & 63;
    const int c0 = lane * 2, r0 = w * 8;
    float2 gw = *reinterpret_cast<const float2*>(&gne_w[c0]);
    float2 gb = *reinterpret_cast<const float2*>(&gne_b[c0]);
    float2 lw = *reinterpret_cast<const float2*>(&ln_w[c0]);
    float2 lb = *reinterpret_cast<const float2*>(&ln_b[c0]);
    for (int r = 0; r < 8; ++r) {
        int e = gbase + r0 + r;
        int g = g8[e];
        u32 ev = *reinterpret_cast<const u32*>(&ehat[(size_t)e * HD + c0]);
        float2 ofe = *reinterpret_cast<const float2*>(&off_e[g * HD + c0]);
        float2 ise = *reinterpret_cast<const float2*>(&istd_e[g * HD + c0]);
        float2 tp  = *reinterpret_cast<const float2*>(&tproj[g * HD + c0]);
        float v0 = gw.x * (us2f((u16)ev) - ofe.x) * ise.x + gb.x;
        float v1 = gw.y * (us2f((u16)(ev >> 16)) - ofe.y) * ise.y + gb.y;
        v0 = fmaxf(v0, 0.f) + tp.x;
        v1 = fmaxf(v1, 0.f) + tp.y;
        float sum = v0 + v1;
        #pragma unroll
        for (int off = 32; off > 0; off >>= 1) sum += __shfl_xor(sum, off, 64);
        float mu = sum * (1.f / 128.f);
        float d0 = v0 - mu, d1 = v1 - mu;
        float sq = d0 * d0 + d1 * d1;
        #pragma unroll
        for (int off = 32; off > 0; off >>= 1) sq += __shfl_xor(sq, off, 64);
        float rstd = rsqrtf(sq * (1.f / 128.f) + EPSV);
        float l0 = d0 * rstd * lw.x + lb.x;
        float l1 = d1 * rstd * lw.y + lb.y;
        *reinterpret_cast<float2*>(&ss[r0 + r][c0]) =
            make_float2(l0 * sigmoidf_(l0), l1 * sigmoidf_(l1));
    }
    __syncthreads();
    float acc[8][2];
    #pragma unroll
    for (int r = 0; r < 8; ++r) { acc[r][0] = 0.f; acc[r][1] = 0.f; }
    for (int k = 0; k < HD; k += 2) {
        float2 w0 = *reinterpret_cast<const float2*>(&Wo[k * HD + c0]);
        float2 w1 = *reinterpret_cast<const float2*>(&Wo[(k + 1) * HD + c0]);
        #pragma unroll
        for (int r = 0; r < 8; ++r) {
            float2 xv = *reinterpret_cast<const float2*>(&ss[r0 + r][k]);
            acc[r][0] = fmaf(xv.x, w0.x, fmaf(xv.y, w1.x, acc[r][0]));
            acc[r][1] = fmaf(xv.x, w0.y, fmaf(xv.y, w1.y, acc[r][1]));
        }
    }
    float2 bo2 = *reinterpret_cast<const float2*>(&bo[c0]);
    #pragma unroll
    for (int r = 0; r < 8; ++r) {
        int e = gbase + r0 + r;
        float2 nm = *reinterpret_cast<const float2*>(&eout[(size_t)e * HD + c0]);
        *reinterpret_cast<float2*>(&eout[(size_t)e * HD + c0]) =
            make_float2(acc[r][0] + bo2.x + nm.x, acc[r][1] + bo2.y + nm.y);
    }
}

// ---------------------------------------------------------------------------
extern "C" void kernel_launch(void* const* d_in, const int* in_sizes, int n_in,
                              void* d_out, int out_size, void* d_ws, size_t ws_size,
                              hipStream_t stream)
{
    const float* feat     = (const float*)d_in[0];
    const int*   eidx     = (const int*)d_in[1];
    const float* noise    = (const float*)d_in[2];
    const float* time_emb = (const float*)d_in[3];
    const int*   batch    = (const int*)d_in[4];
    const float* We = (const float*)d_in[5],  *be = (const float*)d_in[6];
    const float* Wp = (const float*)d_in[7],  *bp = (const float*)d_in[8];
    const float* Wq = (const float*)d_in[9],  *bq = (const float*)d_in[10];
    const float* Wr = (const float*)d_in[11], *br = (const float*)d_in[12];
    const float* Wu = (const float*)d_in[13], *bu = (const float*)d_in[14];
    const float* Wv = (const float*)d_in[15], *bv = (const float*)d_in[16];
    const float* gnh_w = (const float*)d_in[17], *gnh_b = (const float*)d_in[18], *gnh_ms = (const float*)d_in[19];
    const float* gne_w = (const float*)d_in[20], *gne_b = (const float*)d_in[21], *gne_ms = (const float*)d_in[22];
    const float* Wt = (const float*)d_in[23], *bt = (const float*)d_in[24];
    const float* ln_w = (const float*)d_in[25], *ln_b = (const float*)d_in[26];
    const float* Wo = (const float*)d_in[27], *bo = (const float*)d_in[28];

    const int* srcArr = eidx;
    const int* dstArr = eidx + NE;

    float* hout = (float*)d_out;                    // [N,H] f32 — doubles as aggr
    float* eout = hout + (size_t)NN * HD;           // [E,H] f32 — holds nme then e

    char* ws = (char*)d_ws;
    size_t off = 0;
    auto take = [&](size_t bytes) -> char* {
        char* p = ws + off;
        off = (off + bytes + 255) & ~(size_t)255;
        return p;
    };
    u16* ehat = (u16*)take((size_t)NE * HD * 2);    // 102.4 MB
    u16* fq = (u16*)take((size_t)NN * HD * 2);
    u16* fr = (u16*)take((size_t)NN * HD * 2);
    u16* fu = (u16*)take((size_t)NN * HD * 2);
    u16* fv = (u16*)take((size_t)NN * HD * 2);
    u8*  g8 = (u8*)take((size_t)NE);
    float* statsH = (float*)take((size_t)SLEN * 4);
    float* statsE = (float*)take((size_t)SLEN * 4);
    float* tproj  = (float*)take((size_t)GG * HD * 4);
    float* off_h  = (float*)take((size_t)GG * HD * 4);
    float* istd_h = (float*)take((size_t)GG * HD * 4);
    float* off_e  = (float*)take((size_t)GG * HD * 4);
    float* istd_e = (float*)take((size_t)GG * HD * 4);
    float* epart  = (float*)take((size_t)EP * PSTRIDE * 4);   // 8.9 MB
    float* hpart  = (float*)take((size_t)HP * PSTRIDE * 4);   // 4.5 MB

    // zero the atomic accumulator (hout doubles as aggr)
    hipMemsetAsync(hout, 0, (size_t)NN * HD * 4, stream);

    proj4_kernel<<<(NN + 31) / 32, 256, 0, stream>>>(feat, Wq, bq, Wr, br, Wu, bu, Wv, bv,
                                                     fq, fr, fu, fv);
    nme_kernel<<<NE / 32, 256, 0, stream>>>(noise, We, be, eout);
    ehat_kernel<<<NE / 32, 256, 0, stream>>>(eout, Wp, bp, fq, fr, fv, srcArr, dstArr, batch,
                                             ehat, hout, g8);
    hstats_part_kernel<<<HP, 256, 0, stream>>>(fu, hout, batch, hpart);
    reduce_part_kernel<<<(SLEN + 255) / 256, 256, 0, stream>>>(hpart, HP, statsH);
    estats_part_kernel<<<EP, 512, 0, stream>>>(ehat, g8, epart);
    reduce_part_kernel<<<(SLEN + 255) / 256, 256, 0, stream>>>(epart, EP, statsE);
    tproj_kernel<<<1, 256, 0, stream>>>(time_emb, Wt, bt, tproj);
    finstats_kernel<<<1, 256, 0, stream>>>(statsH, statsE, gnh_ms, gne_ms,
                                           off_h, istd_h, off_e, istd_e);
    hfinal_kernel<<<(NN * HD / 4 + 255) / 256, 256, 0, stream>>>(feat, fu, batch, off_h, istd_h,
                                                                 gnh_w, gnh_b, hout);
    efinal_kernel<<<NE / 32, 256, 0, stream>>>(ehat, g8, off_e, istd_e,
                                               gne_w, gne_b, tproj, ln_w, ln_b, Wo, bo, eout);
}

// Round 3
// 1303.222 us; speedup vs baseline: 1.4449x; 1.4449x over previous
//
#include <hip/hip_runtime.h>

#define NN 50000
#define NE 400000
#define HD 128
#define ND 64
#define GG 16
#define EPSV 1e-5f

#define SLEN (2 * GG * HD + GG)   // 4112 floats: [sum 2048 | sumsq 2048 | cnt 16]
#define PSTRIDE 4352              // partial-set stride (floats), non-pow2
#define EP 512                    // estats stage-1 blocks
#define HP 256                    // hstats stage-1 blocks

typedef unsigned short u16;
typedef unsigned int   u32;
typedef unsigned char  u8;

__device__ __forceinline__ float us2f(u16 u) { return __uint_as_float(((u32)u) << 16); }
__device__ __forceinline__ u16 f2us(float f) {
    u32 u = __float_as_uint(f);
    u += 0x7fffu + ((u >> 16) & 1u);   // RNE
    return (u16)(u >> 16);
}
__device__ __forceinline__ float sigmoidf_(float x) { return 1.f / (1.f + __expf(-x)); }

// accumulate x into register-resident per-graph slots via wave-uniform scalar switch
#define ACC_CASE(G) case G: s[G] += x; z[G] = fmaf(x, x, z[G]); cn[G] += cinc; break;
#define ACC_SWITCH(g) switch (g) { \
    ACC_CASE(0) ACC_CASE(1) ACC_CASE(2) ACC_CASE(3) ACC_CASE(4) ACC_CASE(5) \
    ACC_CASE(6) ACC_CASE(7) ACC_CASE(8) ACC_CASE(9) ACC_CASE(10) ACC_CASE(11) \
    ACC_CASE(12) ACC_CASE(13) ACC_CASE(14) ACC_CASE(15) default: break; }

// ---------------------------------------------------------------------------
// K1: fq/fr/fu/fv = features @ {Wq,Wr,Wu,Wv} + b   (bf16 out)
// ---------------------------------------------------------------------------
__global__ __launch_bounds__(256) void proj4_kernel(
    const float* __restrict__ feat,
    const float* __restrict__ Wq, const float* __restrict__ bq,
    const float* __restrict__ Wr, const float* __restrict__ br,
    const float* __restrict__ Wu, const float* __restrict__ bu,
    const float* __restrict__ Wv, const float* __restrict__ bv,
    u16* __restrict__ fq, u16* __restrict__ fr,
    u16* __restrict__ fu, u16* __restrict__ fv)
{
    __shared__ float xs[32][HD];
    const int t = threadIdx.x;
    const int gbase = blockIdx.x * 32;
    #pragma unroll
    for (int i = 0; i < 8; ++i) {
        int idx2 = t + i * 256;          // float2 index, 0..2047
        int row = idx2 >> 6;
        int c2 = (idx2 & 63) * 2;
        float2 v = make_float2(0.f, 0.f);
        int grow = gbase + row;
        if (grow < NN) v = *reinterpret_cast<const float2*>(&feat[(size_t)grow * HD + c2]);
        xs[row][c2] = v.x; xs[row][c2 + 1] = v.y;
    }
    __syncthreads();
    const int w = t >> 6, lane = t & 63;
    const int c0 = lane * 2, r0 = w * 8;
    const float* Ws[4] = {Wq, Wr, Wu, Wv};
    const float* Bs[4] = {bq, br, bu, bv};
    u16* Os[4] = {fq, fr, fu, fv};
    #pragma unroll
    for (int m = 0; m < 4; ++m) {
        const float* W = Ws[m];
        float acc[8][2];
        #pragma unroll
        for (int r = 0; r < 8; ++r) { acc[r][0] = 0.f; acc[r][1] = 0.f; }
        for (int k = 0; k < HD; k += 2) {
            float2 w0 = *reinterpret_cast<const float2*>(&W[k * HD + c0]);
            float2 w1 = *reinterpret_cast<const float2*>(&W[(k + 1) * HD + c0]);
            #pragma unroll
            for (int r = 0; r < 8; ++r) {
                float2 xv = *reinterpret_cast<const float2*>(&xs[r0 + r][k]);
                acc[r][0] = fmaf(xv.x, w0.x, fmaf(xv.y, w1.x, acc[r][0]));
                acc[r][1] = fmaf(xv.x, w0.y, fmaf(xv.y, w1.y, acc[r][1]));
            }
        }
        float2 b2 = *reinterpret_cast<const float2*>(&Bs[m][c0]);
        #pragma unroll
        for (int r = 0; r < 8; ++r) {
            int grow = gbase + r0 + r;
            if (grow < NN) {
                u32 o = (u32)f2us(acc[r][0] + b2.x) | ((u32)f2us(acc[r][1] + b2.y) << 16);
                *reinterpret_cast<u32*>(&Os[m][(size_t)grow * HD + c0]) = o;
            }
        }
    }
}

// ---------------------------------------------------------------------------
// K2: nme = noise @ We + be   (f32, written directly into e-output region)
// ---------------------------------------------------------------------------
__global__ __launch_bounds__(256) void nme_kernel(
    const float* __restrict__ noise, const float* __restrict__ We,
    const float* __restrict__ be, float* __restrict__ nme_out)
{
    __shared__ float xs[32][ND];
    const int t = threadIdx.x;
    const int gbase = blockIdx.x * 32;
    #pragma unroll
    for (int i = 0; i < 4; ++i) {
        int idx2 = t + i * 256;          // 0..1023
        int row = idx2 >> 5;
        int c2 = (idx2 & 31) * 2;
        float2 v = *reinterpret_cast<const float2*>(&noise[(size_t)(gbase + row) * ND + c2]);
        xs[row][c2] = v.x; xs[row][c2 + 1] = v.y;
    }
    __syncthreads();
    const int w = t >> 6, lane = t & 63;
    const int c0 = lane * 2, r0 = w * 8;
    float acc[8][2];
    #pragma unroll
    for (int r = 0; r < 8; ++r) { acc[r][0] = 0.f; acc[r][1] = 0.f; }
    for (int k = 0; k < ND; k += 2) {
        float2 w0 = *reinterpret_cast<const float2*>(&We[k * HD + c0]);
        float2 w1 = *reinterpret_cast<const float2*>(&We[(k + 1) * HD + c0]);
        #pragma unroll
        for (int r = 0; r < 8; ++r) {
            float2 xv = *reinterpret_cast<const float2*>(&xs[r0 + r][k]);
            acc[r][0] = fmaf(xv.x, w0.x, fmaf(xv.y, w1.x, acc[r][0]));
            acc[r][1] = fmaf(xv.x, w0.y, fmaf(xv.y, w1.y, acc[r][1]));
        }
    }
    float2 b2 = *reinterpret_cast<const float2*>(&be[c0]);
    #pragma unroll
    for (int r = 0; r < 8; ++r) {
        int e = gbase + r0 + r;
        *reinterpret_cast<float2*>(&nme_out[(size_t)e * HD + c0]) =
            make_float2(acc[r][0] + b2.x, acc[r][1] + b2.y);
    }
}

// ---------------------------------------------------------------------------
// K3: e_hat = nme@Wp + bp + fq[src] + fr[dst]; gates=sigmoid; aggr atomics;
//     also writes g8[e] = batch[src[e]]
// ---------------------------------------------------------------------------
__global__ __launch_bounds__(256) void ehat_kernel(
    const float* __restrict__ nme, const float* __restrict__ Wp, const float* __restrict__ bp,
    const u16* __restrict__ fq, const u16* __restrict__ fr, const u16* __restrict__ fv,
    const int* __restrict__ srcArr, const int* __restrict__ dstArr,
    const int* __restrict__ batch,
    u16* __restrict__ ehat, float* aggr, u8* __restrict__ g8)
{
    __shared__ float xs[32][HD];
    const int t = threadIdx.x;
    const int gbase = blockIdx.x * 32;
    #pragma unroll
    for (int i = 0; i < 8; ++i) {
        int idx2 = t + i * 256;
        int row = idx2 >> 6;
        int c2 = (idx2 & 63) * 2;
        float2 v = *reinterpret_cast<const float2*>(&nme[(size_t)(gbase + row) * HD + c2]);
        xs[row][c2] = v.x; xs[row][c2 + 1] = v.y;
    }
    __syncthreads();
    const int w = t >> 6, lane = t & 63;
    const int c0 = lane * 2, r0 = w * 8;
    float acc[8][2];
    #pragma unroll
    for (int r = 0; r < 8; ++r) { acc[r][0] = 0.f; acc[r][1] = 0.f; }
    for (int k = 0; k < HD; k += 2) {
        float2 w0 = *reinterpret_cast<const float2*>(&Wp[k * HD + c0]);
        float2 w1 = *reinterpret_cast<const float2*>(&Wp[(k + 1) * HD + c0]);
        #pragma unroll
        for (int r = 0; r < 8; ++r) {
            float2 xv = *reinterpret_cast<const float2*>(&xs[r0 + r][k]);
            acc[r][0] = fmaf(xv.x, w0.x, fmaf(xv.y, w1.x, acc[r][0]));
            acc[r][1] = fmaf(xv.x, w0.y, fmaf(xv.y, w1.y, acc[r][1]));
        }
    }
    float2 bp2 = *reinterpret_cast<const float2*>(&bp[c0]);
    #pragma unroll
    for (int r = 0; r < 8; ++r) {
        int e = gbase + r0 + r;
        int s = srcArr[e], d = dstArr[e];
        if (c0 == 0) g8[e] = (u8)batch[s];
        u32 qv = *reinterpret_cast<const u32*>(&fq[(size_t)s * HD + c0]);
        u32 rv = *reinterpret_cast<const u32*>(&fr[(size_t)d * HD + c0]);
        float e0 = acc[r][0] + bp2.x + us2f((u16)qv) + us2f((u16)rv);
        float e1 = acc[r][1] + bp2.y + us2f((u16)(qv >> 16)) + us2f((u16)(rv >> 16));
        *reinterpret_cast<u32*>(&ehat[(size_t)e * HD + c0]) =
            (u32)f2us(e0) | ((u32)f2us(e1) << 16);
        u32 vv = *reinterpret_cast<const u32*>(&fv[(size_t)d * HD + c0]);
        unsafeAtomicAdd(&aggr[(size_t)s * HD + c0],     sigmoidf_(e0) * us2f((u16)vv));
        unsafeAtomicAdd(&aggr[(size_t)s * HD + c0 + 1], sigmoidf_(e1) * us2f((u16)(vv >> 16)));
    }
}

// ---------------------------------------------------------------------------
// K4: per-graph sum/sumsq of x = fu + aggr.  Register accumulation (g is
//     wave-uniform), NO atomics anywhere. Flush via private LDS slots.
// ---------------------------------------------------------------------------
__global__ __launch_bounds__(256) void hstats_part_kernel(
    const u16* __restrict__ fu, const float* __restrict__ aggr,
    const int* __restrict__ batch, float* __restrict__ hpart)
{
    __shared__ float sm[2 * GG * HD];     // 16 KB, reused in 2 phases
    __shared__ float smc[2 * GG];
    const int t = threadIdx.x;
    const int c = t & 127, half = t >> 7;
    const int chunk = (NN + HP - 1) / HP;
    const int rstart = blockIdx.x * chunk;
    const int rend = min(NN, rstart + chunk);
    const float cinc = (c == 0) ? 1.f : 0.f;
    float s[GG], z[GG], cn[GG];
    #pragma unroll
    for (int g = 0; g < GG; ++g) { s[g] = 0.f; z[g] = 0.f; cn[g] = 0.f; }
    for (int row = rstart + half; row < rend; row += 2) {
        int g = __builtin_amdgcn_readfirstlane(batch[row]);
        float x = us2f(fu[(size_t)row * HD + c]) + aggr[(size_t)row * HD + c];
        ACC_SWITCH(g)
    }
    // phase A: sums + cnt
    #pragma unroll
    for (int g = 0; g < GG; ++g) sm[(half * GG + g) * HD + c] = s[g];
    if (c == 0) {
        #pragma unroll
        for (int g = 0; g < GG; ++g) smc[half * GG + g] = cn[g];
    }
    __syncthreads();
    float* dst = hpart + (size_t)blockIdx.x * PSTRIDE;
    for (int j = t; j < GG * HD; j += 256) dst[j] = sm[j] + sm[GG * HD + j];
    if (t < GG) dst[2 * GG * HD + t] = smc[t] + smc[GG + t];
    __syncthreads();
    // phase B: sumsq
    #pragma unroll
    for (int g = 0; g < GG; ++g) sm[(half * GG + g) * HD + c] = z[g];
    __syncthreads();
    for (int j = t; j < GG * HD; j += 256) dst[GG * HD + j] = sm[j] + sm[GG * HD + j];
}

// ---------------------------------------------------------------------------
// K5: per-graph sum/sumsq of e_hat (g = g8[e], wave-uniform).  Register
//     accumulation, no atomics.
// ---------------------------------------------------------------------------
__global__ __launch_bounds__(512) void estats_part_kernel(
    const u16* __restrict__ ehat, const u8* __restrict__ g8,
    float* __restrict__ epart)
{
    __shared__ float sm[4 * GG * HD];     // 32 KB, reused in 2 phases
    __shared__ float smc[4 * GG];
    const int t = threadIdx.x;
    const int c = t & 127, q = t >> 7;    // q in 0..3, 2 waves per q-group
    const int chunk = (NE + EP - 1) / EP;
    const int rstart = blockIdx.x * chunk;
    const int rend = min(NE, rstart + chunk);
    const float cinc = (c == 0) ? 1.f : 0.f;
    float s[GG], z[GG], cn[GG];
    #pragma unroll
    for (int g = 0; g < GG; ++g) { s[g] = 0.f; z[g] = 0.f; cn[g] = 0.f; }
    for (int row = rstart + q; row < rend; row += 4) {
        int g = __builtin_amdgcn_readfirstlane((int)g8[row]);
        float x = us2f(ehat[(size_t)row * HD + c]);
        ACC_SWITCH(g)
    }
    // phase A: sums + cnt
    #pragma unroll
    for (int g = 0; g < GG; ++g) sm[(q * GG + g) * HD + c] = s[g];
    if (c == 0) {
        #pragma unroll
        for (int g = 0; g < GG; ++g) smc[q * GG + g] = cn[g];
    }
    __syncthreads();
    float* dst = epart + (size_t)blockIdx.x * PSTRIDE;
    for (int j = t; j < GG * HD; j += 512)
        dst[j] = sm[j] + sm[2048 + j] + sm[4096 + j] + sm[6144 + j];
    if (t < GG) dst[2 * GG * HD + t] = smc[t] + smc[GG + t] + smc[2 * GG + t] + smc[3 * GG + t];
    __syncthreads();
    // phase B: sumsq
    #pragma unroll
    for (int g = 0; g < GG; ++g) sm[(q * GG + g) * HD + c] = z[g];
    __syncthreads();
    for (int j = t; j < GG * HD; j += 512)
        dst[GG * HD + j] = sm[j] + sm[2048 + j] + sm[4096 + j] + sm[6144 + j];
}

// ---------------------------------------------------------------------------
// K5b: chunked partial-slice reduce: out[ch][j] = sum over p in chunk of part
//      (called twice: P->nchunk, then nchunk->1)
// ---------------------------------------------------------------------------
__global__ __launch_bounds__(256) void reduce_part_kernel(
    const float* __restrict__ part, int P, int csz, float* __restrict__ out)
{
    int j = blockIdx.x * 256 + threadIdx.x;
    if (j >= SLEN) return;
    int p0 = blockIdx.y * csz;
    int p1 = min(P, p0 + csz);
    float a = 0.f;
    for (int p = p0; p < p1; ++p) a += part[(size_t)p * PSTRIDE + j];
    out[(size_t)blockIdx.y * PSTRIDE + j] = a;
}

// ---------------------------------------------------------------------------
// K6: stats -> (off = mean*ms, istd);  var = E[x^2] - 2*off*mean + off^2
// ---------------------------------------------------------------------------
__global__ __launch_bounds__(256) void finstats_kernel(
    const float* __restrict__ statsH, const float* __restrict__ statsE,
    const float* __restrict__ gnh_ms, const float* __restrict__ gne_ms,
    float* off_h, float* istd_h, float* off_e, float* istd_e)
{
    for (int i = threadIdx.x; i < GG * HD; i += 256) {
        int g = i >> 7, c = i & 127;
        {
            float cnt = fmaxf(statsH[4096 + g], 1.f);
            float mean = statsH[i] / cnt;
            float ex2 = statsH[2048 + i] / cnt;
            float off = mean * gnh_ms[c];
            float var = ex2 - 2.f * off * mean + off * off;
            off_h[i] = off;
            istd_h[i] = rsqrtf(var + EPSV);
        }
        {
            float cnt = fmaxf(statsE[4096 + g], 1.f);
            float mean = statsE[i] / cnt;
            float ex2 = statsE[2048 + i] / cnt;
            float off = mean * gne_ms[c];
            float var = ex2 - 2.f * off * mean + off * off;
            off_e[i] = off;
            istd_e[i] = rsqrtf(var + EPSV);
        }
    }
}

// ---------------------------------------------------------------------------
// K7: tproj = relu(time_emb) @ Wt + bt   [16 x 128]
// ---------------------------------------------------------------------------
__global__ __launch_bounds__(256) void tproj_kernel(
    const float* __restrict__ time_emb, const float* __restrict__ Wt,
    const float* __restrict__ bt, float* __restrict__ tproj)
{
    __shared__ float te[GG][HD];
    const int t = threadIdx.x;
    for (int i = t; i < GG * HD; i += 256) te[i >> 7][i & 127] = fmaxf(time_emb[i], 0.f);
    __syncthreads();
    const int c = t & 127, rb = t >> 7;
    float acc[8];
    #pragma unroll
    for (int j = 0; j < 8; ++j) acc[j] = 0.f;
    for (int k = 0; k < HD; ++k) {
        float wv = Wt[k * HD + c];
        #pragma unroll
        for (int j = 0; j < 8; ++j) acc[j] = fmaf(te[rb + 2 * j][k], wv, acc[j]);
    }
    float b = bt[c];
    #pragma unroll
    for (int j = 0; j < 8; ++j) tproj[(rb + 2 * j) * HD + c] = acc[j] + b;
}

// ---------------------------------------------------------------------------
// K8: h = features + relu(graphnorm_h(fu + aggr));  aggr lives in hout (in-place)
// ---------------------------------------------------------------------------
__global__ __launch_bounds__(256) void hfinal_kernel(
    const float* __restrict__ feat, const u16* __restrict__ fu,
    const int* __restrict__ batch,
    const float* __restrict__ off_h, const float* __restrict__ istd_h,
    const float* __restrict__ gnh_w, const float* __restrict__ gnh_b,
    float* hout_aggr)
{
    int i = blockIdx.x * 256 + threadIdx.x;
    size_t base = (size_t)i * 4;
    if (base >= (size_t)NN * HD) return;
    int row = (int)(base >> 7), c0 = (int)(base & 127);
    int g = batch[row];
    float4 fe = *reinterpret_cast<const float4*>(&feat[base]);
    float4 ag = *reinterpret_cast<const float4*>(&hout_aggr[base]);
    uint2 fv2 = *reinterpret_cast<const uint2*>(&fu[base]);
    float xv[4] = { us2f((u16)fv2.x) + ag.x, us2f((u16)(fv2.x >> 16)) + ag.y,
                    us2f((u16)fv2.y) + ag.z, us2f((u16)(fv2.y >> 16)) + ag.w };
    float4 ou;
    float* op = &ou.x;
    const float* fp = &fe.x;
    #pragma unroll
    for (int j = 0; j < 4; ++j) {
        int idx = g * HD + c0 + j;
        float out = xv[j] - off_h[idx];
        float v = gnh_w[c0 + j] * out * istd_h[idx] + gnh_b[c0 + j];
        op[j] = fp[j] + fmaxf(v, 0.f);
    }
    *reinterpret_cast<float4*>(&hout_aggr[base]) = ou;
}

// ---------------------------------------------------------------------------
// K9: e = nme + silu(LN(relu(graphnorm_e(e_hat)) + tproj[g8])) @ Wo + bo
// ---------------------------------------------------------------------------
__global__ __launch_bounds__(256) void efinal_kernel(
    const u16* __restrict__ ehat, const u8* __restrict__ g8,
    const float* __restrict__ off_e, const float* __restrict__ istd_e,
    const float* __restrict__ gne_w, const float* __restrict__ gne_b,
    const float* __restrict__ tproj,
    const float* __restrict__ ln_w, const float* __restrict__ ln_b,
    const float* __restrict__ Wo, const float* __restrict__ bo,
    float* eout)
{
    __shared__ float ss[32][HD];
    const int t = threadIdx.x;
    const int gbase = blockIdx.x * 32;
    const int w = t >> 6, lane = t & 63;
    const int c0 = lane * 2, r0 = w * 8;
    float2 gw = *reinterpret_cast<const float2*>(&gne_w[c0]);
    float2 gb = *reinterpret_cast<const float2*>(&gne_b[c0]);
    float2 lw = *reinterpret_cast<const float2*>(&ln_w[c0]);
    float2 lb = *reinterpret_cast<const float2*>(&ln_b[c0]);
    for (int r = 0; r < 8; ++r) {
        int e = gbase + r0 + r;
        int g = g8[e];
        u32 ev = *reinterpret_cast<const u32*>(&ehat[(size_t)e * HD + c0]);
        float2 ofe = *reinterpret_cast<const float2*>(&off_e[g * HD + c0]);
        float2 ise = *reinterpret_cast<const float2*>(&istd_e[g * HD + c0]);
        float2 tp  = *reinterpret_cast<const float2*>(&tproj[g * HD + c0]);
        float v0 = gw.x * (us2f((u16)ev) - ofe.x) * ise.x + gb.x;
        float v1 = gw.y * (us2f((u16)(ev >> 16)) - ofe.y) * ise.y + gb.y;
        v0 = fmaxf(v0, 0.f) + tp.x;
        v1 = fmaxf(v1, 0.f) + tp.y;
        float sum = v0 + v1;
        #pragma unroll
        for (int off = 32; off > 0; off >>= 1) sum += __shfl_xor(sum, off, 64);
        float mu = sum * (1.f / 128.f);
        float d0 = v0 - mu, d1 = v1 - mu;
        float sq = d0 * d0 + d1 * d1;
        #pragma unroll
        for (int off = 32; off > 0; off >>= 1) sq += __shfl_xor(sq, off, 64);
        float rstd = rsqrtf(sq * (1.f / 128.f) + EPSV);
        float l0 = d0 * rstd * lw.x + lb.x;
        float l1 = d1 * rstd * lw.y + lb.y;
        *reinterpret_cast<float2*>(&ss[r0 + r][c0]) =
            make_float2(l0 * sigmoidf_(l0), l1 * sigmoidf_(l1));
    }
    __syncthreads();
    float acc[8][2];
    #pragma unroll
    for (int r = 0; r < 8; ++r) { acc[r][0] = 0.f; acc[r][1] = 0.f; }
    for (int k = 0; k < HD; k += 2) {
        float2 w0 = *reinterpret_cast<const float2*>(&Wo[k * HD + c0]);
        float2 w1 = *reinterpret_cast<const float2*>(&Wo[(k + 1) * HD + c0]);
        #pragma unroll
        for (int r = 0; r < 8; ++r) {
            float2 xv = *reinterpret_cast<const float2*>(&ss[r0 + r][k]);
            acc[r][0] = fmaf(xv.x, w0.x, fmaf(xv.y, w1.x, acc[r][0]));
            acc[r][1] = fmaf(xv.x, w0.y, fmaf(xv.y, w1.y, acc[r][1]));
        }
    }
    float2 bo2 = *reinterpret_cast<const float2*>(&bo[c0]);
    #pragma unroll
    for (int r = 0; r < 8; ++r) {
        int e = gbase + r0 + r;
        float2 nm = *reinterpret_cast<const float2*>(&eout[(size_t)e * HD + c0]);
        *reinterpret_cast<float2*>(&eout[(size_t)e * HD + c0]) =
            make_float2(acc[r][0] + bo2.x + nm.x, acc[r][1] + bo2.y + nm.y);
    }
}

// ---------------------------------------------------------------------------
extern "C" void kernel_launch(void* const* d_in, const int* in_sizes, int n_in,
                              void* d_out, int out_size, void* d_ws, size_t ws_size,
                              hipStream_t stream)
{
    const float* feat     = (const float*)d_in[0];
    const int*   eidx     = (const int*)d_in[1];
    const float* noise    = (const float*)d_in[2];
    const float* time_emb = (const float*)d_in[3];
    const int*   batch    = (const int*)d_in[4];
    const float* We = (const float*)d_in[5],  *be = (const float*)d_in[6];
    const float* Wp = (const float*)d_in[7],  *bp = (const float*)d_in[8];
    const float* Wq = (const float*)d_in[9],  *bq = (const float*)d_in[10];
    const float* Wr = (const float*)d_in[11], *br = (const float*)d_in[12];
    const float* Wu = (const float*)d_in[13], *bu = (const float*)d_in[14];
    const float* Wv = (const float*)d_in[15], *bv = (const float*)d_in[16];
    const float* gnh_w = (const float*)d_in[17], *gnh_b = (const float*)d_in[18], *gnh_ms = (const float*)d_in[19];
    const float* gne_w = (const float*)d_in[20], *gne_b = (const float*)d_in[21], *gne_ms = (const float*)d_in[22];
    const float* Wt = (const float*)d_in[23], *bt = (const float*)d_in[24];
    const float* ln_w = (const float*)d_in[25], *ln_b = (const float*)d_in[26];
    const float* Wo = (const float*)d_in[27], *bo = (const float*)d_in[28];

    const int* srcArr = eidx;
    const int* dstArr = eidx + NE;

    float* hout = (float*)d_out;                    // [N,H] f32 — doubles as aggr
    float* eout = hout + (size_t)NN * HD;           // [E,H] f32 — holds nme then e

    char* ws = (char*)d_ws;
    size_t off = 0;
    auto take = [&](size_t bytes) -> char* {
        char* p = ws + off;
        off = (off + bytes + 255) & ~(size_t)255;
        return p;
    };
    u16* ehat = (u16*)take((size_t)NE * HD * 2);    // 102.4 MB
    u16* fq = (u16*)take((size_t)NN * HD * 2);
    u16* fr = (u16*)take((size_t)NN * HD * 2);
    u16* fu = (u16*)take((size_t)NN * HD * 2);
    u16* fv = (u16*)take((size_t)NN * HD * 2);
    u8*  g8 = (u8*)take((size_t)NE);
    float* statsH = (float*)take((size_t)PSTRIDE * 4);
    float* statsE = (float*)take((size_t)PSTRIDE * 4);
    float* tproj  = (float*)take((size_t)GG * HD * 4);
    float* off_h  = (float*)take((size_t)GG * HD * 4);
    float* istd_h = (float*)take((size_t)GG * HD * 4);
    float* off_e  = (float*)take((size_t)GG * HD * 4);
    float* istd_e = (float*)take((size_t)GG * HD * 4);
    float* epart  = (float*)take((size_t)EP * PSTRIDE * 4);   // 8.9 MB
    float* hpart  = (float*)take((size_t)HP * PSTRIDE * 4);   // 4.5 MB
    float* etmp   = (float*)take((size_t)8 * PSTRIDE * 4);
    float* htmp   = (float*)take((size_t)8 * PSTRIDE * 4);

    // zero the atomic accumulator (hout doubles as aggr)
    hipMemsetAsync(hout, 0, (size_t)NN * HD * 4, stream);

    proj4_kernel<<<(NN + 31) / 32, 256, 0, stream>>>(feat, Wq, bq, Wr, br, Wu, bu, Wv, bv,
                                                     fq, fr, fu, fv);
    nme_kernel<<<NE / 32, 256, 0, stream>>>(noise, We, be, eout);
    ehat_kernel<<<NE / 32, 256, 0, stream>>>(eout, Wp, bp, fq, fr, fv, srcArr, dstArr, batch,
                                             ehat, hout, g8);
    hstats_part_kernel<<<HP, 256, 0, stream>>>(fu, hout, batch, hpart);
    estats_part_kernel<<<EP, 512, 0, stream>>>(ehat, g8, epart);
    {
        dim3 gA((SLEN + 255) / 256, 8);
        reduce_part_kernel<<<gA, 256, 0, stream>>>(hpart, HP, HP / 8, htmp);
        reduce_part_kernel<<<gA, 256, 0, stream>>>(epart, EP, EP / 8, etmp);
        dim3 gB((SLEN + 255) / 256, 1);
        reduce_part_kernel<<<gB, 256, 0, stream>>>(htmp, 8, 8, statsH);
        reduce_part_kernel<<<gB, 256, 0, stream>>>(etmp, 8, 8, statsE);
    }
    tproj_kernel<<<1, 256, 0, stream>>>(time_emb, Wt, bt, tproj);
    finstats_kernel<<<1, 256, 0, stream>>>(statsH, statsE, gnh_ms, gne_ms,
                                           off_h, istd_h, off_e, istd_e);
    hfinal_kernel<<<(NN * HD / 4 + 255) / 256, 256, 0, stream>>>(feat, fu, batch, off_h, istd_h,
                                                                 gnh_w, gnh_b, hout);
    efinal_kernel<<<NE / 32, 256, 0, stream>>>(ehat, g8, off_e, istd_e,
                                               gne_w, gne_b, tproj, ln_w, ln_b, Wo, bo, eout);
}

// Round 5
// 1227.711 us; speedup vs baseline: 1.5338x; 1.0615x over previous
//
#include <hip/hip_runtime.h>

#define NN 50000
#define NE 400000
#define HD 128
#define ND 64
#define GG 16
#define EPSV 1e-5f

#define SLEN (2 * GG * HD + GG)   // 4112 floats: [sum 2048 | sumsq 2048 | cnt 16]
#define PSTRIDE 4352              // partial-set stride (floats), non-pow2
#define EP 256                    // estats stage-1 blocks
#define HP 256                    // hstats stage-1 blocks

typedef unsigned short u16;
typedef unsigned int   u32;
typedef unsigned char  u8;

__device__ __forceinline__ float us2f(u16 u) { return __uint_as_float(((u32)u) << 16); }
__device__ __forceinline__ u16 f2us(float f) {
    u32 u = __float_as_uint(f);
    u += 0x7fffu + ((u >> 16) & 1u);   // RNE
    return (u16)(u >> 16);
}
__device__ __forceinline__ float sigmoidf_(float x) { return 1.f / (1.f + __expf(-x)); }

// accumulate x into register-resident per-graph slots via wave-uniform scalar switch
#define ACC_CASE(G) case G: s[G] += x; z[G] = fmaf(x, x, z[G]); cn[G] += cinc; break;
#define ACC_SWITCH(g) switch (g) { \
    ACC_CASE(0) ACC_CASE(1) ACC_CASE(2) ACC_CASE(3) ACC_CASE(4) ACC_CASE(5) \
    ACC_CASE(6) ACC_CASE(7) ACC_CASE(8) ACC_CASE(9) ACC_CASE(10) ACC_CASE(11) \
    ACC_CASE(12) ACC_CASE(13) ACC_CASE(14) ACC_CASE(15) default: break; }

// ---------------------------------------------------------------------------
// K0a: Wep = We @ Wp  [64x128], bep = be @ Wp + bp   (grid=16, Wp in LDS)
// ---------------------------------------------------------------------------
__global__ __launch_bounds__(256) void wep_kernel(
    const float* __restrict__ We, const float* __restrict__ Wp,
    const float* __restrict__ be, const float* __restrict__ bp,
    float* __restrict__ Wep, float* __restrict__ bep)
{
    __shared__ float wp[HD][HD];      // 64 KB
    const int t = threadIdx.x;
    for (int i = t; i < HD * HD; i += 256) wp[i >> 7][i & 127] = Wp[i];
    __syncthreads();
    const int c = t & 127;
    for (int r = blockIdx.x * 4 + (t >> 7); r < (blockIdx.x + 1) * 4 && r < ND; r += 2) {
        float a = 0.f;
        for (int k = 0; k < HD; ++k) a = fmaf(We[r * HD + k], wp[k][c], a);
        Wep[r * HD + c] = a;
    }
    if (blockIdx.x == 0 && t < HD) {
        float a = bp[t];
        for (int k = 0; k < HD; ++k) a = fmaf(be[k], wp[k][t], a);
        bep[t] = a;
    }
}

// ---------------------------------------------------------------------------
// K0b: degree histogram + g8[e] = batch[src[e]]
// ---------------------------------------------------------------------------
__global__ __launch_bounds__(256) void hist_kernel(
    const int* __restrict__ srcArr, const int* __restrict__ batch,
    u32* __restrict__ deg, u8* __restrict__ g8)
{
    int e = blockIdx.x * 256 + threadIdx.x;
    if (e >= NE) return;
    int s = srcArr[e];
    atomicAdd(&deg[s], 1u);
    g8[e] = (u8)batch[s];
}

// ---------------------------------------------------------------------------
// K0c: exclusive prefix sum of deg[NN] -> start[NN+1]   (1 block, 1024 thr)
// ---------------------------------------------------------------------------
#define SCAN_C 49   // 1024*49 = 50176 >= NN
__global__ __launch_bounds__(1024) void scan_kernel(
    const u32* __restrict__ deg, int* __restrict__ start)
{
    __shared__ u32 sums[1024];
    const int t = threadIdx.x;
    const int i0 = t * SCAN_C;
    u32 tot = 0;
    for (int j = 0; j < SCAN_C; ++j) { int i = i0 + j; if (i < NN) tot += deg[i]; }
    sums[t] = tot;
    __syncthreads();
    for (int off = 1; off < 1024; off <<= 1) {
        u32 v = (t >= off) ? sums[t - off] : 0u;
        __syncthreads();
        sums[t] += v;
        __syncthreads();
    }
    u32 run = (t == 0) ? 0u : sums[t - 1];
    for (int j = 0; j < SCAN_C; ++j) {
        int i = i0 + j;
        if (i < NN) { start[i] = (int)run; run += deg[i]; }
    }
    if (t == 1023) start[NN] = (int)run;   // == NE
}

// ---------------------------------------------------------------------------
// K0d: scatter edge ids into CSR order
// ---------------------------------------------------------------------------
__global__ __launch_bounds__(256) void scatter_kernel(
    const int* __restrict__ srcArr, const int* __restrict__ start,
    u32* __restrict__ cnt2, int* __restrict__ perm)
{
    int e = blockIdx.x * 256 + threadIdx.x;
    if (e >= NE) return;
    int s = srcArr[e];
    u32 pos = atomicAdd(&cnt2[s], 1u);
    perm[start[s] + pos] = e;
}

// ---------------------------------------------------------------------------
// K1: fq/fr/fv = features @ {Wq,Wr,Wv} + b (bf16); fu32 = features@Wu + bu (f32 -> hout)
// ---------------------------------------------------------------------------
__global__ __launch_bounds__(256) void proj4_kernel(
    const float* __restrict__ feat,
    const float* __restrict__ Wq, const float* __restrict__ bq,
    const float* __restrict__ Wr, const float* __restrict__ br,
    const float* __restrict__ Wu, const float* __restrict__ bu,
    const float* __restrict__ Wv, const float* __restrict__ bv,
    u16* __restrict__ fq, u16* __restrict__ fr, u16* __restrict__ fv,
    float* __restrict__ fu32)
{
    __shared__ float xs[32][HD];
    const int t = threadIdx.x;
    const int gbase = blockIdx.x * 32;
    #pragma unroll
    for (int i = 0; i < 8; ++i) {
        int idx2 = t + i * 256;          // float2 index, 0..2047
        int row = idx2 >> 6;
        int c2 = (idx2 & 63) * 2;
        float2 v = make_float2(0.f, 0.f);
        int grow = gbase + row;
        if (grow < NN) v = *reinterpret_cast<const float2*>(&feat[(size_t)grow * HD + c2]);
        xs[row][c2] = v.x; xs[row][c2 + 1] = v.y;
    }
    __syncthreads();
    const int w = t >> 6, lane = t & 63;
    const int c0 = lane * 2, r0 = w * 8;
    const float* Ws[4] = {Wq, Wr, Wv, Wu};
    const float* Bs[4] = {bq, br, bv, bu};
    u16* Os[3] = {fq, fr, fv};
    #pragma unroll
    for (int m = 0; m < 4; ++m) {
        const float* W = Ws[m];
        float acc[8][2];
        #pragma unroll
        for (int r = 0; r < 8; ++r) { acc[r][0] = 0.f; acc[r][1] = 0.f; }
        for (int k = 0; k < HD; k += 2) {
            float2 w0 = *reinterpret_cast<const float2*>(&W[k * HD + c0]);
            float2 w1 = *reinterpret_cast<const float2*>(&W[(k + 1) * HD + c0]);
            #pragma unroll
            for (int r = 0; r < 8; ++r) {
                float2 xv = *reinterpret_cast<const float2*>(&xs[r0 + r][k]);
                acc[r][0] = fmaf(xv.x, w0.x, fmaf(xv.y, w1.x, acc[r][0]));
                acc[r][1] = fmaf(xv.x, w0.y, fmaf(xv.y, w1.y, acc[r][1]));
            }
        }
        float2 b2 = *reinterpret_cast<const float2*>(&Bs[m][c0]);
        #pragma unroll
        for (int r = 0; r < 8; ++r) {
            int grow = gbase + r0 + r;
            if (grow < NN) {
                if (m < 3) {
                    u32 o = (u32)f2us(acc[r][0] + b2.x) | ((u32)f2us(acc[r][1] + b2.y) << 16);
                    *reinterpret_cast<u32*>(&Os[m][(size_t)grow * HD + c0]) = o;
                } else {
                    *reinterpret_cast<float2*>(&fu32[(size_t)grow * HD + c0]) =
                        make_float2(acc[r][0] + b2.x, acc[r][1] + b2.y);
                }
            }
        }
    }
}

// ---------------------------------------------------------------------------
// K3: e_hat = noise@Wep + bep + fq[src] + fr[dst]   (K=64 GEMM, bf16 out)
// ---------------------------------------------------------------------------
__global__ __launch_bounds__(256) void ehat_kernel(
    const float* __restrict__ noise, const float* __restrict__ Wep,
    const float* __restrict__ bep,
    const u16* __restrict__ fq, const u16* __restrict__ fr,
    const int* __restrict__ srcArr, const int* __restrict__ dstArr,
    u16* __restrict__ ehat)
{
    __shared__ float xs[32][ND];
    const int t = threadIdx.x;
    const int gbase = blockIdx.x * 32;
    #pragma unroll
    for (int i = 0; i < 4; ++i) {
        int idx2 = t + i * 256;          // 0..1023
        int row = idx2 >> 5;
        int c2 = (idx2 & 31) * 2;
        float2 v = *reinterpret_cast<const float2*>(&noise[(size_t)(gbase + row) * ND + c2]);
        xs[row][c2] = v.x; xs[row][c2 + 1] = v.y;
    }
    __syncthreads();
    const int w = t >> 6, lane = t & 63;
    const int c0 = lane * 2, r0 = w * 8;
    float acc[8][2];
    #pragma unroll
    for (int r = 0; r < 8; ++r) { acc[r][0] = 0.f; acc[r][1] = 0.f; }
    for (int k = 0; k < ND; k += 2) {
        float2 w0 = *reinterpret_cast<const float2*>(&Wep[k * HD + c0]);
        float2 w1 = *reinterpret_cast<const float2*>(&Wep[(k + 1) * HD + c0]);
        #pragma unroll
        for (int r = 0; r < 8; ++r) {
            float2 xv = *reinterpret_cast<const float2*>(&xs[r0 + r][k]);
            acc[r][0] = fmaf(xv.x, w0.x, fmaf(xv.y, w1.x, acc[r][0]));
            acc[r][1] = fmaf(xv.x, w0.y, fmaf(xv.y, w1.y, acc[r][1]));
        }
    }
    float2 b2 = *reinterpret_cast<const float2*>(&bep[c0]);
    #pragma unroll
    for (int r = 0; r < 8; ++r) {
        int e = gbase + r0 + r;
        int s = srcArr[e], d = dstArr[e];
        u32 qv = *reinterpret_cast<const u32*>(&fq[(size_t)s * HD + c0]);
        u32 rv = *reinterpret_cast<const u32*>(&fr[(size_t)d * HD + c0]);
        float e0 = acc[r][0] + b2.x + us2f((u16)qv) + us2f((u16)rv);
        float e1 = acc[r][1] + b2.y + us2f((u16)(qv >> 16)) + us2f((u16)(rv >> 16));
        *reinterpret_cast<u32*>(&ehat[(size_t)e * HD + c0]) =
            (u32)f2us(e0) | ((u32)f2us(e1) << 16);
    }
}

// ---------------------------------------------------------------------------
// K3b: x[node] = fu32[node] + sum_{e in CSR(node)} sigmoid(ehat[e]) * fv[dst[e]]
//      one wave per node, register accumulation, NO atomics. fu32 lives in
//      xout already (written by proj4); in-place RMW by the owning wave.
// ---------------------------------------------------------------------------
__global__ __launch_bounds__(256) void aggr_kernel(
    const u16* __restrict__ ehat, const u16* __restrict__ fv,
    const int* __restrict__ dstArr, const int* __restrict__ start,
    const int* __restrict__ perm, float* __restrict__ xout)
{
    const int w = threadIdx.x >> 6, lane = threadIdx.x & 63;
    const int c0 = lane * 2;
    for (int node = blockIdx.x * 4 + w; node < NN; node += gridDim.x * 4) {
        int s0 = start[node], s1 = start[node + 1];
        float2 uv = *reinterpret_cast<const float2*>(&xout[(size_t)node * HD + c0]);
        float a0 = 0.f, a1 = 0.f;
        for (int j = s0; j < s1; ++j) {
            int e = perm[j];
            int d = dstArr[e];
            u32 ev = *reinterpret_cast<const u32*>(&ehat[(size_t)e * HD + c0]);
            u32 vv = *reinterpret_cast<const u32*>(&fv[(size_t)d * HD + c0]);
            a0 = fmaf(sigmoidf_(us2f((u16)ev)),         us2f((u16)vv),         a0);
            a1 = fmaf(sigmoidf_(us2f((u16)(ev >> 16))), us2f((u16)(vv >> 16)), a1);
        }
        *reinterpret_cast<float2*>(&xout[(size_t)node * HD + c0]) =
            make_float2(a0 + uv.x, a1 + uv.y);
    }
}

// ---------------------------------------------------------------------------
// K4: per-graph sum/sumsq of x (batch sorted -> register accum, no atomics)
// ---------------------------------------------------------------------------
__global__ __launch_bounds__(256) void hstats_part_kernel(
    const float* __restrict__ xout, const int* __restrict__ batch,
    float* __restrict__ hpart)
{
    __shared__ float sm[2 * GG * HD];
    __shared__ float smc[2 * GG];
    const int t = threadIdx.x;
    const int c = t & 127, half = t >> 7;
    const int chunk = (NN + HP - 1) / HP;
    const int rstart = blockIdx.x * chunk;
    const int rend = min(NN, rstart + chunk);
    const float cinc = (c == 0) ? 1.f : 0.f;
    float s[GG], z[GG], cn[GG];
    #pragma unroll
    for (int g = 0; g < GG; ++g) { s[g] = 0.f; z[g] = 0.f; cn[g] = 0.f; }
    for (int row = rstart + half; row < rend; row += 2) {
        int g = __builtin_amdgcn_readfirstlane(batch[row]);
        float x = xout[(size_t)row * HD + c];
        ACC_SWITCH(g)
    }
    #pragma unroll
    for (int g = 0; g < GG; ++g) sm[(half * GG + g) * HD + c] = s[g];
    if (c == 0) {
        #pragma unroll
        for (int g = 0; g < GG; ++g) smc[half * GG + g] = cn[g];
    }
    __syncthreads();
    float* dst = hpart + (size_t)blockIdx.x * PSTRIDE;
    for (int j = t; j < GG * HD; j += 256) dst[j] = sm[j] + sm[GG * HD + j];
    if (t < GG) dst[2 * GG * HD + t] = smc[t] + smc[GG + t];
    __syncthreads();
    #pragma unroll
    for (int g = 0; g < GG; ++g) sm[(half * GG + g) * HD + c] = z[g];
    __syncthreads();
    for (int j = t; j < GG * HD; j += 256) dst[GG * HD + j] = sm[j] + sm[GG * HD + j];
}

// ---------------------------------------------------------------------------
// K5: per-graph sum/sumsq of e_hat (g = g8[e], wave-uniform)
// ---------------------------------------------------------------------------
__global__ __launch_bounds__(512) void estats_part_kernel(
    const u16* __restrict__ ehat, const u8* __restrict__ g8,
    float* __restrict__ epart)
{
    __shared__ float sm[4 * GG * HD];
    __shared__ float smc[4 * GG];
    const int t = threadIdx.x;
    const int c = t & 127, q = t >> 7;
    const int chunk = (NE + EP - 1) / EP;
    const int rstart = blockIdx.x * chunk;
    const int rend = min(NE, rstart + chunk);
    const float cinc = (c == 0) ? 1.f : 0.f;
    float s[GG], z[GG], cn[GG];
    #pragma unroll
    for (int g = 0; g < GG; ++g) { s[g] = 0.f; z[g] = 0.f; cn[g] = 0.f; }
    for (int row = rstart + q; row < rend; row += 4) {
        int g = __builtin_amdgcn_readfirstlane((int)g8[row]);
        float x = us2f(ehat[(size_t)row * HD + c]);
        ACC_SWITCH(g)
    }
    #pragma unroll
    for (int g = 0; g < GG; ++g) sm[(q * GG + g) * HD + c] = s[g];
    if (c == 0) {
        #pragma unroll
        for (int g = 0; g < GG; ++g) smc[q * GG + g] = cn[g];
    }
    __syncthreads();
    float* dst = epart + (size_t)blockIdx.x * PSTRIDE;
    for (int j = t; j < GG * HD; j += 512)
        dst[j] = sm[j] + sm[2048 + j] + sm[4096 + j] + sm[6144 + j];
    if (t < GG) dst[2 * GG * HD + t] = smc[t] + smc[GG + t] + smc[2 * GG + t] + smc[3 * GG + t];
    __syncthreads();
    #pragma unroll
    for (int g = 0; g < GG; ++g) sm[(q * GG + g) * HD + c] = z[g];
    __syncthreads();
    for (int j = t; j < GG * HD; j += 512)
        dst[GG * HD + j] = sm[j] + sm[2048 + j] + sm[4096 + j] + sm[6144 + j];
}

// ---------------------------------------------------------------------------
// K5b: chunked partial-slice reduce
// ---------------------------------------------------------------------------
__global__ __launch_bounds__(256) void reduce_part_kernel(
    const float* __restrict__ part, int P, int csz, float* __restrict__ out)
{
    int j = blockIdx.x * 256 + threadIdx.x;
    if (j >= SLEN) return;
    int p0 = blockIdx.y * csz;
    int p1 = min(P, p0 + csz);
    float a = 0.f;
    for (int p = p0; p < p1; ++p) a += part[(size_t)p * PSTRIDE + j];
    out[(size_t)blockIdx.y * PSTRIDE + j] = a;
}

// ---------------------------------------------------------------------------
// K6: stats -> (off = mean*ms, istd)
// ---------------------------------------------------------------------------
__global__ __launch_bounds__(256) void finstats_kernel(
    const float* __restrict__ statsH, const float* __restrict__ statsE,
    const float* __restrict__ gnh_ms, const float* __restrict__ gne_ms,
    float* off_h, float* istd_h, float* off_e, float* istd_e)
{
    for (int i = threadIdx.x; i < GG * HD; i += 256) {
        int g = i >> 7, c = i & 127;
        {
            float cnt = fmaxf(statsH[4096 + g], 1.f);
            float mean = statsH[i] / cnt;
            float ex2 = statsH[2048 + i] / cnt;
            float off = mean * gnh_ms[c];
            float var = ex2 - 2.f * off * mean + off * off;
            off_h[i] = off;
            istd_h[i] = rsqrtf(var + EPSV);
        }
        {
            float cnt = fmaxf(statsE[4096 + g], 1.f);
            float mean = statsE[i] / cnt;
            float ex2 = statsE[2048 + i] / cnt;
            float off = mean * gne_ms[c];
            float var = ex2 - 2.f * off * mean + off * off;
            off_e[i] = off;
            istd_e[i] = rsqrtf(var + EPSV);
        }
    }
}

// ---------------------------------------------------------------------------
// K7: tproj = relu(time_emb) @ Wt + bt   [16 x 128]
// ---------------------------------------------------------------------------
__global__ __launch_bounds__(256) void tproj_kernel(
    const float* __restrict__ time_emb, const float* __restrict__ Wt,
    const float* __restrict__ bt, float* __restrict__ tproj)
{
    __shared__ float te[GG][HD];
    const int t = threadIdx.x;
    for (int i = t; i < GG * HD; i += 256) te[i >> 7][i & 127] = fmaxf(time_emb[i], 0.f);
    __syncthreads();
    const int c = t & 127, rb = t >> 7;
    float acc[8];
    #pragma unroll
    for (int j = 0; j < 8; ++j) acc[j] = 0.f;
    for (int k = 0; k < HD; ++k) {
        float wv = Wt[k * HD + c];
        #pragma unroll
        for (int j = 0; j < 8; ++j) acc[j] = fmaf(te[rb + 2 * j][k], wv, acc[j]);
    }
    float b = bt[c];
    #pragma unroll
    for (int j = 0; j < 8; ++j) tproj[(rb + 2 * j) * HD + c] = acc[j] + b;
}

// ---------------------------------------------------------------------------
// K8: h = features + relu(graphnorm_h(x));  x lives in hout (in-place)
// ---------------------------------------------------------------------------
__global__ __launch_bounds__(256) void hfinal_kernel(
    const float* __restrict__ feat, const int* __restrict__ batch,
    const float* __restrict__ off_h, const float* __restrict__ istd_h,
    const float* __restrict__ gnh_w, const float* __restrict__ gnh_b,
    float* hout_x)
{
    int i = blockIdx.x * 256 + threadIdx.x;
    size_t base = (size_t)i * 4;
    if (base >= (size_t)NN * HD) return;
    int row = (int)(base >> 7), c0 = (int)(base & 127);
    int g = batch[row];
    float4 fe = *reinterpret_cast<const float4*>(&feat[base]);
    float4 xv = *reinterpret_cast<const float4*>(&hout_x[base]);
    float4 ou;
    float* op = &ou.x;
    const float* fp = &fe.x;
    const float* xp = &xv.x;
    #pragma unroll
    for (int j = 0; j < 4; ++j) {
        int idx = g * HD + c0 + j;
        float out = xp[j] - off_h[idx];
        float v = gnh_w[c0 + j] * out * istd_h[idx] + gnh_b[c0 + j];
        op[j] = fp[j] + fmaxf(v, 0.f);
    }
    *reinterpret_cast<float4*>(&hout_x[base]) = ou;
}

// ---------------------------------------------------------------------------
// K9: e = (noise@We + be) + silu(LN(relu(graphnorm_e(ehat)) + tproj[g8])) @ Wo + bo
//      nme recomputed inline (K=64 GEMM) — never materialized.
// ---------------------------------------------------------------------------
__global__ __launch_bounds__(256) void efinal_kernel(
    const u16* __restrict__ ehat, const u8* __restrict__ g8,
    const float* __restrict__ noise, const float* __restrict__ We,
    const float* __restrict__ be,
    const float* __restrict__ off_e, const float* __restrict__ istd_e,
    const float* __restrict__ gne_w, const float* __restrict__ gne_b,
    const float* __restrict__ tproj,
    const float* __restrict__ ln_w, const float* __restrict__ ln_b,
    const float* __restrict__ Wo, const float* __restrict__ bo,
    float* __restrict__ eout)
{
    __shared__ float ss[32][HD];      // silu(LN(...)) matrix
    __shared__ float ns[32][ND];      // noise tile
    const int t = threadIdx.x;
    const int gbase = blockIdx.x * 32;
    const int w = t >> 6, lane = t & 63;
    const int c0 = lane * 2, r0 = w * 8;
    // stage noise tile
    #pragma unroll
    for (int i = 0; i < 4; ++i) {
        int idx2 = t + i * 256;
        int row = idx2 >> 5;
        int c2 = (idx2 & 31) * 2;
        float2 v = *reinterpret_cast<const float2*>(&noise[(size_t)(gbase + row) * ND + c2]);
        ns[row][c2] = v.x; ns[row][c2 + 1] = v.y;
    }
    float2 gw = *reinterpret_cast<const float2*>(&gne_w[c0]);
    float2 gb = *reinterpret_cast<const float2*>(&gne_b[c0]);
    float2 lw = *reinterpret_cast<const float2*>(&ln_w[c0]);
    float2 lb = *reinterpret_cast<const float2*>(&ln_b[c0]);
    for (int r = 0; r < 8; ++r) {
        int e = gbase + r0 + r;
        int g = g8[e];
        u32 ev = *reinterpret_cast<const u32*>(&ehat[(size_t)e * HD + c0]);
        float2 ofe = *reinterpret_cast<const float2*>(&off_e[g * HD + c0]);
        float2 ise = *reinterpret_cast<const float2*>(&istd_e[g * HD + c0]);
        float2 tp  = *reinterpret_cast<const float2*>(&tproj[g * HD + c0]);
        float v0 = gw.x * (us2f((u16)ev) - ofe.x) * ise.x + gb.x;
        float v1 = gw.y * (us2f((u16)(ev >> 16)) - ofe.y) * ise.y + gb.y;
        v0 = fmaxf(v0, 0.f) + tp.x;
        v1 = fmaxf(v1, 0.f) + tp.y;
        float sum = v0 + v1;
        #pragma unroll
        for (int off = 32; off > 0; off >>= 1) sum += __shfl_xor(sum, off, 64);
        float mu = sum * (1.f / 128.f);
        float d0 = v0 - mu, d1 = v1 - mu;
        float sq = d0 * d0 + d1 * d1;
        #pragma unroll
        for (int off = 32; off > 0; off >>= 1) sq += __shfl_xor(sq, off, 64);
        float rstd = rsqrtf(sq * (1.f / 128.f) + EPSV);
        float l0 = d0 * rstd * lw.x + lb.x;
        float l1 = d1 * rstd * lw.y + lb.y;
        *reinterpret_cast<float2*>(&ss[r0 + r][c0]) =
            make_float2(l0 * sigmoidf_(l0), l1 * sigmoidf_(l1));
    }
    __syncthreads();
    float acc[8][2], nm[8][2];
    #pragma unroll
    for (int r = 0; r < 8; ++r) { acc[r][0] = 0.f; acc[r][1] = 0.f; nm[r][0] = 0.f; nm[r][1] = 0.f; }
    for (int k = 0; k < HD; k += 2) {
        float2 w0 = *reinterpret_cast<const float2*>(&Wo[k * HD + c0]);
        float2 w1 = *reinterpret_cast<const float2*>(&Wo[(k + 1) * HD + c0]);
        #pragma unroll
        for (int r = 0; r < 8; ++r) {
            float2 xv = *reinterpret_cast<const float2*>(&ss[r0 + r][k]);
            acc[r][0] = fmaf(xv.x, w0.x, fmaf(xv.y, w1.x, acc[r][0]));
            acc[r][1] = fmaf(xv.x, w0.y, fmaf(xv.y, w1.y, acc[r][1]));
        }
    }
    for (int k = 0; k < ND; k += 2) {
        float2 w0 = *reinterpret_cast<const float2*>(&We[k * HD + c0]);
        float2 w1 = *reinterpret_cast<const float2*>(&We[(k + 1) * HD + c0]);
        #pragma unroll
        for (int r = 0; r < 8; ++r) {
            float2 xv = *reinterpret_cast<const float2*>(&ns[r0 + r][k]);
            nm[r][0] = fmaf(xv.x, w0.x, fmaf(xv.y, w1.x, nm[r][0]));
            nm[r][1] = fmaf(xv.x, w0.y, fmaf(xv.y, w1.y, nm[r][1]));
        }
    }
    float2 bo2 = *reinterpret_cast<const float2*>(&bo[c0]);
    float2 be2 = *reinterpret_cast<const float2*>(&be[c0]);
    #pragma unroll
    for (int r = 0; r < 8; ++r) {
        int e = gbase + r0 + r;
        *reinterpret_cast<float2*>(&eout[(size_t)e * HD + c0]) =
            make_float2(acc[r][0] + bo2.x + nm[r][0] + be2.x,
                        acc[r][1] + bo2.y + nm[r][1] + be2.y);
    }
}

// ---------------------------------------------------------------------------
extern "C" void kernel_launch(void* const* d_in, const int* in_sizes, int n_in,
                              void* d_out, int out_size, void* d_ws, size_t ws_size,
                              hipStream_t stream)
{
    const float* feat     = (const float*)d_in[0];
    const int*   eidx     = (const int*)d_in[1];
    const float* noise    = (const float*)d_in[2];
    const float* time_emb = (const float*)d_in[3];
    const int*   batch    = (const int*)d_in[4];
    const float* We = (const float*)d_in[5],  *be = (const float*)d_in[6];
    const float* Wp = (const float*)d_in[7],  *bp = (const float*)d_in[8];
    const float* Wq = (const float*)d_in[9],  *bq = (const float*)d_in[10];
    const float* Wr = (const float*)d_in[11], *br = (const float*)d_in[12];
    const float* Wu = (const float*)d_in[13], *bu = (const float*)d_in[14];
    const float* Wv = (const float*)d_in[15], *bv = (const float*)d_in[16];
    const float* gnh_w = (const float*)d_in[17], *gnh_b = (const float*)d_in[18], *gnh_ms = (const float*)d_in[19];
    const float* gne_w = (const float*)d_in[20], *gne_b = (const float*)d_in[21], *gne_ms = (const float*)d_in[22];
    const float* Wt = (const float*)d_in[23], *bt = (const float*)d_in[24];
    const float* ln_w = (const float*)d_in[25], *ln_b = (const float*)d_in[26];
    const float* Wo = (const float*)d_in[27], *bo = (const float*)d_in[28];

    const int* srcArr = eidx;
    const int* dstArr = eidx + NE;

    float* hout = (float*)d_out;                    // [N,H] f32 — holds fu32, then x, then h
    float* eout = hout + (size_t)NN * HD;           // [E,H] f32 — final e

    char* ws = (char*)d_ws;
    size_t off = 0;
    auto take = [&](size_t bytes) -> char* {
        char* p = ws + off;
        off = (off + bytes + 255) & ~(size_t)255;
        return p;
    };
    u16* ehat = (u16*)take((size_t)NE * HD * 2);    // 102.4 MB
    u16* fq = (u16*)take((size_t)NN * HD * 2);      // 12.8 MB
    u16* fr = (u16*)take((size_t)NN * HD * 2);
    u16* fv = (u16*)take((size_t)NN * HD * 2);
    u8*  g8 = (u8*)take((size_t)NE);
    u32* deg  = (u32*)take((size_t)2 * NN * 4);     // deg[NN] + cnt2[NN], one memset
    u32* cnt2 = deg + NN;
    int* start = (int*)take((size_t)(NN + 1) * 4);
    int* perm  = (int*)take((size_t)NE * 4);
    float* Wep = (float*)take((size_t)ND * HD * 4);
    float* bep = (float*)take((size_t)HD * 4);
    float* statsH = (float*)take((size_t)PSTRIDE * 4);
    float* statsE = (float*)take((size_t)PSTRIDE * 4);
    float* tproj  = (float*)take((size_t)GG * HD * 4);
    float* off_h  = (float*)take((size_t)GG * HD * 4);
    float* istd_h = (float*)take((size_t)GG * HD * 4);
    float* off_e  = (float*)take((size_t)GG * HD * 4);
    float* istd_e = (float*)take((size_t)GG * HD * 4);
    float* epart  = (float*)take((size_t)EP * PSTRIDE * 4);   // 4.5 MB
    float* hpart  = (float*)take((size_t)HP * PSTRIDE * 4);   // 4.5 MB
    float* etmp   = (float*)take((size_t)8 * PSTRIDE * 4);
    float* htmp   = (float*)take((size_t)8 * PSTRIDE * 4);
    // total ~152.7 MB < known-good 153.7 MB (R1) < ws_size

    hipMemsetAsync(deg, 0, (size_t)2 * NN * 4, stream);

    wep_kernel<<<16, 256, 0, stream>>>(We, Wp, be, bp, Wep, bep);
    hist_kernel<<<(NE + 255) / 256, 256, 0, stream>>>(srcArr, batch, deg, g8);
    scan_kernel<<<1, 1024, 0, stream>>>(deg, start);
    scatter_kernel<<<(NE + 255) / 256, 256, 0, stream>>>(srcArr, start, cnt2, perm);
    proj4_kernel<<<(NN + 31) / 32, 256, 0, stream>>>(feat, Wq, bq, Wr, br, Wu, bu, Wv, bv,
                                                     fq, fr, fv, hout);
    ehat_kernel<<<NE / 32, 256, 0, stream>>>(noise, Wep, bep, fq, fr, srcArr, dstArr, ehat);
    aggr_kernel<<<2048, 256, 0, stream>>>(ehat, fv, dstArr, start, perm, hout);
    hstats_part_kernel<<<HP, 256, 0, stream>>>(hout, batch, hpart);
    estats_part_kernel<<<EP, 512, 0, stream>>>(ehat, g8, epart);
    {
        dim3 gA((SLEN + 255) / 256, 8);
        reduce_part_kernel<<<gA, 256, 0, stream>>>(hpart, HP, HP / 8, htmp);
        reduce_part_kernel<<<gA, 256, 0, stream>>>(epart, EP, EP / 8, etmp);
        dim3 gB((SLEN + 255) / 256, 1);
        reduce_part_kernel<<<gB, 256, 0, stream>>>(htmp, 8, 8, statsH);
        reduce_part_kernel<<<gB, 256, 0, stream>>>(etmp, 8, 8, statsE);
    }
    tproj_kernel<<<1, 256, 0, stream>>>(time_emb, Wt, bt, tproj);
    finstats_kernel<<<1, 256, 0, stream>>>(statsH, statsE, gnh_ms, gne_ms,
                                           off_h, istd_h, off_e, istd_e);
    hfinal_kernel<<<(NN * HD / 4 + 255) / 256, 256, 0, stream>>>(feat, batch, off_h, istd_h,
                                                                 gnh_w, gnh_b, hout);
    efinal_kernel<<<NE / 32, 256, 0, stream>>>(ehat, g8, noise, We, be, off_e, istd_e,
                                               gne_w, gne_b, tproj, ln_w, ln_b, Wo, bo, eout);
}

// Round 6
// 1072.860 us; speedup vs baseline: 1.7552x; 1.1443x over previous
//
#include <hip/hip_runtime.h>

#define NN 50000
#define NE 400000
#define HD 128
#define ND 64
#define GG 16
#define EPSV 1e-5f
#define ETILE 64

#define SLEN (2 * GG * HD + GG)   // 4112 floats: [sum 2048 | sumsq 2048 | cnt 16]
#define PSTRIDE 4352              // partial-set stride (floats), non-pow2
#define EP 256                    // estats stage-1 blocks
#define HP 256                    // hstats stage-1 blocks

typedef unsigned short u16;
typedef unsigned int   u32;
typedef unsigned char  u8;
typedef __attribute__((__ext_vector_type__(8))) __bf16 bf16x8;
typedef __attribute__((__ext_vector_type__(4))) float  f32x4;

__device__ __forceinline__ float us2f(u16 u) { return __uint_as_float(((u32)u) << 16); }
__device__ __forceinline__ u16 f2us(float f) {
    u32 u = __float_as_uint(f);
    u += 0x7fffu + ((u >> 16) & 1u);   // RNE
    return (u16)(u >> 16);
}
__device__ __forceinline__ float sigmoidf_(float x) { return 1.f / (1.f + __expf(-x)); }

// accumulate x into register-resident per-graph slots via wave-uniform scalar switch
#define ACC_CASE(G) case G: s[G] += x; z[G] = fmaf(x, x, z[G]); cn[G] += cinc; break;
#define ACC_SWITCH(g) switch (g) { \
    ACC_CASE(0) ACC_CASE(1) ACC_CASE(2) ACC_CASE(3) ACC_CASE(4) ACC_CASE(5) \
    ACC_CASE(6) ACC_CASE(7) ACC_CASE(8) ACC_CASE(9) ACC_CASE(10) ACC_CASE(11) \
    ACC_CASE(12) ACC_CASE(13) ACC_CASE(14) ACC_CASE(15) default: break; }

// ---------------------------------------------------------------------------
// K0a: Wep = We @ Wp  [64x128], bep = be @ Wp + bp   (grid=16, Wp in LDS)
// ---------------------------------------------------------------------------
__global__ __launch_bounds__(256) void wep_kernel(
    const float* __restrict__ We, const float* __restrict__ Wp,
    const float* __restrict__ be, const float* __restrict__ bp,
    float* __restrict__ Wep, float* __restrict__ bep)
{
    __shared__ float wp[HD][HD];      // 64 KB
    const int t = threadIdx.x;
    for (int i = t; i < HD * HD; i += 256) wp[i >> 7][i & 127] = Wp[i];
    __syncthreads();
    const int c = t & 127;
    for (int r = blockIdx.x * 4 + (t >> 7); r < (blockIdx.x + 1) * 4 && r < ND; r += 2) {
        float a = 0.f;
        for (int k = 0; k < HD; ++k) a = fmaf(We[r * HD + k], wp[k][c], a);
        Wep[r * HD + c] = a;
    }
    if (blockIdx.x == 0 && t < HD) {
        float a = bp[t];
        for (int k = 0; k < HD; ++k) a = fmaf(be[k], wp[k][t], a);
        bep[t] = a;
    }
}

// ---------------------------------------------------------------------------
// K0e: transpose f32 [K][128] -> bf16 [128][K]  (B-operand layout for MFMA)
// ---------------------------------------------------------------------------
__global__ __launch_bounds__(256) void prep_kernel(
    const float* __restrict__ in, u16* __restrict__ out, int K)
{
    int idx = blockIdx.x * 256 + threadIdx.x;
    if (idx >= K * HD) return;
    int k = idx >> 7, n = idx & 127;
    out[n * K + k] = f2us(in[idx]);
}

// ---------------------------------------------------------------------------
// K0b: degree histogram + g8[e] = batch[src[e]]
// ---------------------------------------------------------------------------
__global__ __launch_bounds__(256) void hist_kernel(
    const int* __restrict__ srcArr, const int* __restrict__ batch,
    u32* __restrict__ deg, u8* __restrict__ g8)
{
    int e = blockIdx.x * 256 + threadIdx.x;
    if (e >= NE) return;
    int s = srcArr[e];
    atomicAdd(&deg[s], 1u);
    g8[e] = (u8)batch[s];
}

// ---------------------------------------------------------------------------
// K0c: exclusive prefix sum of deg[NN] -> start[NN+1]   (1 block, 1024 thr)
// ---------------------------------------------------------------------------
#define SCAN_C 49   // 1024*49 = 50176 >= NN
__global__ __launch_bounds__(1024) void scan_kernel(
    const u32* __restrict__ deg, int* __restrict__ start)
{
    __shared__ u32 sums[1024];
    const int t = threadIdx.x;
    const int i0 = t * SCAN_C;
    u32 tot = 0;
    for (int j = 0; j < SCAN_C; ++j) { int i = i0 + j; if (i < NN) tot += deg[i]; }
    sums[t] = tot;
    __syncthreads();
    for (int off = 1; off < 1024; off <<= 1) {
        u32 v = (t >= off) ? sums[t - off] : 0u;
        __syncthreads();
        sums[t] += v;
        __syncthreads();
    }
    u32 run = (t == 0) ? 0u : sums[t - 1];
    for (int j = 0; j < SCAN_C; ++j) {
        int i = i0 + j;
        if (i < NN) { start[i] = (int)run; run += deg[i]; }
    }
    if (t == 1023) start[NN] = (int)run;   // == NE
}

// ---------------------------------------------------------------------------
// K0d: scatter edge ids into CSR order
// ---------------------------------------------------------------------------
__global__ __launch_bounds__(256) void scatter_kernel(
    const int* __restrict__ srcArr, const int* __restrict__ start,
    u32* __restrict__ cnt2, int* __restrict__ perm)
{
    int e = blockIdx.x * 256 + threadIdx.x;
    if (e >= NE) return;
    int s = srcArr[e];
    u32 pos = atomicAdd(&cnt2[s], 1u);
    perm[start[s] + pos] = e;
}

// ---------------------------------------------------------------------------
// K1: MFMA: fq/fr/fv = feat @ {Wq,Wr,Wv} + b (bf16); fu32 = feat@Wu + bu (f32)
//     64 rows/block, 4 waves x 16-row stripes, A staged bf16 swizzled in LDS.
// ---------------------------------------------------------------------------
__global__ __launch_bounds__(256) void proj4_kernel(
    const float* __restrict__ feat,
    const u16* __restrict__ WqT, const u16* __restrict__ WrT,
    const u16* __restrict__ WvT, const u16* __restrict__ WuT,
    const float* __restrict__ bq, const float* __restrict__ br,
    const float* __restrict__ bv, const float* __restrict__ bu,
    u16* __restrict__ fq, u16* __restrict__ fr, u16* __restrict__ fv,
    float* __restrict__ fu32)
{
    __shared__ __align__(16) u16 As[ETILE * HD];   // 16 KB, XOR-swizzled
    const int t = threadIdx.x;
    const int rbase = blockIdx.x * ETILE;
    #pragma unroll
    for (int i = 0; i < 16; ++i) {
        int idx2 = t + i * 256;            // bf16-pair index
        int row = idx2 >> 6, p = idx2 & 63;
        int grow = rbase + row;
        float2 v = make_float2(0.f, 0.f);
        if (grow < NN) v = *reinterpret_cast<const float2*>(&feat[(size_t)grow * HD + p * 2]);
        u32 pk = (u32)f2us(v.x) | ((u32)f2us(v.y) << 16);
        int off = (row * 256 + p * 4) ^ ((row & 7) << 4);
        *reinterpret_cast<u32*>(reinterpret_cast<char*>(As) + off) = pk;
    }
    __syncthreads();
    const int w = t >> 6, lane = t & 63;
    const int rt = w * 16, l15 = lane & 15, kg = lane >> 4;
    const int lrow = rt + l15;
    bf16x8 afr[4];
    #pragma unroll
    for (int kk = 0; kk < 4; ++kk) {
        int off = (lrow * 256 + (kk * 32 + kg * 8) * 2) ^ ((lrow & 7) << 4);
        afr[kk] = *reinterpret_cast<const bf16x8*>(reinterpret_cast<const char*>(As) + off);
    }
    const u16* WTs[4] = {WqT, WrT, WvT, WuT};
    const float* Bs2[4] = {bq, br, bv, bu};
    u16* Os[3] = {fq, fr, fv};
    #pragma unroll
    for (int m = 0; m < 4; ++m) {
        f32x4 acc[8];
        #pragma unroll
        for (int nt = 0; nt < 8; ++nt) { acc[nt][0]=0.f; acc[nt][1]=0.f; acc[nt][2]=0.f; acc[nt][3]=0.f; }
        const u16* W = WTs[m];
        #pragma unroll
        for (int nt = 0; nt < 8; ++nt) {
            #pragma unroll
            for (int kk = 0; kk < 4; ++kk) {
                bf16x8 b = *reinterpret_cast<const bf16x8*>(&W[(nt * 16 + l15) * HD + kk * 32 + kg * 8]);
                acc[nt] = __builtin_amdgcn_mfma_f32_16x16x32_bf16(afr[kk], b, acc[nt], 0, 0, 0);
            }
        }
        #pragma unroll
        for (int nt = 0; nt < 8; ++nt) {
            int gcol = nt * 16 + l15;
            float bias = Bs2[m][gcol];
            #pragma unroll
            for (int i = 0; i < 4; ++i) {
                int grow = rbase + rt + kg * 4 + i;
                if (grow < NN) {
                    float v = acc[nt][i] + bias;
                    if (m < 3) Os[m][(size_t)grow * HD + gcol] = f2us(v);
                    else       fu32[(size_t)grow * HD + gcol] = v;
                }
            }
        }
    }
}

// ---------------------------------------------------------------------------
// K3: MFMA: e_hat = noise@Wep + bep + fq[src] + fr[dst]  (K=64, bf16 out)
// ---------------------------------------------------------------------------
__global__ __launch_bounds__(256) void ehat_kernel(
    const float* __restrict__ noise, const u16* __restrict__ WepT,
    const float* __restrict__ bep,
    const u16* __restrict__ fq, const u16* __restrict__ fr,
    const int* __restrict__ srcArr, const int* __restrict__ dstArr,
    u16* __restrict__ ehat)
{
    __shared__ __align__(16) u16 Ns[ETILE * ND];   // 8 KB, XOR-swizzled
    const int t = threadIdx.x;
    const int rbase = blockIdx.x * ETILE;
    #pragma unroll
    for (int i = 0; i < 8; ++i) {
        int idx2 = t + i * 256;
        int row = idx2 >> 5, p = idx2 & 31;
        float2 v = *reinterpret_cast<const float2*>(&noise[(size_t)(rbase + row) * ND + p * 2]);
        u32 pk = (u32)f2us(v.x) | ((u32)f2us(v.y) << 16);
        int off = (row * 128 + p * 4) ^ ((row & 7) << 4);
        *reinterpret_cast<u32*>(reinterpret_cast<char*>(Ns) + off) = pk;
    }
    __syncthreads();
    const int w = t >> 6, lane = t & 63;
    const int rt = w * 16, l15 = lane & 15, kg = lane >> 4;
    const int lrow = rt + l15;
    bf16x8 afr[2];
    #pragma unroll
    for (int kk = 0; kk < 2; ++kk) {
        int off = (lrow * 128 + (kk * 32 + kg * 8) * 2) ^ ((lrow & 7) << 4);
        afr[kk] = *reinterpret_cast<const bf16x8*>(reinterpret_cast<const char*>(Ns) + off);
    }
    f32x4 acc[8];
    #pragma unroll
    for (int nt = 0; nt < 8; ++nt) { acc[nt][0]=0.f; acc[nt][1]=0.f; acc[nt][2]=0.f; acc[nt][3]=0.f; }
    float bepv[8];
    #pragma unroll
    for (int nt = 0; nt < 8; ++nt) {
        bepv[nt] = bep[nt * 16 + l15];
        #pragma unroll
        for (int kk = 0; kk < 2; ++kk) {
            bf16x8 b = *reinterpret_cast<const bf16x8*>(&WepT[(nt * 16 + l15) * ND + kk * 32 + kg * 8]);
            acc[nt] = __builtin_amdgcn_mfma_f32_16x16x32_bf16(afr[kk], b, acc[nt], 0, 0, 0);
        }
    }
    #pragma unroll
    for (int i = 0; i < 4; ++i) {
        int grow = rbase + rt + kg * 4 + i;
        int s = srcArr[grow], d = dstArr[grow];
        #pragma unroll
        for (int nt = 0; nt < 8; ++nt) {
            int gcol = nt * 16 + l15;
            float v = acc[nt][i] + bepv[nt]
                    + us2f(fq[(size_t)s * HD + gcol]) + us2f(fr[(size_t)d * HD + gcol]);
            ehat[(size_t)grow * HD + gcol] = f2us(v);
        }
    }
}

// ---------------------------------------------------------------------------
// K3b: x[node] = fu32[node] + sum_{e in CSR(node)} sigmoid(ehat[e]) * fv[dst[e]]
// ---------------------------------------------------------------------------
__global__ __launch_bounds__(256) void aggr_kernel(
    const u16* __restrict__ ehat, const u16* __restrict__ fv,
    const int* __restrict__ dstArr, const int* __restrict__ start,
    const int* __restrict__ perm, float* __restrict__ xout)
{
    const int w = threadIdx.x >> 6, lane = threadIdx.x & 63;
    const int c0 = lane * 2;
    for (int node = blockIdx.x * 4 + w; node < NN; node += gridDim.x * 4) {
        int s0 = start[node], s1 = start[node + 1];
        float2 uv = *reinterpret_cast<const float2*>(&xout[(size_t)node * HD + c0]);
        float a0 = 0.f, a1 = 0.f;
        for (int j = s0; j < s1; ++j) {
            int e = perm[j];
            int d = dstArr[e];
            u32 ev = *reinterpret_cast<const u32*>(&ehat[(size_t)e * HD + c0]);
            u32 vv = *reinterpret_cast<const u32*>(&fv[(size_t)d * HD + c0]);
            a0 = fmaf(sigmoidf_(us2f((u16)ev)),         us2f((u16)vv),         a0);
            a1 = fmaf(sigmoidf_(us2f((u16)(ev >> 16))), us2f((u16)(vv >> 16)), a1);
        }
        *reinterpret_cast<float2*>(&xout[(size_t)node * HD + c0]) =
            make_float2(a0 + uv.x, a1 + uv.y);
    }
}

// ---------------------------------------------------------------------------
// K4: per-graph sum/sumsq of x (batch sorted -> register accum, no atomics)
// ---------------------------------------------------------------------------
__global__ __launch_bounds__(256) void hstats_part_kernel(
    const float* __restrict__ xout, const int* __restrict__ batch,
    float* __restrict__ hpart)
{
    __shared__ float sm[2 * GG * HD];
    __shared__ float smc[2 * GG];
    const int t = threadIdx.x;
    const int c = t & 127, half = t >> 7;
    const int chunk = (NN + HP - 1) / HP;
    const int rstart = blockIdx.x * chunk;
    const int rend = min(NN, rstart + chunk);
    const float cinc = (c == 0) ? 1.f : 0.f;
    float s[GG], z[GG], cn[GG];
    #pragma unroll
    for (int g = 0; g < GG; ++g) { s[g] = 0.f; z[g] = 0.f; cn[g] = 0.f; }
    for (int row = rstart + half; row < rend; row += 2) {
        int g = __builtin_amdgcn_readfirstlane(batch[row]);
        float x = xout[(size_t)row * HD + c];
        ACC_SWITCH(g)
    }
    #pragma unroll
    for (int g = 0; g < GG; ++g) sm[(half * GG + g) * HD + c] = s[g];
    if (c == 0) {
        #pragma unroll
        for (int g = 0; g < GG; ++g) smc[half * GG + g] = cn[g];
    }
    __syncthreads();
    float* dst = hpart + (size_t)blockIdx.x * PSTRIDE;
    for (int j = t; j < GG * HD; j += 256) dst[j] = sm[j] + sm[GG * HD + j];
    if (t < GG) dst[2 * GG * HD + t] = smc[t] + smc[GG + t];
    __syncthreads();
    #pragma unroll
    for (int g = 0; g < GG; ++g) sm[(half * GG + g) * HD + c] = z[g];
    __syncthreads();
    for (int j = t; j < GG * HD; j += 256) dst[GG * HD + j] = sm[j] + sm[GG * HD + j];
}

// ---------------------------------------------------------------------------
// K5: per-graph sum/sumsq of e_hat (g = g8[e], wave-uniform)
// ---------------------------------------------------------------------------
__global__ __launch_bounds__(512) void estats_part_kernel(
    const u16* __restrict__ ehat, const u8* __restrict__ g8,
    float* __restrict__ epart)
{
    __shared__ float sm[4 * GG * HD];
    __shared__ float smc[4 * GG];
    const int t = threadIdx.x;
    const int c = t & 127, q = t >> 7;
    const int chunk = (NE + EP - 1) / EP;
    const int rstart = blockIdx.x * chunk;
    const int rend = min(NE, rstart + chunk);
    const float cinc = (c == 0) ? 1.f : 0.f;
    float s[GG], z[GG], cn[GG];
    #pragma unroll
    for (int g = 0; g < GG; ++g) { s[g] = 0.f; z[g] = 0.f; cn[g] = 0.f; }
    for (int row = rstart + q; row < rend; row += 4) {
        int g = __builtin_amdgcn_readfirstlane((int)g8[row]);
        float x = us2f(ehat[(size_t)row * HD + c]);
        ACC_SWITCH(g)
    }
    #pragma unroll
    for (int g = 0; g < GG; ++g) sm[(q * GG + g) * HD + c] = s[g];
    if (c == 0) {
        #pragma unroll
        for (int g = 0; g < GG; ++g) smc[q * GG + g] = cn[g];
    }
    __syncthreads();
    float* dst = epart + (size_t)blockIdx.x * PSTRIDE;
    for (int j = t; j < GG * HD; j += 512)
        dst[j] = sm[j] + sm[2048 + j] + sm[4096 + j] + sm[6144 + j];
    if (t < GG) dst[2 * GG * HD + t] = smc[t] + smc[GG + t] + smc[2 * GG + t] + smc[3 * GG + t];
    __syncthreads();
    #pragma unroll
    for (int g = 0; g < GG; ++g) sm[(q * GG + g) * HD + c] = z[g];
    __syncthreads();
    for (int j = t; j < GG * HD; j += 512)
        dst[GG * HD + j] = sm[j] + sm[2048 + j] + sm[4096 + j] + sm[6144 + j];
}

// ---------------------------------------------------------------------------
// K5b: chunked partial-slice reduce
// ---------------------------------------------------------------------------
__global__ __launch_bounds__(256) void reduce_part_kernel(
    const float* __restrict__ part, int P, int csz, float* __restrict__ out)
{
    int j = blockIdx.x * 256 + threadIdx.x;
    if (j >= SLEN) return;
    int p0 = blockIdx.y * csz;
    int p1 = min(P, p0 + csz);
    float a = 0.f;
    for (int p = p0; p < p1; ++p) a += part[(size_t)p * PSTRIDE + j];
    out[(size_t)blockIdx.y * PSTRIDE + j] = a;
}

// ---------------------------------------------------------------------------
// K6: stats -> (off = mean*ms, istd)
// ---------------------------------------------------------------------------
__global__ __launch_bounds__(256) void finstats_kernel(
    const float* __restrict__ statsH, const float* __restrict__ statsE,
    const float* __restrict__ gnh_ms, const float* __restrict__ gne_ms,
    float* off_h, float* istd_h, float* off_e, float* istd_e)
{
    for (int i = threadIdx.x; i < GG * HD; i += 256) {
        int g = i >> 7, c = i & 127;
        {
            float cnt = fmaxf(statsH[4096 + g], 1.f);
            float mean = statsH[i] / cnt;
            float ex2 = statsH[2048 + i] / cnt;
            float off = mean * gnh_ms[c];
            float var = ex2 - 2.f * off * mean + off * off;
            off_h[i] = off;
            istd_h[i] = rsqrtf(var + EPSV);
        }
        {
            float cnt = fmaxf(statsE[4096 + g], 1.f);
            float mean = statsE[i] / cnt;
            float ex2 = statsE[2048 + i] / cnt;
            float off = mean * gne_ms[c];
            float var = ex2 - 2.f * off * mean + off * off;
            off_e[i] = off;
            istd_e[i] = rsqrtf(var + EPSV);
        }
    }
}

// ---------------------------------------------------------------------------
// K7: tproj = relu(time_emb) @ Wt + bt   [16 x 128]
// ---------------------------------------------------------------------------
__global__ __launch_bounds__(256) void tproj_kernel(
    const float* __restrict__ time_emb, const float* __restrict__ Wt,
    const float* __restrict__ bt, float* __restrict__ tproj)
{
    __shared__ float te[GG][HD];
    const int t = threadIdx.x;
    for (int i = t; i < GG * HD; i += 256) te[i >> 7][i & 127] = fmaxf(time_emb[i], 0.f);
    __syncthreads();
    const int c = t & 127, rb = t >> 7;
    float acc[8];
    #pragma unroll
    for (int j = 0; j < 8; ++j) acc[j] = 0.f;
    for (int k = 0; k < HD; ++k) {
        float wv = Wt[k * HD + c];
        #pragma unroll
        for (int j = 0; j < 8; ++j) acc[j] = fmaf(te[rb + 2 * j][k], wv, acc[j]);
    }
    float b = bt[c];
    #pragma unroll
    for (int j = 0; j < 8; ++j) tproj[(rb + 2 * j) * HD + c] = acc[j] + b;
}

// ---------------------------------------------------------------------------
// K8: h = features + relu(graphnorm_h(x));  x lives in hout (in-place)
// ---------------------------------------------------------------------------
__global__ __launch_bounds__(256) void hfinal_kernel(
    const float* __restrict__ feat, const int* __restrict__ batch,
    const float* __restrict__ off_h, const float* __restrict__ istd_h,
    const float* __restrict__ gnh_w, const float* __restrict__ gnh_b,
    float* hout_x)
{
    int i = blockIdx.x * 256 + threadIdx.x;
    size_t base = (size_t)i * 4;
    if (base >= (size_t)NN * HD) return;
    int row = (int)(base >> 7), c0 = (int)(base & 127);
    int g = batch[row];
    float4 fe = *reinterpret_cast<const float4*>(&feat[base]);
    float4 xv = *reinterpret_cast<const float4*>(&hout_x[base]);
    float4 ou;
    float* op = &ou.x;
    const float* fp = &fe.x;
    const float* xp = &xv.x;
    #pragma unroll
    for (int j = 0; j < 4; ++j) {
        int idx = g * HD + c0 + j;
        float out = xp[j] - off_h[idx];
        float v = gnh_w[c0 + j] * out * istd_h[idx] + gnh_b[c0 + j];
        op[j] = fp[j] + fmaxf(v, 0.f);
    }
    *reinterpret_cast<float4*>(&hout_x[base]) = ou;
}

// ---------------------------------------------------------------------------
// K9: MFMA: e = noise@We + be + silu(LN(relu(gn_e(ehat)) + tproj[g8])) @ Wo + bo
//     Phase 1: per-row LN/silu -> bf16 A-tile in LDS (swizzled).
//     Phase 2: acc = A_ss@WoT + A_noise@WeT (accumulated), + bo + be, f32 store.
// ---------------------------------------------------------------------------
__global__ __launch_bounds__(256) void efinal_kernel(
    const u16* __restrict__ ehat, const u8* __restrict__ g8,
    const float* __restrict__ noise,
    const u16* __restrict__ WoT, const u16* __restrict__ WeT,
    const float* __restrict__ be, const float* __restrict__ bo,
    const float* __restrict__ off_e, const float* __restrict__ istd_e,
    const float* __restrict__ gne_w, const float* __restrict__ gne_b,
    const float* __restrict__ tproj,
    const float* __restrict__ ln_w, const float* __restrict__ ln_b,
    float* __restrict__ eout)
{
    __shared__ __align__(16) u16 As[ETILE * HD];   // 16 KB silu-LN bf16, swizzled
    __shared__ __align__(16) u16 Ns[ETILE * ND];   // 8 KB noise bf16, swizzled
    const int t = threadIdx.x;
    const int rbase = blockIdx.x * ETILE;
    const int w = t >> 6, lane = t & 63;
    // stage noise tile
    #pragma unroll
    for (int i = 0; i < 8; ++i) {
        int idx2 = t + i * 256;
        int row = idx2 >> 5, p = idx2 & 31;
        float2 v = *reinterpret_cast<const float2*>(&noise[(size_t)(rbase + row) * ND + p * 2]);
        u32 pk = (u32)f2us(v.x) | ((u32)f2us(v.y) << 16);
        int off = (row * 128 + p * 4) ^ ((row & 7) << 4);
        *reinterpret_cast<u32*>(reinterpret_cast<char*>(Ns) + off) = pk;
    }
    // phase 1: LN/silu for this wave's 16 rows, 2 cols per lane
    const int c0 = lane * 2;
    float2 gw = *reinterpret_cast<const float2*>(&gne_w[c0]);
    float2 gb = *reinterpret_cast<const float2*>(&gne_b[c0]);
    float2 lw = *reinterpret_cast<const float2*>(&ln_w[c0]);
    float2 lb = *reinterpret_cast<const float2*>(&ln_b[c0]);
    for (int r = 0; r < 16; ++r) {
        int row = w * 16 + r;
        int e = rbase + row;
        int g = g8[e];
        u32 ev = *reinterpret_cast<const u32*>(&ehat[(size_t)e * HD + c0]);
        float2 ofe = *reinterpret_cast<const float2*>(&off_e[g * HD + c0]);
        float2 ise = *reinterpret_cast<const float2*>(&istd_e[g * HD + c0]);
        float2 tp  = *reinterpret_cast<const float2*>(&tproj[g * HD + c0]);
        float v0 = gw.x * (us2f((u16)ev) - ofe.x) * ise.x + gb.x;
        float v1 = gw.y * (us2f((u16)(ev >> 16)) - ofe.y) * ise.y + gb.y;
        v0 = fmaxf(v0, 0.f) + tp.x;
        v1 = fmaxf(v1, 0.f) + tp.y;
        float sum = v0 + v1;
        #pragma unroll
        for (int off = 32; off > 0; off >>= 1) sum += __shfl_xor(sum, off, 64);
        float mu = sum * (1.f / 128.f);
        float d0 = v0 - mu, d1 = v1 - mu;
        float sq = d0 * d0 + d1 * d1;
        #pragma unroll
        for (int off = 32; off > 0; off >>= 1) sq += __shfl_xor(sq, off, 64);
        float rstd = rsqrtf(sq * (1.f / 128.f) + EPSV);
        float l0 = d0 * rstd * lw.x + lb.x;
        float l1 = d1 * rstd * lw.y + lb.y;
        float s0 = l0 * sigmoidf_(l0), s1 = l1 * sigmoidf_(l1);
        u32 pk = (u32)f2us(s0) | ((u32)f2us(s1) << 16);
        int off2 = (row * 256 + lane * 4) ^ ((row & 7) << 4);
        *reinterpret_cast<u32*>(reinterpret_cast<char*>(As) + off2) = pk;
    }
    __syncthreads();
    // phase 2: MFMA
    const int rt = w * 16, l15 = lane & 15, kg = lane >> 4;
    const int lrow = rt + l15;
    bf16x8 aW[4], aN[2];
    #pragma unroll
    for (int kk = 0; kk < 4; ++kk) {
        int off = (lrow * 256 + (kk * 32 + kg * 8) * 2) ^ ((lrow & 7) << 4);
        aW[kk] = *reinterpret_cast<const bf16x8*>(reinterpret_cast<const char*>(As) + off);
    }
    #pragma unroll
    for (int kk = 0; kk < 2; ++kk) {
        int off = (lrow * 128 + (kk * 32 + kg * 8) * 2) ^ ((lrow & 7) << 4);
        aN[kk] = *reinterpret_cast<const bf16x8*>(reinterpret_cast<const char*>(Ns) + off);
    }
    f32x4 acc[8];
    #pragma unroll
    for (int nt = 0; nt < 8; ++nt) { acc[nt][0]=0.f; acc[nt][1]=0.f; acc[nt][2]=0.f; acc[nt][3]=0.f; }
    #pragma unroll
    for (int nt = 0; nt < 8; ++nt) {
        #pragma unroll
        for (int kk = 0; kk < 4; ++kk) {
            bf16x8 b = *reinterpret_cast<const bf16x8*>(&WoT[(nt * 16 + l15) * HD + kk * 32 + kg * 8]);
            acc[nt] = __builtin_amdgcn_mfma_f32_16x16x32_bf16(aW[kk], b, acc[nt], 0, 0, 0);
        }
        #pragma unroll
        for (int kk = 0; kk < 2; ++kk) {
            bf16x8 b = *reinterpret_cast<const bf16x8*>(&WeT[(nt * 16 + l15) * ND + kk * 32 + kg * 8]);
            acc[nt] = __builtin_amdgcn_mfma_f32_16x16x32_bf16(aN[kk], b, acc[nt], 0, 0, 0);
        }
    }
    #pragma unroll
    for (int nt = 0; nt < 8; ++nt) {
        int gcol = nt * 16 + l15;
        float bsum = bo[gcol] + be[gcol];
        #pragma unroll
        for (int i = 0; i < 4; ++i) {
            int grow = rbase + rt + kg * 4 + i;
            eout[(size_t)grow * HD + gcol] = acc[nt][i] + bsum;
        }
    }
}

// ---------------------------------------------------------------------------
extern "C" void kernel_launch(void* const* d_in, const int* in_sizes, int n_in,
                              void* d_out, int out_size, void* d_ws, size_t ws_size,
                              hipStream_t stream)
{
    const float* feat     = (const float*)d_in[0];
    const int*   eidx     = (const int*)d_in[1];
    const float* noise    = (const float*)d_in[2];
    const float* time_emb = (const float*)d_in[3];
    const int*   batch    = (const int*)d_in[4];
    const float* We = (const float*)d_in[5],  *be = (const float*)d_in[6];
    const float* Wp = (const float*)d_in[7],  *bp = (const float*)d_in[8];
    const float* Wq = (const float*)d_in[9],  *bq = (const float*)d_in[10];
    const float* Wr = (const float*)d_in[11], *br = (const float*)d_in[12];
    const float* Wu = (const float*)d_in[13], *bu = (const float*)d_in[14];
    const float* Wv = (const float*)d_in[15], *bv = (const float*)d_in[16];
    const float* gnh_w = (const float*)d_in[17], *gnh_b = (const float*)d_in[18], *gnh_ms = (const float*)d_in[19];
    const float* gne_w = (const float*)d_in[20], *gne_b = (const float*)d_in[21], *gne_ms = (const float*)d_in[22];
    const float* Wt = (const float*)d_in[23], *bt = (const float*)d_in[24];
    const float* ln_w = (const float*)d_in[25], *ln_b = (const float*)d_in[26];
    const float* Wo = (const float*)d_in[27], *bo = (const float*)d_in[28];

    const int* srcArr = eidx;
    const int* dstArr = eidx + NE;

    float* hout = (float*)d_out;                    // [N,H] f32 — holds fu32, then x, then h
    float* eout = hout + (size_t)NN * HD;           // [E,H] f32 — final e

    char* ws = (char*)d_ws;
    size_t off = 0;
    auto take = [&](size_t bytes) -> char* {
        char* p = ws + off;
        off = (off + bytes + 255) & ~(size_t)255;
        return p;
    };
    u16* ehat = (u16*)take((size_t)NE * HD * 2);    // 102.4 MB
    u16* fq = (u16*)take((size_t)NN * HD * 2);      // 12.8 MB
    u16* fr = (u16*)take((size_t)NN * HD * 2);
    u16* fv = (u16*)take((size_t)NN * HD * 2);
    u8*  g8 = (u8*)take((size_t)NE);
    u32* deg  = (u32*)take((size_t)2 * NN * 4);     // deg[NN] + cnt2[NN], one memset
    u32* cnt2 = deg + NN;
    int* start = (int*)take((size_t)(NN + 1) * 4);
    int* perm  = (int*)take((size_t)NE * 4);
    float* Wep = (float*)take((size_t)ND * HD * 4);
    float* bep = (float*)take((size_t)HD * 4);
    u16* WqT = (u16*)take((size_t)HD * HD * 2);     // transposed bf16 weights
    u16* WrT = (u16*)take((size_t)HD * HD * 2);
    u16* WvT = (u16*)take((size_t)HD * HD * 2);
    u16* WuT = (u16*)take((size_t)HD * HD * 2);
    u16* WoT = (u16*)take((size_t)HD * HD * 2);
    u16* WepT = (u16*)take((size_t)HD * ND * 2);
    u16* WeT  = (u16*)take((size_t)HD * ND * 2);
    float* statsH = (float*)take((size_t)PSTRIDE * 4);
    float* statsE = (float*)take((size_t)PSTRIDE * 4);
    float* tproj  = (float*)take((size_t)GG * HD * 4);
    float* off_h  = (float*)take((size_t)GG * HD * 4);
    float* istd_h = (float*)take((size_t)GG * HD * 4);
    float* off_e  = (float*)take((size_t)GG * HD * 4);
    float* istd_e = (float*)take((size_t)GG * HD * 4);
    float* epart  = (float*)take((size_t)EP * PSTRIDE * 4);   // 4.5 MB
    float* hpart  = (float*)take((size_t)HP * PSTRIDE * 4);   // 4.5 MB
    float* etmp   = (float*)take((size_t)8 * PSTRIDE * 4);
    float* htmp   = (float*)take((size_t)8 * PSTRIDE * 4);
    // total ~152.9 MB — below known-good 153.7 MB (R1)

    hipMemsetAsync(deg, 0, (size_t)2 * NN * 4, stream);

    wep_kernel<<<16, 256, 0, stream>>>(We, Wp, be, bp, Wep, bep);
    prep_kernel<<<64, 256, 0, stream>>>(Wq, WqT, HD);
    prep_kernel<<<64, 256, 0, stream>>>(Wr, WrT, HD);
    prep_kernel<<<64, 256, 0, stream>>>(Wv, WvT, HD);
    prep_kernel<<<64, 256, 0, stream>>>(Wu, WuT, HD);
    prep_kernel<<<64, 256, 0, stream>>>(Wo, WoT, HD);
    prep_kernel<<<32, 256, 0, stream>>>(Wep, WepT, ND);
    prep_kernel<<<32, 256, 0, stream>>>(We, WeT, ND);
    hist_kernel<<<(NE + 255) / 256, 256, 0, stream>>>(srcArr, batch, deg, g8);
    scan_kernel<<<1, 1024, 0, stream>>>(deg, start);
    scatter_kernel<<<(NE + 255) / 256, 256, 0, stream>>>(srcArr, start, cnt2, perm);
    proj4_kernel<<<(NN + ETILE - 1) / ETILE, 256, 0, stream>>>(
        feat, WqT, WrT, WvT, WuT, bq, br, bv, bu, fq, fr, fv, hout);
    ehat_kernel<<<NE / ETILE, 256, 0, stream>>>(noise, WepT, bep, fq, fr, srcArr, dstArr, ehat);
    aggr_kernel<<<2048, 256, 0, stream>>>(ehat, fv, dstArr, start, perm, hout);
    hstats_part_kernel<<<HP, 256, 0, stream>>>(hout, batch, hpart);
    estats_part_kernel<<<EP, 512, 0, stream>>>(ehat, g8, epart);
    {
        dim3 gA((SLEN + 255) / 256, 8);
        reduce_part_kernel<<<gA, 256, 0, stream>>>(hpart, HP, HP / 8, htmp);
        reduce_part_kernel<<<gA, 256, 0, stream>>>(epart, EP, EP / 8, etmp);
        dim3 gB((SLEN + 255) / 256, 1);
        reduce_part_kernel<<<gB, 256, 0, stream>>>(htmp, 8, 8, statsH);
        reduce_part_kernel<<<gB, 256, 0, stream>>>(etmp, 8, 8, statsE);
    }
    tproj_kernel<<<1, 256, 0, stream>>>(time_emb, Wt, bt, tproj);
    finstats_kernel<<<1, 256, 0, stream>>>(statsH, statsE, gnh_ms, gne_ms,
                                           off_h, istd_h, off_e, istd_e);
    hfinal_kernel<<<(NN * HD / 4 + 255) / 256, 256, 0, stream>>>(feat, batch, off_h, istd_h,
                                                                 gnh_w, gnh_b, hout);
    efinal_kernel<<<NE / ETILE, 256, 0, stream>>>(ehat, g8, noise, WoT, WeT, be, bo,
                                                  off_e, istd_e, gne_w, gne_b, tproj,
                                                  ln_w, ln_b, eout);
}

// Round 7
// 1060.011 us; speedup vs baseline: 1.7764x; 1.0121x over previous
//
#include <hip/hip_runtime.h>

#define NN 50000
#define NE 400000
#define HD 128
#define ND 64
#define GG 16
#define EPSV 1e-5f
#define ETILE 64

#define SLEN (2 * GG * HD + GG)   // 4112 floats: [sum 2048 | sumsq 2048 | cnt 16]
#define PSTRIDE 4352              // partial-set stride (floats), non-pow2
#define EP 256                    // estats stage-1 blocks
#define HP 256                    // hstats stage-1 blocks

typedef unsigned short u16;
typedef unsigned int   u32;
typedef unsigned char  u8;
typedef __attribute__((__ext_vector_type__(8))) __bf16 bf16x8;
typedef __attribute__((__ext_vector_type__(4))) float  f32x4;

__device__ __forceinline__ float us2f(u16 u) { return __uint_as_float(((u32)u) << 16); }
__device__ __forceinline__ u16 f2us(float f) {
    u32 u = __float_as_uint(f);
    u += 0x7fffu + ((u >> 16) & 1u);   // RNE
    return (u16)(u >> 16);
}
__device__ __forceinline__ float sigmoidf_(float x) { return 1.f / (1.f + __expf(-x)); }

// accumulate x into register-resident per-graph slots via wave-uniform scalar switch
#define ACC_CASE(G) case G: s[G] += x; z[G] = fmaf(x, x, z[G]); cn[G] += cinc; break;
#define ACC_SWITCH(g) switch (g) { \
    ACC_CASE(0) ACC_CASE(1) ACC_CASE(2) ACC_CASE(3) ACC_CASE(4) ACC_CASE(5) \
    ACC_CASE(6) ACC_CASE(7) ACC_CASE(8) ACC_CASE(9) ACC_CASE(10) ACC_CASE(11) \
    ACC_CASE(12) ACC_CASE(13) ACC_CASE(14) ACC_CASE(15) default: break; }

// ---------------------------------------------------------------------------
// K0a: Wep = We @ Wp  [64x128], bep = be @ Wp + bp   (grid=16, Wp in LDS)
// ---------------------------------------------------------------------------
__global__ __launch_bounds__(256) void wep_kernel(
    const float* __restrict__ We, const float* __restrict__ Wp,
    const float* __restrict__ be, const float* __restrict__ bp,
    float* __restrict__ Wep, float* __restrict__ bep)
{
    __shared__ float wp[HD][HD];      // 64 KB
    const int t = threadIdx.x;
    for (int i = t; i < HD * HD; i += 256) wp[i >> 7][i & 127] = Wp[i];
    __syncthreads();
    const int c = t & 127;
    for (int r = blockIdx.x * 4 + (t >> 7); r < (blockIdx.x + 1) * 4 && r < ND; r += 2) {
        float a = 0.f;
        for (int k = 0; k < HD; ++k) a = fmaf(We[r * HD + k], wp[k][c], a);
        Wep[r * HD + c] = a;
    }
    if (blockIdx.x == 0 && t < HD) {
        float a = bp[t];
        for (int k = 0; k < HD; ++k) a = fmaf(be[k], wp[k][t], a);
        bep[t] = a;
    }
}

// ---------------------------------------------------------------------------
// K0e: transpose f32 [K][128] -> bf16 [128][K]  (B-operand layout for MFMA)
// ---------------------------------------------------------------------------
__global__ __launch_bounds__(256) void prep_kernel(
    const float* __restrict__ in, u16* __restrict__ out, int K)
{
    int idx = blockIdx.x * 256 + threadIdx.x;
    if (idx >= K * HD) return;
    int k = idx >> 7, n = idx & 127;
    out[n * K + k] = f2us(in[idx]);
}

// ---------------------------------------------------------------------------
// K0b: degree histogram + g8[e] = batch[src[e]]
// ---------------------------------------------------------------------------
__global__ __launch_bounds__(256) void hist_kernel(
    const int* __restrict__ srcArr, const int* __restrict__ batch,
    u32* __restrict__ deg, u8* __restrict__ g8)
{
    int e = blockIdx.x * 256 + threadIdx.x;
    if (e >= NE) return;
    int s = srcArr[e];
    atomicAdd(&deg[s], 1u);
    g8[e] = (u8)batch[s];
}

// ---------------------------------------------------------------------------
// K0c: exclusive prefix sum of deg[NN] -> start[NN+1]   (1 block, 1024 thr)
// ---------------------------------------------------------------------------
#define SCAN_C 49   // 1024*49 = 50176 >= NN
__global__ __launch_bounds__(1024) void scan_kernel(
    const u32* __restrict__ deg, int* __restrict__ start)
{
    __shared__ u32 sums[1024];
    const int t = threadIdx.x;
    const int i0 = t * SCAN_C;
    u32 tot = 0;
    for (int j = 0; j < SCAN_C; ++j) { int i = i0 + j; if (i < NN) tot += deg[i]; }
    sums[t] = tot;
    __syncthreads();
    for (int off = 1; off < 1024; off <<= 1) {
        u32 v = (t >= off) ? sums[t - off] : 0u;
        __syncthreads();
        sums[t] += v;
        __syncthreads();
    }
    u32 run = (t == 0) ? 0u : sums[t - 1];
    for (int j = 0; j < SCAN_C; ++j) {
        int i = i0 + j;
        if (i < NN) { start[i] = (int)run; run += deg[i]; }
    }
    if (t == 1023) start[NN] = (int)run;   // == NE
}

// ---------------------------------------------------------------------------
// K0d: scatter edge ids into CSR order
// ---------------------------------------------------------------------------
__global__ __launch_bounds__(256) void scatter_kernel(
    const int* __restrict__ srcArr, const int* __restrict__ start,
    u32* __restrict__ cnt2, int* __restrict__ perm)
{
    int e = blockIdx.x * 256 + threadIdx.x;
    if (e >= NE) return;
    int s = srcArr[e];
    u32 pos = atomicAdd(&cnt2[s], 1u);
    perm[start[s] + pos] = e;
}

// ---------------------------------------------------------------------------
// K1: MFMA: fq/fr/fv = feat @ {Wq,Wr,Wv} + b (bf16); fu32 = feat@Wu + bu (f32)
//     64 rows/block, 4 waves x 16-row stripes, A staged bf16 swizzled in LDS.
// ---------------------------------------------------------------------------
__global__ __launch_bounds__(256) void proj4_kernel(
    const float* __restrict__ feat,
    const u16* __restrict__ WqT, const u16* __restrict__ WrT,
    const u16* __restrict__ WvT, const u16* __restrict__ WuT,
    const float* __restrict__ bq, const float* __restrict__ br,
    const float* __restrict__ bv, const float* __restrict__ bu,
    u16* __restrict__ fq, u16* __restrict__ fr, u16* __restrict__ fv,
    float* __restrict__ fu32)
{
    __shared__ __align__(16) u16 As[ETILE * HD];   // 16 KB, XOR-swizzled
    const int t = threadIdx.x;
    const int rbase = blockIdx.x * ETILE;
    #pragma unroll
    for (int i = 0; i < 16; ++i) {
        int idx2 = t + i * 256;            // bf16-pair index
        int row = idx2 >> 6, p = idx2 & 63;
        int grow = rbase + row;
        float2 v = make_float2(0.f, 0.f);
        if (grow < NN) v = *reinterpret_cast<const float2*>(&feat[(size_t)grow * HD + p * 2]);
        u32 pk = (u32)f2us(v.x) | ((u32)f2us(v.y) << 16);
        int off = (row * 256 + p * 4) ^ ((row & 7) << 4);
        *reinterpret_cast<u32*>(reinterpret_cast<char*>(As) + off) = pk;
    }
    __syncthreads();
    const int w = t >> 6, lane = t & 63;
    const int rt = w * 16, l15 = lane & 15, kg = lane >> 4;
    const int lrow = rt + l15;
    bf16x8 afr[4];
    #pragma unroll
    for (int kk = 0; kk < 4; ++kk) {
        int off = (lrow * 256 + (kk * 32 + kg * 8) * 2) ^ ((lrow & 7) << 4);
        afr[kk] = *reinterpret_cast<const bf16x8*>(reinterpret_cast<const char*>(As) + off);
    }
    const u16* WTs[4] = {WqT, WrT, WvT, WuT};
    const float* Bs2[4] = {bq, br, bv, bu};
    u16* Os[3] = {fq, fr, fv};
    #pragma unroll
    for (int m = 0; m < 4; ++m) {
        f32x4 acc[8];
        #pragma unroll
        for (int nt = 0; nt < 8; ++nt) { acc[nt][0]=0.f; acc[nt][1]=0.f; acc[nt][2]=0.f; acc[nt][3]=0.f; }
        const u16* W = WTs[m];
        #pragma unroll
        for (int nt = 0; nt < 8; ++nt) {
            #pragma unroll
            for (int kk = 0; kk < 4; ++kk) {
                bf16x8 b = *reinterpret_cast<const bf16x8*>(&W[(nt * 16 + l15) * HD + kk * 32 + kg * 8]);
                acc[nt] = __builtin_amdgcn_mfma_f32_16x16x32_bf16(afr[kk], b, acc[nt], 0, 0, 0);
            }
        }
        #pragma unroll
        for (int nt = 0; nt < 8; ++nt) {
            int gcol = nt * 16 + l15;
            float bias = Bs2[m][gcol];
            #pragma unroll
            for (int i = 0; i < 4; ++i) {
                int grow = rbase + rt + kg * 4 + i;
                if (grow < NN) {
                    float v = acc[nt][i] + bias;
                    if (m < 3) Os[m][(size_t)grow * HD + gcol] = f2us(v);
                    else       fu32[(size_t)grow * HD + gcol] = v;
                }
            }
        }
    }
}

// ---------------------------------------------------------------------------
// K3: MFMA: e_hat = noise@Wep + bep + fq[src] + fr[dst]  (K=64, bf16 out)
// ---------------------------------------------------------------------------
__global__ __launch_bounds__(256) void ehat_kernel(
    const float* __restrict__ noise, const u16* __restrict__ WepT,
    const float* __restrict__ bep,
    const u16* __restrict__ fq, const u16* __restrict__ fr,
    const int* __restrict__ srcArr, const int* __restrict__ dstArr,
    u16* __restrict__ ehat)
{
    __shared__ __align__(16) u16 Ns[ETILE * ND];   // 8 KB, XOR-swizzled
    const int t = threadIdx.x;
    const int rbase = blockIdx.x * ETILE;
    #pragma unroll
    for (int i = 0; i < 8; ++i) {
        int idx2 = t + i * 256;
        int row = idx2 >> 5, p = idx2 & 31;
        float2 v = *reinterpret_cast<const float2*>(&noise[(size_t)(rbase + row) * ND + p * 2]);
        u32 pk = (u32)f2us(v.x) | ((u32)f2us(v.y) << 16);
        int off = (row * 128 + p * 4) ^ ((row & 7) << 4);
        *reinterpret_cast<u32*>(reinterpret_cast<char*>(Ns) + off) = pk;
    }
    __syncthreads();
    const int w = t >> 6, lane = t & 63;
    const int rt = w * 16, l15 = lane & 15, kg = lane >> 4;
    const int lrow = rt + l15;
    bf16x8 afr[2];
    #pragma unroll
    for (int kk = 0; kk < 2; ++kk) {
        int off = (lrow * 128 + (kk * 32 + kg * 8) * 2) ^ ((lrow & 7) << 4);
        afr[kk] = *reinterpret_cast<const bf16x8*>(reinterpret_cast<const char*>(Ns) + off);
    }
    f32x4 acc[8];
    #pragma unroll
    for (int nt = 0; nt < 8; ++nt) { acc[nt][0]=0.f; acc[nt][1]=0.f; acc[nt][2]=0.f; acc[nt][3]=0.f; }
    float bepv[8];
    #pragma unroll
    for (int nt = 0; nt < 8; ++nt) {
        bepv[nt] = bep[nt * 16 + l15];
        #pragma unroll
        for (int kk = 0; kk < 2; ++kk) {
            bf16x8 b = *reinterpret_cast<const bf16x8*>(&WepT[(nt * 16 + l15) * ND + kk * 32 + kg * 8]);
            acc[nt] = __builtin_amdgcn_mfma_f32_16x16x32_bf16(afr[kk], b, acc[nt], 0, 0, 0);
        }
    }
    #pragma unroll
    for (int i = 0; i < 4; ++i) {
        int grow = rbase + rt + kg * 4 + i;
        int s = srcArr[grow], d = dstArr[grow];
        #pragma unroll
        for (int nt = 0; nt < 8; ++nt) {
            int gcol = nt * 16 + l15;
            float v = acc[nt][i] + bepv[nt]
                    + us2f(fq[(size_t)s * HD + gcol]) + us2f(fr[(size_t)d * HD + gcol]);
            ehat[(size_t)grow * HD + gcol] = f2us(v);
        }
    }
}

// ---------------------------------------------------------------------------
// K3b: x[node] = fu32[node] + sum_{e in CSR(node)} sigmoid(ehat[e]) * fv[dst[e]]
// ---------------------------------------------------------------------------
__global__ __launch_bounds__(256) void aggr_kernel(
    const u16* __restrict__ ehat, const u16* __restrict__ fv,
    const int* __restrict__ dstArr, const int* __restrict__ start,
    const int* __restrict__ perm, float* __restrict__ xout)
{
    const int w = threadIdx.x >> 6, lane = threadIdx.x & 63;
    const int c0 = lane * 2;
    for (int node = blockIdx.x * 4 + w; node < NN; node += gridDim.x * 4) {
        int s0 = start[node], s1 = start[node + 1];
        float2 uv = *reinterpret_cast<const float2*>(&xout[(size_t)node * HD + c0]);
        float a0 = 0.f, a1 = 0.f;
        for (int j = s0; j < s1; ++j) {
            int e = perm[j];
            int d = dstArr[e];
            u32 ev = *reinterpret_cast<const u32*>(&ehat[(size_t)e * HD + c0]);
            u32 vv = *reinterpret_cast<const u32*>(&fv[(size_t)d * HD + c0]);
            a0 = fmaf(sigmoidf_(us2f((u16)ev)),         us2f((u16)vv),         a0);
            a1 = fmaf(sigmoidf_(us2f((u16)(ev >> 16))), us2f((u16)(vv >> 16)), a1);
        }
        *reinterpret_cast<float2*>(&xout[(size_t)node * HD + c0]) =
            make_float2(a0 + uv.x, a1 + uv.y);
    }
}

// ---------------------------------------------------------------------------
// K4: per-graph sum/sumsq of x (batch sorted -> register accum, no atomics)
// ---------------------------------------------------------------------------
__global__ __launch_bounds__(256) void hstats_part_kernel(
    const float* __restrict__ xout, const int* __restrict__ batch,
    float* __restrict__ hpart)
{
    __shared__ float sm[2 * GG * HD];
    __shared__ float smc[2 * GG];
    const int t = threadIdx.x;
    const int c = t & 127, half = t >> 7;
    const int chunk = (NN + HP - 1) / HP;
    const int rstart = blockIdx.x * chunk;
    const int rend = min(NN, rstart + chunk);
    const float cinc = (c == 0) ? 1.f : 0.f;
    float s[GG], z[GG], cn[GG];
    #pragma unroll
    for (int g = 0; g < GG; ++g) { s[g] = 0.f; z[g] = 0.f; cn[g] = 0.f; }
    for (int row = rstart + half; row < rend; row += 2) {
        int g = __builtin_amdgcn_readfirstlane(batch[row]);
        float x = xout[(size_t)row * HD + c];
        ACC_SWITCH(g)
    }
    #pragma unroll
    for (int g = 0; g < GG; ++g) sm[(half * GG + g) * HD + c] = s[g];
    if (c == 0) {
        #pragma unroll
        for (int g = 0; g < GG; ++g) smc[half * GG + g] = cn[g];
    }
    __syncthreads();
    float* dst = hpart + (size_t)blockIdx.x * PSTRIDE;
    for (int j = t; j < GG * HD; j += 256) dst[j] = sm[j] + sm[GG * HD + j];
    if (t < GG) dst[2 * GG * HD + t] = smc[t] + smc[GG + t];
    __syncthreads();
    #pragma unroll
    for (int g = 0; g < GG; ++g) sm[(half * GG + g) * HD + c] = z[g];
    __syncthreads();
    for (int j = t; j < GG * HD; j += 256) dst[GG * HD + j] = sm[j] + sm[GG * HD + j];
}

// ---------------------------------------------------------------------------
// K5: per-graph sum/sumsq of e_hat (g = g8[e], wave-uniform)
// ---------------------------------------------------------------------------
__global__ __launch_bounds__(512) void estats_part_kernel(
    const u16* __restrict__ ehat, const u8* __restrict__ g8,
    float* __restrict__ epart)
{
    __shared__ float sm[4 * GG * HD];
    __shared__ float smc[4 * GG];
    const int t = threadIdx.x;
    const int c = t & 127, q = t >> 7;
    const int chunk = (NE + EP - 1) / EP;
    const int rstart = blockIdx.x * chunk;
    const int rend = min(NE, rstart + chunk);
    const float cinc = (c == 0) ? 1.f : 0.f;
    float s[GG], z[GG], cn[GG];
    #pragma unroll
    for (int g = 0; g < GG; ++g) { s[g] = 0.f; z[g] = 0.f; cn[g] = 0.f; }
    for (int row = rstart + q; row < rend; row += 4) {
        int g = __builtin_amdgcn_readfirstlane((int)g8[row]);
        float x = us2f(ehat[(size_t)row * HD + c]);
        ACC_SWITCH(g)
    }
    #pragma unroll
    for (int g = 0; g < GG; ++g) sm[(q * GG + g) * HD + c] = s[g];
    if (c == 0) {
        #pragma unroll
        for (int g = 0; g < GG; ++g) smc[q * GG + g] = cn[g];
    }
    __syncthreads();
    float* dst = epart + (size_t)blockIdx.x * PSTRIDE;
    for (int j = t; j < GG * HD; j += 512)
        dst[j] = sm[j] + sm[2048 + j] + sm[4096 + j] + sm[6144 + j];
    if (t < GG) dst[2 * GG * HD + t] = smc[t] + smc[GG + t] + smc[2 * GG + t] + smc[3 * GG + t];
    __syncthreads();
    #pragma unroll
    for (int g = 0; g < GG; ++g) sm[(q * GG + g) * HD + c] = z[g];
    __syncthreads();
    for (int j = t; j < GG * HD; j += 512)
        dst[GG * HD + j] = sm[j] + sm[2048 + j] + sm[4096 + j] + sm[6144 + j];
}

// ---------------------------------------------------------------------------
// K5b: chunked partial-slice reduce
// ---------------------------------------------------------------------------
__global__ __launch_bounds__(256) void reduce_part_kernel(
    const float* __restrict__ part, int P, int csz, float* __restrict__ out)
{
    int j = blockIdx.x * 256 + threadIdx.x;
    if (j >= SLEN) return;
    int p0 = blockIdx.y * csz;
    int p1 = min(P, p0 + csz);
    float a = 0.f;
    for (int p = p0; p < p1; ++p) a += part[(size_t)p * PSTRIDE + j];
    out[(size_t)blockIdx.y * PSTRIDE + j] = a;
}

// ---------------------------------------------------------------------------
// K6: stats -> (off = mean*ms, istd)
// ---------------------------------------------------------------------------
__global__ __launch_bounds__(256) void finstats_kernel(
    const float* __restrict__ statsH, const float* __restrict__ statsE,
    const float* __restrict__ gnh_ms, const float* __restrict__ gne_ms,
    float* off_h, float* istd_h, float* off_e, float* istd_e)
{
    for (int i = threadIdx.x; i < GG * HD; i += 256) {
        int g = i >> 7, c = i & 127;
        {
            float cnt = fmaxf(statsH[4096 + g], 1.f);
            float mean = statsH[i] / cnt;
            float ex2 = statsH[2048 + i] / cnt;
            float off = mean * gnh_ms[c];
            float var = ex2 - 2.f * off * mean + off * off;
            off_h[i] = off;
            istd_h[i] = rsqrtf(var + EPSV);
        }
        {
            float cnt = fmaxf(statsE[4096 + g], 1.f);
            float mean = statsE[i] / cnt;
            float ex2 = statsE[2048 + i] / cnt;
            float off = mean * gne_ms[c];
            float var = ex2 - 2.f * off * mean + off * off;
            off_e[i] = off;
            istd_e[i] = rsqrtf(var + EPSV);
        }
    }
}

// ---------------------------------------------------------------------------
// K7: tproj = relu(time_emb) @ Wt + bt   [16 x 128]
// ---------------------------------------------------------------------------
__global__ __launch_bounds__(256) void tproj_kernel(
    const float* __restrict__ time_emb, const float* __restrict__ Wt,
    const float* __restrict__ bt, float* __restrict__ tproj)
{
    __shared__ float te[GG][HD];
    const int t = threadIdx.x;
    for (int i = t; i < GG * HD; i += 256) te[i >> 7][i & 127] = fmaxf(time_emb[i], 0.f);
    __syncthreads();
    const int c = t & 127, rb = t >> 7;
    float acc[8];
    #pragma unroll
    for (int j = 0; j < 8; ++j) acc[j] = 0.f;
    for (int k = 0; k < HD; ++k) {
        float wv = Wt[k * HD + c];
        #pragma unroll
        for (int j = 0; j < 8; ++j) acc[j] = fmaf(te[rb + 2 * j][k], wv, acc[j]);
    }
    float b = bt[c];
    #pragma unroll
    for (int j = 0; j < 8; ++j) tproj[(rb + 2 * j) * HD + c] = acc[j] + b;
}

// ---------------------------------------------------------------------------
// K8: h = features + relu(graphnorm_h(x));  x lives in hout (in-place)
// ---------------------------------------------------------------------------
__global__ __launch_bounds__(256) void hfinal_kernel(
    const float* __restrict__ feat, const int* __restrict__ batch,
    const float* __restrict__ off_h, const float* __restrict__ istd_h,
    const float* __restrict__ gnh_w, const float* __restrict__ gnh_b,
    float* hout_x)
{
    int i = blockIdx.x * 256 + threadIdx.x;
    size_t base = (size_t)i * 4;
    if (base >= (size_t)NN * HD) return;
    int row = (int)(base >> 7), c0 = (int)(base & 127);
    int g = batch[row];
    float4 fe = *reinterpret_cast<const float4*>(&feat[base]);
    float4 xv = *reinterpret_cast<const float4*>(&hout_x[base]);
    float4 ou;
    float* op = &ou.x;
    const float* fp = &fe.x;
    const float* xp = &xv.x;
    #pragma unroll
    for (int j = 0; j < 4; ++j) {
        int idx = g * HD + c0 + j;
        float out = xp[j] - off_h[idx];
        float v = gnh_w[c0 + j] * out * istd_h[idx] + gnh_b[c0 + j];
        op[j] = fp[j] + fmaxf(v, 0.f);
    }
    *reinterpret_cast<float4*>(&hout_x[base]) = ou;
}

// ---------------------------------------------------------------------------
// K9: MFMA: e = noise@We + be + silu(LN(relu(gn_e(ehat)) + tproj[g8])) @ Wo + bo
//     Zero LDS. Each lane computes its MFMA A-fragment elements directly:
//     lane (l15,kg) owns row rt+l15, cols kk*32+kg*8+j. Row LN reduction =
//     2 shuffles across the 4 lanes sharing a row (xor 16, 32).
// ---------------------------------------------------------------------------
__global__ __launch_bounds__(256) void efinal_kernel(
    const u16* __restrict__ ehat, const u8* __restrict__ g8,
    const float* __restrict__ noise,
    const u16* __restrict__ WoT, const u16* __restrict__ WeT,
    const float* __restrict__ be, const float* __restrict__ bo,
    const float* __restrict__ off_e, const float* __restrict__ istd_e,
    const float* __restrict__ gne_w, const float* __restrict__ gne_b,
    const float* __restrict__ tproj,
    const float* __restrict__ ln_w, const float* __restrict__ ln_b,
    float* __restrict__ eout)
{
    const int t = threadIdx.x;
    const int rbase = blockIdx.x * ETILE;
    const int w = t >> 6, lane = t & 63;
    const int l15 = lane & 15, kg = lane >> 4;
    const int rt = w * 16;
    const int e = rbase + rt + l15;        // this lane's edge row (= A-frag row)
    const int g = g8[e];

    // phase 1: GN + relu + tproj for this lane's 32 fragment cols
    float v[4][8];
    float lsum = 0.f;
    #pragma unroll
    for (int kk = 0; kk < 4; ++kk) {
        const int c = kk * 32 + kg * 8;
        uint4 ev = *reinterpret_cast<const uint4*>(&ehat[(size_t)e * HD + c]);
        const u32 wds[4] = {ev.x, ev.y, ev.z, ev.w};
        #pragma unroll
        for (int p = 0; p < 4; ++p) {
            const int c2 = c + p * 2;
            float x0 = us2f((u16)wds[p]);
            float x1 = us2f((u16)(wds[p] >> 16));
            float2 gw = *reinterpret_cast<const float2*>(&gne_w[c2]);
            float2 gb = *reinterpret_cast<const float2*>(&gne_b[c2]);
            float2 of = *reinterpret_cast<const float2*>(&off_e[g * HD + c2]);
            float2 is = *reinterpret_cast<const float2*>(&istd_e[g * HD + c2]);
            float2 tp = *reinterpret_cast<const float2*>(&tproj[g * HD + c2]);
            float a0 = fmaxf(gw.x * (x0 - of.x) * is.x + gb.x, 0.f) + tp.x;
            float a1 = fmaxf(gw.y * (x1 - of.y) * is.y + gb.y, 0.f) + tp.y;
            v[kk][p * 2]     = a0;
            v[kk][p * 2 + 1] = a1;
            lsum += a0 + a1;
        }
    }
    // row reduction across 4 lanes sharing this row (kg = 0..3)
    lsum += __shfl_xor(lsum, 16, 64);
    lsum += __shfl_xor(lsum, 32, 64);
    float mu = lsum * (1.f / 128.f);
    float sq = 0.f;
    #pragma unroll
    for (int kk = 0; kk < 4; ++kk)
        #pragma unroll
        for (int j = 0; j < 8; ++j) { float d = v[kk][j] - mu; sq = fmaf(d, d, sq); }
    sq += __shfl_xor(sq, 16, 64);
    sq += __shfl_xor(sq, 32, 64);
    float rstd = rsqrtf(sq * (1.f / 128.f) + EPSV);

    // LN scale + silu -> bf16 A-fragments (in registers, A-frag layout)
    u32 aw[4][4];
    #pragma unroll
    for (int kk = 0; kk < 4; ++kk) {
        const int c = kk * 32 + kg * 8;
        #pragma unroll
        for (int p = 0; p < 4; ++p) {
            const int c2 = c + p * 2;
            float2 lw = *reinterpret_cast<const float2*>(&ln_w[c2]);
            float2 lb = *reinterpret_cast<const float2*>(&ln_b[c2]);
            float l0 = (v[kk][p * 2]     - mu) * rstd * lw.x + lb.x;
            float l1 = (v[kk][p * 2 + 1] - mu) * rstd * lw.y + lb.y;
            float s0 = l0 * sigmoidf_(l0);
            float s1 = l1 * sigmoidf_(l1);
            aw[kk][p] = (u32)f2us(s0) | ((u32)f2us(s1) << 16);
        }
    }
    // noise A-fragments direct from global (f32 -> bf16 in-register)
    u32 an[2][4];
    #pragma unroll
    for (int kk = 0; kk < 2; ++kk) {
        const int c = kk * 32 + kg * 8;
        float4 n0 = *reinterpret_cast<const float4*>(&noise[(size_t)e * ND + c]);
        float4 n1 = *reinterpret_cast<const float4*>(&noise[(size_t)e * ND + c + 4]);
        an[kk][0] = (u32)f2us(n0.x) | ((u32)f2us(n0.y) << 16);
        an[kk][1] = (u32)f2us(n0.z) | ((u32)f2us(n0.w) << 16);
        an[kk][2] = (u32)f2us(n1.x) | ((u32)f2us(n1.y) << 16);
        an[kk][3] = (u32)f2us(n1.z) | ((u32)f2us(n1.w) << 16);
    }

    // phase 2: MFMA (acc = silu@WoT + noise@WeT)
    f32x4 acc[8];
    #pragma unroll
    for (int nt = 0; nt < 8; ++nt) { acc[nt][0]=0.f; acc[nt][1]=0.f; acc[nt][2]=0.f; acc[nt][3]=0.f; }
    #pragma unroll
    for (int nt = 0; nt < 8; ++nt) {
        #pragma unroll
        for (int kk = 0; kk < 4; ++kk) {
            bf16x8 b = *reinterpret_cast<const bf16x8*>(&WoT[(nt * 16 + l15) * HD + kk * 32 + kg * 8]);
            acc[nt] = __builtin_amdgcn_mfma_f32_16x16x32_bf16(
                *reinterpret_cast<const bf16x8*>(aw[kk]), b, acc[nt], 0, 0, 0);
        }
        #pragma unroll
        for (int kk = 0; kk < 2; ++kk) {
            bf16x8 b = *reinterpret_cast<const bf16x8*>(&WeT[(nt * 16 + l15) * ND + kk * 32 + kg * 8]);
            acc[nt] = __builtin_amdgcn_mfma_f32_16x16x32_bf16(
                *reinterpret_cast<const bf16x8*>(an[kk]), b, acc[nt], 0, 0, 0);
        }
    }
    #pragma unroll
    for (int nt = 0; nt < 8; ++nt) {
        int gcol = nt * 16 + l15;
        float bsum = bo[gcol] + be[gcol];
        #pragma unroll
        for (int i = 0; i < 4; ++i) {
            int grow = rbase + rt + kg * 4 + i;
            eout[(size_t)grow * HD + gcol] = acc[nt][i] + bsum;
        }
    }
}

// ---------------------------------------------------------------------------
extern "C" void kernel_launch(void* const* d_in, const int* in_sizes, int n_in,
                              void* d_out, int out_size, void* d_ws, size_t ws_size,
                              hipStream_t stream)
{
    const float* feat     = (const float*)d_in[0];
    const int*   eidx     = (const int*)d_in[1];
    const float* noise    = (const float*)d_in[2];
    const float* time_emb = (const float*)d_in[3];
    const int*   batch    = (const int*)d_in[4];
    const float* We = (const float*)d_in[5],  *be = (const float*)d_in[6];
    const float* Wp = (const float*)d_in[7],  *bp = (const float*)d_in[8];
    const float* Wq = (const float*)d_in[9],  *bq = (const float*)d_in[10];
    const float* Wr = (const float*)d_in[11], *br = (const float*)d_in[12];
    const float* Wu = (const float*)d_in[13], *bu = (const float*)d_in[14];
    const float* Wv = (const float*)d_in[15], *bv = (const float*)d_in[16];
    const float* gnh_w = (const float*)d_in[17], *gnh_b = (const float*)d_in[18], *gnh_ms = (const float*)d_in[19];
    const float* gne_w = (const float*)d_in[20], *gne_b = (const float*)d_in[21], *gne_ms = (const float*)d_in[22];
    const float* Wt = (const float*)d_in[23], *bt = (const float*)d_in[24];
    const float* ln_w = (const float*)d_in[25], *ln_b = (const float*)d_in[26];
    const float* Wo = (const float*)d_in[27], *bo = (const float*)d_in[28];

    const int* srcArr = eidx;
    const int* dstArr = eidx + NE;

    float* hout = (float*)d_out;                    // [N,H] f32 — holds fu32, then x, then h
    float* eout = hout + (size_t)NN * HD;           // [E,H] f32 — final e

    char* ws = (char*)d_ws;
    size_t off = 0;
    auto take = [&](size_t bytes) -> char* {
        char* p = ws + off;
        off = (off + bytes + 255) & ~(size_t)255;
        return p;
    };
    u16* ehat = (u16*)take((size_t)NE * HD * 2);    // 102.4 MB
    u16* fq = (u16*)take((size_t)NN * HD * 2);      // 12.8 MB
    u16* fr = (u16*)take((size_t)NN * HD * 2);
    u16* fv = (u16*)take((size_t)NN * HD * 2);
    u8*  g8 = (u8*)take((size_t)NE);
    u32* deg  = (u32*)take((size_t)2 * NN * 4);     // deg[NN] + cnt2[NN], one memset
    u32* cnt2 = deg + NN;
    int* start = (int*)take((size_t)(NN + 1) * 4);
    int* perm  = (int*)take((size_t)NE * 4);
    float* Wep = (float*)take((size_t)ND * HD * 4);
    float* bep = (float*)take((size_t)HD * 4);
    u16* WqT = (u16*)take((size_t)HD * HD * 2);     // transposed bf16 weights
    u16* WrT = (u16*)take((size_t)HD * HD * 2);
    u16* WvT = (u16*)take((size_t)HD * HD * 2);
    u16* WuT = (u16*)take((size_t)HD * HD * 2);
    u16* WoT = (u16*)take((size_t)HD * HD * 2);
    u16* WepT = (u16*)take((size_t)HD * ND * 2);
    u16* WeT  = (u16*)take((size_t)HD * ND * 2);
    float* statsH = (float*)take((size_t)PSTRIDE * 4);
    float* statsE = (float*)take((size_t)PSTRIDE * 4);
    float* tproj  = (float*)take((size_t)GG * HD * 4);
    float* off_h  = (float*)take((size_t)GG * HD * 4);
    float* istd_h = (float*)take((size_t)GG * HD * 4);
    float* off_e  = (float*)take((size_t)GG * HD * 4);
    float* istd_e = (float*)take((size_t)GG * HD * 4);
    float* epart  = (float*)take((size_t)EP * PSTRIDE * 4);   // 4.5 MB
    float* hpart  = (float*)take((size_t)HP * PSTRIDE * 4);   // 4.5 MB
    float* etmp   = (float*)take((size_t)8 * PSTRIDE * 4);
    float* htmp   = (float*)take((size_t)8 * PSTRIDE * 4);
    // total ~152.9 MB — below known-good 153.7 MB (R1)

    hipMemsetAsync(deg, 0, (size_t)2 * NN * 4, stream);

    wep_kernel<<<16, 256, 0, stream>>>(We, Wp, be, bp, Wep, bep);
    prep_kernel<<<64, 256, 0, stream>>>(Wq, WqT, HD);
    prep_kernel<<<64, 256, 0, stream>>>(Wr, WrT, HD);
    prep_kernel<<<64, 256, 0, stream>>>(Wv, WvT, HD);
    prep_kernel<<<64, 256, 0, stream>>>(Wu, WuT, HD);
    prep_kernel<<<64, 256, 0, stream>>>(Wo, WoT, HD);
    prep_kernel<<<32, 256, 0, stream>>>(Wep, WepT, ND);
    prep_kernel<<<32, 256, 0, stream>>>(We, WeT, ND);
    hist_kernel<<<(NE + 255) / 256, 256, 0, stream>>>(srcArr, batch, deg, g8);
    scan_kernel<<<1, 1024, 0, stream>>>(deg, start);
    scatter_kernel<<<(NE + 255) / 256, 256, 0, stream>>>(srcArr, start, cnt2, perm);
    proj4_kernel<<<(NN + ETILE - 1) / ETILE, 256, 0, stream>>>(
        feat, WqT, WrT, WvT, WuT, bq, br, bv, bu, fq, fr, fv, hout);
    ehat_kernel<<<NE / ETILE, 256, 0, stream>>>(noise, WepT, bep, fq, fr, srcArr, dstArr, ehat);
    aggr_kernel<<<2048, 256, 0, stream>>>(ehat, fv, dstArr, start, perm, hout);
    hstats_part_kernel<<<HP, 256, 0, stream>>>(hout, batch, hpart);
    estats_part_kernel<<<EP, 512, 0, stream>>>(ehat, g8, epart);
    {
        dim3 gA((SLEN + 255) / 256, 8);
        reduce_part_kernel<<<gA, 256, 0, stream>>>(hpart, HP, HP / 8, htmp);
        reduce_part_kernel<<<gA, 256, 0, stream>>>(epart, EP, EP / 8, etmp);
        dim3 gB((SLEN + 255) / 256, 1);
        reduce_part_kernel<<<gB, 256, 0, stream>>>(htmp, 8, 8, statsH);
        reduce_part_kernel<<<gB, 256, 0, stream>>>(etmp, 8, 8, statsE);
    }
    tproj_kernel<<<1, 256, 0, stream>>>(time_emb, Wt, bt, tproj);
    finstats_kernel<<<1, 256, 0, stream>>>(statsH, statsE, gnh_ms, gne_ms,
                                           off_h, istd_h, off_e, istd_e);
    hfinal_kernel<<<(NN * HD / 4 + 255) / 256, 256, 0, stream>>>(feat, batch, off_h, istd_h,
                                                                 gnh_w, gnh_b, hout);
    efinal_kernel<<<NE / ETILE, 256, 0, stream>>>(ehat, g8, noise, WoT, WeT, be, bo,
                                                  off_e, istd_e, gne_w, gne_b, tproj,
                                                  ln_w, ln_b, eout);
}

// Round 8
// 1008.429 us; speedup vs baseline: 1.8673x; 1.0512x over previous
//
#include <hip/hip_runtime.h>

#define NN 50000
#define NE 400000
#define HD 128
#define ND 64
#define GG 16
#define EPSV 1e-5f
#define ETILE 64
#define ETILE2 128

#define SLEN (2 * GG * HD + GG)   // 4112 floats: [sum 2048 | sumsq 2048 | cnt 16]
#define PSTRIDE 4352              // partial-set stride (floats), non-pow2
#define EP 256                    // estats stage-1 blocks
#define HP 256                    // hstats stage-1 blocks

typedef unsigned short u16;
typedef unsigned int   u32;
typedef unsigned char  u8;
typedef __attribute__((__ext_vector_type__(8))) __bf16 bf16x8;
typedef __attribute__((__ext_vector_type__(4))) float  f32x4;

__device__ __forceinline__ float us2f(u16 u) { return __uint_as_float(((u32)u) << 16); }
__device__ __forceinline__ u16 f2us(float f) {
    u32 u = __float_as_uint(f);
    u += 0x7fffu + ((u >> 16) & 1u);   // RNE
    return (u16)(u >> 16);
}
__device__ __forceinline__ float sigmoidf_(float x) { return 1.f / (1.f + __expf(-x)); }

// accumulate x into register-resident per-graph slots via wave-uniform scalar switch
#define ACC_CASE(G) case G: s[G] += x; z[G] = fmaf(x, x, z[G]); cn[G] += cinc; break;
#define ACC_SWITCH(g) switch (g) { \
    ACC_CASE(0) ACC_CASE(1) ACC_CASE(2) ACC_CASE(3) ACC_CASE(4) ACC_CASE(5) \
    ACC_CASE(6) ACC_CASE(7) ACC_CASE(8) ACC_CASE(9) ACC_CASE(10) ACC_CASE(11) \
    ACC_CASE(12) ACC_CASE(13) ACC_CASE(14) ACC_CASE(15) default: break; }

// ---------------------------------------------------------------------------
// K0a: Wep = We @ Wp  [64x128], bep = be @ Wp + bp   (grid=16, Wp in LDS)
// ---------------------------------------------------------------------------
__global__ __launch_bounds__(256) void wep_kernel(
    const float* __restrict__ We, const float* __restrict__ Wp,
    const float* __restrict__ be, const float* __restrict__ bp,
    float* __restrict__ Wep, float* __restrict__ bep)
{
    __shared__ float wp[HD][HD];      // 64 KB
    const int t = threadIdx.x;
    for (int i = t; i < HD * HD; i += 256) wp[i >> 7][i & 127] = Wp[i];
    __syncthreads();
    const int c = t & 127;
    for (int r = blockIdx.x * 4 + (t >> 7); r < (blockIdx.x + 1) * 4 && r < ND; r += 2) {
        float a = 0.f;
        for (int k = 0; k < HD; ++k) a = fmaf(We[r * HD + k], wp[k][c], a);
        Wep[r * HD + c] = a;
    }
    if (blockIdx.x == 0 && t < HD) {
        float a = bp[t];
        for (int k = 0; k < HD; ++k) a = fmaf(be[k], wp[k][t], a);
        bep[t] = a;
    }
}

// ---------------------------------------------------------------------------
// K0e: all weight transposes in ONE launch. grid=(64,7).
//      y: 0..4 -> K=HD {Wq,Wr,Wv,Wu,Wo}; 5,6 -> K=ND {Wep,We}
// ---------------------------------------------------------------------------
__global__ __launch_bounds__(256) void prep_all_kernel(
    const float* __restrict__ Wq, const float* __restrict__ Wr,
    const float* __restrict__ Wv, const float* __restrict__ Wu,
    const float* __restrict__ Wo, const float* __restrict__ Wep,
    const float* __restrict__ We,
    u16* __restrict__ WqT, u16* __restrict__ WrT, u16* __restrict__ WvT,
    u16* __restrict__ WuT, u16* __restrict__ WoT, u16* __restrict__ WepT,
    u16* __restrict__ WeT)
{
    const float* in; u16* out; int K;
    switch (blockIdx.y) {
        case 0: in = Wq;  out = WqT;  K = HD; break;
        case 1: in = Wr;  out = WrT;  K = HD; break;
        case 2: in = Wv;  out = WvT;  K = HD; break;
        case 3: in = Wu;  out = WuT;  K = HD; break;
        case 4: in = Wo;  out = WoT;  K = HD; break;
        case 5: in = Wep; out = WepT; K = ND; break;
        default: in = We; out = WeT;  K = ND; break;
    }
    int idx = blockIdx.x * 256 + threadIdx.x;
    if (idx >= K * HD) return;
    int k = idx >> 7, n = idx & 127;
    out[n * K + k] = f2us(in[idx]);
}

// ---------------------------------------------------------------------------
// K0b: degree histogram + g8[e] = batch[src[e]]
// ---------------------------------------------------------------------------
__global__ __launch_bounds__(256) void hist_kernel(
    const int* __restrict__ srcArr, const int* __restrict__ batch,
    u32* __restrict__ deg, u8* __restrict__ g8)
{
    int e = blockIdx.x * 256 + threadIdx.x;
    if (e >= NE) return;
    int s = srcArr[e];
    atomicAdd(&deg[s], 1u);
    g8[e] = (u8)batch[s];
}

// ---------------------------------------------------------------------------
// K0c: exclusive prefix sum of deg[NN] -> start[NN+1]   (1 block, 1024 thr)
// ---------------------------------------------------------------------------
#define SCAN_C 49   // 1024*49 = 50176 >= NN
__global__ __launch_bounds__(1024) void scan_kernel(
    const u32* __restrict__ deg, int* __restrict__ start)
{
    __shared__ u32 sums[1024];
    const int t = threadIdx.x;
    const int i0 = t * SCAN_C;
    u32 tot = 0;
    for (int j = 0; j < SCAN_C; ++j) { int i = i0 + j; if (i < NN) tot += deg[i]; }
    sums[t] = tot;
    __syncthreads();
    for (int off = 1; off < 1024; off <<= 1) {
        u32 v = (t >= off) ? sums[t - off] : 0u;
        __syncthreads();
        sums[t] += v;
        __syncthreads();
    }
    u32 run = (t == 0) ? 0u : sums[t - 1];
    for (int j = 0; j < SCAN_C; ++j) {
        int i = i0 + j;
        if (i < NN) { start[i] = (int)run; run += deg[i]; }
    }
    if (t == 1023) start[NN] = (int)run;   // == NE
}

// ---------------------------------------------------------------------------
// K0d: scatter edge ids into CSR order
// ---------------------------------------------------------------------------
__global__ __launch_bounds__(256) void scatter_kernel(
    const int* __restrict__ srcArr, const int* __restrict__ start,
    u32* __restrict__ cnt2, int* __restrict__ perm)
{
    int e = blockIdx.x * 256 + threadIdx.x;
    if (e >= NE) return;
    int s = srcArr[e];
    u32 pos = atomicAdd(&cnt2[s], 1u);
    perm[start[s] + pos] = e;
}

// ---------------------------------------------------------------------------
// K1: MFMA: fq/fr/fv = feat @ {Wq,Wr,Wv} + b (bf16); fu32 = feat@Wu + bu (f32)
// ---------------------------------------------------------------------------
__global__ __launch_bounds__(256) void proj4_kernel(
    const float* __restrict__ feat,
    const u16* __restrict__ WqT, const u16* __restrict__ WrT,
    const u16* __restrict__ WvT, const u16* __restrict__ WuT,
    const float* __restrict__ bq, const float* __restrict__ br,
    const float* __restrict__ bv, const float* __restrict__ bu,
    u16* __restrict__ fq, u16* __restrict__ fr, u16* __restrict__ fv,
    float* __restrict__ fu32)
{
    __shared__ __align__(16) u16 As[ETILE * HD];   // 16 KB, XOR-swizzled
    const int t = threadIdx.x;
    const int rbase = blockIdx.x * ETILE;
    #pragma unroll
    for (int i = 0; i < 16; ++i) {
        int idx2 = t + i * 256;            // bf16-pair index
        int row = idx2 >> 6, p = idx2 & 63;
        int grow = rbase + row;
        float2 v = make_float2(0.f, 0.f);
        if (grow < NN) v = *reinterpret_cast<const float2*>(&feat[(size_t)grow * HD + p * 2]);
        u32 pk = (u32)f2us(v.x) | ((u32)f2us(v.y) << 16);
        int off = (row * 256 + p * 4) ^ ((row & 7) << 4);
        *reinterpret_cast<u32*>(reinterpret_cast<char*>(As) + off) = pk;
    }
    __syncthreads();
    const int w = t >> 6, lane = t & 63;
    const int rt = w * 16, l15 = lane & 15, kg = lane >> 4;
    const int lrow = rt + l15;
    bf16x8 afr[4];
    #pragma unroll
    for (int kk = 0; kk < 4; ++kk) {
        int off = (lrow * 256 + (kk * 32 + kg * 8) * 2) ^ ((lrow & 7) << 4);
        afr[kk] = *reinterpret_cast<const bf16x8*>(reinterpret_cast<const char*>(As) + off);
    }
    const u16* WTs[4] = {WqT, WrT, WvT, WuT};
    const float* Bs2[4] = {bq, br, bv, bu};
    u16* Os[3] = {fq, fr, fv};
    #pragma unroll
    for (int m = 0; m < 4; ++m) {
        f32x4 acc[8];
        #pragma unroll
        for (int nt = 0; nt < 8; ++nt) { acc[nt][0]=0.f; acc[nt][1]=0.f; acc[nt][2]=0.f; acc[nt][3]=0.f; }
        const u16* W = WTs[m];
        #pragma unroll
        for (int nt = 0; nt < 8; ++nt) {
            #pragma unroll
            for (int kk = 0; kk < 4; ++kk) {
                bf16x8 b = *reinterpret_cast<const bf16x8*>(&W[(nt * 16 + l15) * HD + kk * 32 + kg * 8]);
                acc[nt] = __builtin_amdgcn_mfma_f32_16x16x32_bf16(afr[kk], b, acc[nt], 0, 0, 0);
            }
        }
        #pragma unroll
        for (int nt = 0; nt < 8; ++nt) {
            int gcol = nt * 16 + l15;
            float bias = Bs2[m][gcol];
            #pragma unroll
            for (int i = 0; i < 4; ++i) {
                int grow = rbase + rt + kg * 4 + i;
                if (grow < NN) {
                    float v = acc[nt][i] + bias;
                    if (m < 3) Os[m][(size_t)grow * HD + gcol] = f2us(v);
                    else       fu32[(size_t)grow * HD + gcol] = v;
                }
            }
        }
    }
}

// ---------------------------------------------------------------------------
// K3: MFMA: e_hat = noise@Wep + bep + fq[src] + fr[dst]  (K=64, bf16 out)
// ---------------------------------------------------------------------------
__global__ __launch_bounds__(256) void ehat_kernel(
    const float* __restrict__ noise, const u16* __restrict__ WepT,
    const float* __restrict__ bep,
    const u16* __restrict__ fq, const u16* __restrict__ fr,
    const int* __restrict__ srcArr, const int* __restrict__ dstArr,
    u16* __restrict__ ehat)
{
    __shared__ __align__(16) u16 Ns[ETILE * ND];   // 8 KB, XOR-swizzled
    const int t = threadIdx.x;
    const int rbase = blockIdx.x * ETILE;
    #pragma unroll
    for (int i = 0; i < 8; ++i) {
        int idx2 = t + i * 256;
        int row = idx2 >> 5, p = idx2 & 31;
        float2 v = *reinterpret_cast<const float2*>(&noise[(size_t)(rbase + row) * ND + p * 2]);
        u32 pk = (u32)f2us(v.x) | ((u32)f2us(v.y) << 16);
        int off = (row * 128 + p * 4) ^ ((row & 7) << 4);
        *reinterpret_cast<u32*>(reinterpret_cast<char*>(Ns) + off) = pk;
    }
    __syncthreads();
    const int w = t >> 6, lane = t & 63;
    const int rt = w * 16, l15 = lane & 15, kg = lane >> 4;
    const int lrow = rt + l15;
    bf16x8 afr[2];
    #pragma unroll
    for (int kk = 0; kk < 2; ++kk) {
        int off = (lrow * 128 + (kk * 32 + kg * 8) * 2) ^ ((lrow & 7) << 4);
        afr[kk] = *reinterpret_cast<const bf16x8*>(reinterpret_cast<const char*>(Ns) + off);
    }
    f32x4 acc[8];
    #pragma unroll
    for (int nt = 0; nt < 8; ++nt) { acc[nt][0]=0.f; acc[nt][1]=0.f; acc[nt][2]=0.f; acc[nt][3]=0.f; }
    float bepv[8];
    #pragma unroll
    for (int nt = 0; nt < 8; ++nt) {
        bepv[nt] = bep[nt * 16 + l15];
        #pragma unroll
        for (int kk = 0; kk < 2; ++kk) {
            bf16x8 b = *reinterpret_cast<const bf16x8*>(&WepT[(nt * 16 + l15) * ND + kk * 32 + kg * 8]);
            acc[nt] = __builtin_amdgcn_mfma_f32_16x16x32_bf16(afr[kk], b, acc[nt], 0, 0, 0);
        }
    }
    #pragma unroll
    for (int i = 0; i < 4; ++i) {
        int grow = rbase + rt + kg * 4 + i;
        int s = srcArr[grow], d = dstArr[grow];
        #pragma unroll
        for (int nt = 0; nt < 8; ++nt) {
            int gcol = nt * 16 + l15;
            float v = acc[nt][i] + bepv[nt]
                    + us2f(fq[(size_t)s * HD + gcol]) + us2f(fr[(size_t)d * HD + gcol]);
            ehat[(size_t)grow * HD + gcol] = f2us(v);
        }
    }
}

// ---------------------------------------------------------------------------
// K3b: x[node] = fu32[node] + sum_{e in CSR(node)} sigmoid(ehat[e]) * fv[dst[e]]
// ---------------------------------------------------------------------------
__global__ __launch_bounds__(256) void aggr_kernel(
    const u16* __restrict__ ehat, const u16* __restrict__ fv,
    const int* __restrict__ dstArr, const int* __restrict__ start,
    const int* __restrict__ perm, float* __restrict__ xout)
{
    const int w = threadIdx.x >> 6, lane = threadIdx.x & 63;
    const int c0 = lane * 2;
    for (int node = blockIdx.x * 4 + w; node < NN; node += gridDim.x * 4) {
        int s0 = start[node], s1 = start[node + 1];
        float2 uv = *reinterpret_cast<const float2*>(&xout[(size_t)node * HD + c0]);
        float a0 = 0.f, a1 = 0.f;
        for (int j = s0; j < s1; ++j) {
            int e = perm[j];
            int d = dstArr[e];
            u32 ev = *reinterpret_cast<const u32*>(&ehat[(size_t)e * HD + c0]);
            u32 vv = *reinterpret_cast<const u32*>(&fv[(size_t)d * HD + c0]);
            a0 = fmaf(sigmoidf_(us2f((u16)ev)),         us2f((u16)vv),         a0);
            a1 = fmaf(sigmoidf_(us2f((u16)(ev >> 16))), us2f((u16)(vv >> 16)), a1);
        }
        *reinterpret_cast<float2*>(&xout[(size_t)node * HD + c0]) =
            make_float2(a0 + uv.x, a1 + uv.y);
    }
}

// ---------------------------------------------------------------------------
// K4: per-graph sum/sumsq of x (batch sorted -> register accum, no atomics)
// ---------------------------------------------------------------------------
__global__ __launch_bounds__(256) void hstats_part_kernel(
    const float* __restrict__ xout, const int* __restrict__ batch,
    float* __restrict__ hpart)
{
    __shared__ float sm[2 * GG * HD];
    __shared__ float smc[2 * GG];
    const int t = threadIdx.x;
    const int c = t & 127, half = t >> 7;
    const int chunk = (NN + HP - 1) / HP;
    const int rstart = blockIdx.x * chunk;
    const int rend = min(NN, rstart + chunk);
    const float cinc = (c == 0) ? 1.f : 0.f;
    float s[GG], z[GG], cn[GG];
    #pragma unroll
    for (int g = 0; g < GG; ++g) { s[g] = 0.f; z[g] = 0.f; cn[g] = 0.f; }
    for (int row = rstart + half; row < rend; row += 2) {
        int g = __builtin_amdgcn_readfirstlane(batch[row]);
        float x = xout[(size_t)row * HD + c];
        ACC_SWITCH(g)
    }
    #pragma unroll
    for (int g = 0; g < GG; ++g) sm[(half * GG + g) * HD + c] = s[g];
    if (c == 0) {
        #pragma unroll
        for (int g = 0; g < GG; ++g) smc[half * GG + g] = cn[g];
    }
    __syncthreads();
    float* dst = hpart + (size_t)blockIdx.x * PSTRIDE;
    for (int j = t; j < GG * HD; j += 256) dst[j] = sm[j] + sm[GG * HD + j];
    if (t < GG) dst[2 * GG * HD + t] = smc[t] + smc[GG + t];
    __syncthreads();
    #pragma unroll
    for (int g = 0; g < GG; ++g) sm[(half * GG + g) * HD + c] = z[g];
    __syncthreads();
    for (int j = t; j < GG * HD; j += 256) dst[GG * HD + j] = sm[j] + sm[GG * HD + j];
}

// ---------------------------------------------------------------------------
// K5: per-graph sum/sumsq of e_hat (g = g8[e], wave-uniform)
// ---------------------------------------------------------------------------
__global__ __launch_bounds__(512) void estats_part_kernel(
    const u16* __restrict__ ehat, const u8* __restrict__ g8,
    float* __restrict__ epart)
{
    __shared__ float sm[4 * GG * HD];
    __shared__ float smc[4 * GG];
    const int t = threadIdx.x;
    const int c = t & 127, q = t >> 7;
    const int chunk = (NE + EP - 1) / EP;
    const int rstart = blockIdx.x * chunk;
    const int rend = min(NE, rstart + chunk);
    const float cinc = (c == 0) ? 1.f : 0.f;
    float s[GG], z[GG], cn[GG];
    #pragma unroll
    for (int g = 0; g < GG; ++g) { s[g] = 0.f; z[g] = 0.f; cn[g] = 0.f; }
    for (int row = rstart + q; row < rend; row += 4) {
        int g = __builtin_amdgcn_readfirstlane((int)g8[row]);
        float x = us2f(ehat[(size_t)row * HD + c]);
        ACC_SWITCH(g)
    }
    #pragma unroll
    for (int g = 0; g < GG; ++g) sm[(q * GG + g) * HD + c] = s[g];
    if (c == 0) {
        #pragma unroll
        for (int g = 0; g < GG; ++g) smc[q * GG + g] = cn[g];
    }
    __syncthreads();
    float* dst = epart + (size_t)blockIdx.x * PSTRIDE;
    for (int j = t; j < GG * HD; j += 512)
        dst[j] = sm[j] + sm[2048 + j] + sm[4096 + j] + sm[6144 + j];
    if (t < GG) dst[2 * GG * HD + t] = smc[t] + smc[GG + t] + smc[2 * GG + t] + smc[3 * GG + t];
    __syncthreads();
    #pragma unroll
    for (int g = 0; g < GG; ++g) sm[(q * GG + g) * HD + c] = z[g];
    __syncthreads();
    for (int j = t; j < GG * HD; j += 512)
        dst[GG * HD + j] = sm[j] + sm[2048 + j] + sm[4096 + j] + sm[6144 + j];
}

// ---------------------------------------------------------------------------
// K5b: chunked partial-slice reduce
// ---------------------------------------------------------------------------
__global__ __launch_bounds__(256) void reduce_part_kernel(
    const float* __restrict__ part, int P, int csz, float* __restrict__ out)
{
    int j = blockIdx.x * 256 + threadIdx.x;
    if (j >= SLEN) return;
    int p0 = blockIdx.y * csz;
    int p1 = min(P, p0 + csz);
    float a = 0.f;
    for (int p = p0; p < p1; ++p) a += part[(size_t)p * PSTRIDE + j];
    out[(size_t)blockIdx.y * PSTRIDE + j] = a;
}

// ---------------------------------------------------------------------------
// K6: stats -> packed scale/bias tables:
//     SB[g][c] = {S, B} interleaved; gn_relu(x) = max(S*x + B, 0)
// ---------------------------------------------------------------------------
__global__ __launch_bounds__(256) void finstats_kernel(
    const float* __restrict__ statsH, const float* __restrict__ statsE,
    const float* __restrict__ gnh_ms, const float* __restrict__ gne_ms,
    const float* __restrict__ gnh_w, const float* __restrict__ gnh_b,
    const float* __restrict__ gne_w, const float* __restrict__ gne_b,
    float* __restrict__ SBh, float* __restrict__ SBe)
{
    for (int i = threadIdx.x; i < GG * HD; i += 256) {
        int g = i >> 7, c = i & 127;
        {
            float cnt = fmaxf(statsH[4096 + g], 1.f);
            float mean = statsH[i] / cnt;
            float ex2 = statsH[2048 + i] / cnt;
            float off = mean * gnh_ms[c];
            float var = ex2 - 2.f * off * mean + off * off;
            float S = gnh_w[c] * rsqrtf(var + EPSV);
            SBh[2 * i]     = S;
            SBh[2 * i + 1] = gnh_b[c] - off * S;
        }
        {
            float cnt = fmaxf(statsE[4096 + g], 1.f);
            float mean = statsE[i] / cnt;
            float ex2 = statsE[2048 + i] / cnt;
            float off = mean * gne_ms[c];
            float var = ex2 - 2.f * off * mean + off * off;
            float S = gne_w[c] * rsqrtf(var + EPSV);
            SBe[2 * i]     = S;
            SBe[2 * i + 1] = gne_b[c] - off * S;
        }
    }
}

// ---------------------------------------------------------------------------
// K7: tproj = relu(time_emb) @ Wt + bt   [16 x 128]
// ---------------------------------------------------------------------------
__global__ __launch_bounds__(256) void tproj_kernel(
    const float* __restrict__ time_emb, const float* __restrict__ Wt,
    const float* __restrict__ bt, float* __restrict__ tproj)
{
    __shared__ float te[GG][HD];
    const int t = threadIdx.x;
    for (int i = t; i < GG * HD; i += 256) te[i >> 7][i & 127] = fmaxf(time_emb[i], 0.f);
    __syncthreads();
    const int c = t & 127, rb = t >> 7;
    float acc[8];
    #pragma unroll
    for (int j = 0; j < 8; ++j) acc[j] = 0.f;
    for (int k = 0; k < HD; ++k) {
        float wv = Wt[k * HD + c];
        #pragma unroll
        for (int j = 0; j < 8; ++j) acc[j] = fmaf(te[rb + 2 * j][k], wv, acc[j]);
    }
    float b = bt[c];
    #pragma unroll
    for (int j = 0; j < 8; ++j) tproj[(rb + 2 * j) * HD + c] = acc[j] + b;
}

// ---------------------------------------------------------------------------
// K8: h = features + max(S*x+B, 0);  x lives in hout (in-place)
// ---------------------------------------------------------------------------
__global__ __launch_bounds__(256) void hfinal_kernel(
    const float* __restrict__ feat, const int* __restrict__ batch,
    const float* __restrict__ SBh, float* hout_x)
{
    int i = blockIdx.x * 256 + threadIdx.x;
    size_t base = (size_t)i * 4;
    if (base >= (size_t)NN * HD) return;
    int row = (int)(base >> 7), c0 = (int)(base & 127);
    int g = batch[row];
    float4 fe = *reinterpret_cast<const float4*>(&feat[base]);
    float4 xv = *reinterpret_cast<const float4*>(&hout_x[base]);
    float4 sb0 = *reinterpret_cast<const float4*>(&SBh[(size_t)(g * HD + c0) * 2]);
    float4 sb1 = *reinterpret_cast<const float4*>(&SBh[(size_t)(g * HD + c0 + 2) * 2]);
    float4 ou;
    ou.x = fe.x + fmaxf(fmaf(xv.x, sb0.x, sb0.y), 0.f);
    ou.y = fe.y + fmaxf(fmaf(xv.y, sb0.z, sb0.w), 0.f);
    ou.z = fe.z + fmaxf(fmaf(xv.z, sb1.x, sb1.y), 0.f);
    ou.w = fe.w + fmaxf(fmaf(xv.w, sb1.z, sb1.w), 0.f);
    *reinterpret_cast<float4*>(&hout_x[base]) = ou;
}

// ---------------------------------------------------------------------------
// K9: MFMA: e = noise@We + be + silu(LN(max(S*ehat+B,0) + tproj[g])) @ Wo + bo
//     ETILE2=128 rows/block; each wave owns TWO 16-row A-tiles so every
//     B-fragment load feeds 2 MFMAs (halves weight traffic). Packed SB table
//     cuts phase-1 gathers ~2.3x. Bias preloaded into accumulator.
// ---------------------------------------------------------------------------
__global__ __launch_bounds__(256) void efinal_kernel(
    const u16* __restrict__ ehat, const u8* __restrict__ g8,
    const float* __restrict__ noise,
    const u16* __restrict__ WoT, const u16* __restrict__ WeT,
    const float* __restrict__ be, const float* __restrict__ bo,
    const float* __restrict__ SBe, const float* __restrict__ tproj,
    const float* __restrict__ ln_w, const float* __restrict__ ln_b,
    float* __restrict__ eout)
{
    const int t = threadIdx.x;
    const int rbase = blockIdx.x * ETILE2;
    const int w = t >> 6, lane = t & 63;
    const int l15 = lane & 15, kg = lane >> 4;
    const int rt = w * 32;

    u32 aw[2][4][4];
    u32 an[2][2][4];
    #pragma unroll
    for (int tile = 0; tile < 2; ++tile) {
        const int e = rbase + rt + tile * 16 + l15;
        const int g = g8[e];
        float v[4][8];
        float lsum = 0.f;
        #pragma unroll
        for (int kk = 0; kk < 4; ++kk) {
            const int c = kk * 32 + kg * 8;
            uint4 ev = *reinterpret_cast<const uint4*>(&ehat[(size_t)e * HD + c]);
            const u32 wds[4] = {ev.x, ev.y, ev.z, ev.w};
            #pragma unroll
            for (int p = 0; p < 4; ++p) {
                const int c2 = c + p * 2;
                float x0 = us2f((u16)wds[p]);
                float x1 = us2f((u16)(wds[p] >> 16));
                float4 sb = *reinterpret_cast<const float4*>(&SBe[(size_t)(g * HD + c2) * 2]);
                float2 tp = *reinterpret_cast<const float2*>(&tproj[g * HD + c2]);
                float a0 = fmaxf(fmaf(x0, sb.x, sb.y), 0.f) + tp.x;
                float a1 = fmaxf(fmaf(x1, sb.z, sb.w), 0.f) + tp.y;
                v[kk][p * 2]     = a0;
                v[kk][p * 2 + 1] = a1;
                lsum += a0 + a1;
            }
        }
        lsum += __shfl_xor(lsum, 16, 64);
        lsum += __shfl_xor(lsum, 32, 64);
        float mu = lsum * (1.f / 128.f);
        float sq = 0.f;
        #pragma unroll
        for (int kk = 0; kk < 4; ++kk)
            #pragma unroll
            for (int j = 0; j < 8; ++j) { float d = v[kk][j] - mu; sq = fmaf(d, d, sq); }
        sq += __shfl_xor(sq, 16, 64);
        sq += __shfl_xor(sq, 32, 64);
        float rstd = rsqrtf(sq * (1.f / 128.f) + EPSV);
        #pragma unroll
        for (int kk = 0; kk < 4; ++kk) {
            const int c = kk * 32 + kg * 8;
            #pragma unroll
            for (int p = 0; p < 4; ++p) {
                const int c2 = c + p * 2;
                float2 lw = *reinterpret_cast<const float2*>(&ln_w[c2]);
                float2 lb = *reinterpret_cast<const float2*>(&ln_b[c2]);
                float l0 = (v[kk][p * 2]     - mu) * rstd * lw.x + lb.x;
                float l1 = (v[kk][p * 2 + 1] - mu) * rstd * lw.y + lb.y;
                float s0 = l0 * sigmoidf_(l0);
                float s1 = l1 * sigmoidf_(l1);
                aw[tile][kk][p] = (u32)f2us(s0) | ((u32)f2us(s1) << 16);
            }
        }
        #pragma unroll
        for (int kk = 0; kk < 2; ++kk) {
            const int c = kk * 32 + kg * 8;
            float4 n0 = *reinterpret_cast<const float4*>(&noise[(size_t)e * ND + c]);
            float4 n1 = *reinterpret_cast<const float4*>(&noise[(size_t)e * ND + c + 4]);
            an[tile][kk][0] = (u32)f2us(n0.x) | ((u32)f2us(n0.y) << 16);
            an[tile][kk][1] = (u32)f2us(n0.z) | ((u32)f2us(n0.w) << 16);
            an[tile][kk][2] = (u32)f2us(n1.x) | ((u32)f2us(n1.y) << 16);
            an[tile][kk][3] = (u32)f2us(n1.z) | ((u32)f2us(n1.w) << 16);
        }
    }

    // MFMA: each B fragment feeds both row-tiles
    f32x4 acc[2][8];
    #pragma unroll
    for (int nt = 0; nt < 8; ++nt) {
        int gcol = nt * 16 + l15;
        float bsum = bo[gcol] + be[gcol];
        #pragma unroll
        for (int i = 0; i < 4; ++i) { acc[0][nt][i] = bsum; acc[1][nt][i] = bsum; }
    }
    #pragma unroll
    for (int nt = 0; nt < 8; ++nt) {
        #pragma unroll
        for (int kk = 0; kk < 4; ++kk) {
            bf16x8 b = *reinterpret_cast<const bf16x8*>(&WoT[(nt * 16 + l15) * HD + kk * 32 + kg * 8]);
            acc[0][nt] = __builtin_amdgcn_mfma_f32_16x16x32_bf16(
                *reinterpret_cast<const bf16x8*>(aw[0][kk]), b, acc[0][nt], 0, 0, 0);
            acc[1][nt] = __builtin_amdgcn_mfma_f32_16x16x32_bf16(
                *reinterpret_cast<const bf16x8*>(aw[1][kk]), b, acc[1][nt], 0, 0, 0);
        }
        #pragma unroll
        for (int kk = 0; kk < 2; ++kk) {
            bf16x8 b = *reinterpret_cast<const bf16x8*>(&WeT[(nt * 16 + l15) * ND + kk * 32 + kg * 8]);
            acc[0][nt] = __builtin_amdgcn_mfma_f32_16x16x32_bf16(
                *reinterpret_cast<const bf16x8*>(an[0][kk]), b, acc[0][nt], 0, 0, 0);
            acc[1][nt] = __builtin_amdgcn_mfma_f32_16x16x32_bf16(
                *reinterpret_cast<const bf16x8*>(an[1][kk]), b, acc[1][nt], 0, 0, 0);
        }
    }
    #pragma unroll
    for (int tile = 0; tile < 2; ++tile) {
        #pragma unroll
        for (int nt = 0; nt < 8; ++nt) {
            int gcol = nt * 16 + l15;
            #pragma unroll
            for (int i = 0; i < 4; ++i) {
                int grow = rbase + rt + tile * 16 + kg * 4 + i;
                eout[(size_t)grow * HD + gcol] = acc[tile][nt][i];
            }
        }
    }
}

// ---------------------------------------------------------------------------
extern "C" void kernel_launch(void* const* d_in, const int* in_sizes, int n_in,
                              void* d_out, int out_size, void* d_ws, size_t ws_size,
                              hipStream_t stream)
{
    const float* feat     = (const float*)d_in[0];
    const int*   eidx     = (const int*)d_in[1];
    const float* noise    = (const float*)d_in[2];
    const float* time_emb = (const float*)d_in[3];
    const int*   batch    = (const int*)d_in[4];
    const float* We = (const float*)d_in[5],  *be = (const float*)d_in[6];
    const float* Wp = (const float*)d_in[7],  *bp = (const float*)d_in[8];
    const float* Wq = (const float*)d_in[9],  *bq = (const float*)d_in[10];
    const float* Wr = (const float*)d_in[11], *br = (const float*)d_in[12];
    const float* Wu = (const float*)d_in[13], *bu = (const float*)d_in[14];
    const float* Wv = (const float*)d_in[15], *bv = (const float*)d_in[16];
    const float* gnh_w = (const float*)d_in[17], *gnh_b = (const float*)d_in[18], *gnh_ms = (const float*)d_in[19];
    const float* gne_w = (const float*)d_in[20], *gne_b = (const float*)d_in[21], *gne_ms = (const float*)d_in[22];
    const float* Wt = (const float*)d_in[23], *bt = (const float*)d_in[24];
    const float* ln_w = (const float*)d_in[25], *ln_b = (const float*)d_in[26];
    const float* Wo = (const float*)d_in[27], *bo = (const float*)d_in[28];

    const int* srcArr = eidx;
    const int* dstArr = eidx + NE;

    float* hout = (float*)d_out;                    // [N,H] f32 — holds fu32, then x, then h
    float* eout = hout + (size_t)NN * HD;           // [E,H] f32 — final e

    char* ws = (char*)d_ws;
    size_t off = 0;
    auto take = [&](size_t bytes) -> char* {
        char* p = ws + off;
        off = (off + bytes + 255) & ~(size_t)255;
        return p;
    };
    u16* ehat = (u16*)take((size_t)NE * HD * 2);    // 102.4 MB
    u16* fq = (u16*)take((size_t)NN * HD * 2);      // 12.8 MB
    u16* fr = (u16*)take((size_t)NN * HD * 2);
    u16* fv = (u16*)take((size_t)NN * HD * 2);
    u8*  g8 = (u8*)take((size_t)NE);
    u32* deg  = (u32*)take((size_t)2 * NN * 4);     // deg[NN] + cnt2[NN], one memset
    u32* cnt2 = deg + NN;
    int* start = (int*)take((size_t)(NN + 1) * 4);
    int* perm  = (int*)take((size_t)NE * 4);
    float* Wep = (float*)take((size_t)ND * HD * 4);
    float* bep = (float*)take((size_t)HD * 4);
    u16* WqT = (u16*)take((size_t)HD * HD * 2);     // transposed bf16 weights
    u16* WrT = (u16*)take((size_t)HD * HD * 2);
    u16* WvT = (u16*)take((size_t)HD * HD * 2);
    u16* WuT = (u16*)take((size_t)HD * HD * 2);
    u16* WoT = (u16*)take((size_t)HD * HD * 2);
    u16* WepT = (u16*)take((size_t)HD * ND * 2);
    u16* WeT  = (u16*)take((size_t)HD * ND * 2);
    float* statsH = (float*)take((size_t)PSTRIDE * 4);
    float* statsE = (float*)take((size_t)PSTRIDE * 4);
    float* tproj  = (float*)take((size_t)GG * HD * 4);
    float* SBh    = (float*)take((size_t)GG * HD * 8);   // {S,B} interleaved
    float* SBe    = (float*)take((size_t)GG * HD * 8);
    float* epart  = (float*)take((size_t)EP * PSTRIDE * 4);   // 4.5 MB
    float* hpart  = (float*)take((size_t)HP * PSTRIDE * 4);   // 4.5 MB
    float* etmp   = (float*)take((size_t)8 * PSTRIDE * 4);
    float* htmp   = (float*)take((size_t)8 * PSTRIDE * 4);
    // total ~152.9 MB — below known-good 153.7 MB (R1)

    hipMemsetAsync(deg, 0, (size_t)2 * NN * 4, stream);

    wep_kernel<<<16, 256, 0, stream>>>(We, Wp, be, bp, Wep, bep);
    prep_all_kernel<<<dim3(64, 7), 256, 0, stream>>>(Wq, Wr, Wv, Wu, Wo, Wep, We,
                                                     WqT, WrT, WvT, WuT, WoT, WepT, WeT);
    hist_kernel<<<(NE + 255) / 256, 256, 0, stream>>>(srcArr, batch, deg, g8);
    scan_kernel<<<1, 1024, 0, stream>>>(deg, start);
    scatter_kernel<<<(NE + 255) / 256, 256, 0, stream>>>(srcArr, start, cnt2, perm);
    proj4_kernel<<<(NN + ETILE - 1) / ETILE, 256, 0, stream>>>(
        feat, WqT, WrT, WvT, WuT, bq, br, bv, bu, fq, fr, fv, hout);
    ehat_kernel<<<NE / ETILE, 256, 0, stream>>>(noise, WepT, bep, fq, fr, srcArr, dstArr, ehat);
    aggr_kernel<<<2048, 256, 0, stream>>>(ehat, fv, dstArr, start, perm, hout);
    hstats_part_kernel<<<HP, 256, 0, stream>>>(hout, batch, hpart);
    estats_part_kernel<<<EP, 512, 0, stream>>>(ehat, g8, epart);
    {
        dim3 gA((SLEN + 255) / 256, 8);
        reduce_part_kernel<<<gA, 256, 0, stream>>>(hpart, HP, HP / 8, htmp);
        reduce_part_kernel<<<gA, 256, 0, stream>>>(epart, EP, EP / 8, etmp);
        dim3 gB((SLEN + 255) / 256, 1);
        reduce_part_kernel<<<gB, 256, 0, stream>>>(htmp, 8, 8, statsH);
        reduce_part_kernel<<<gB, 256, 0, stream>>>(etmp, 8, 8, statsE);
    }
    tproj_kernel<<<1, 256, 0, stream>>>(time_emb, Wt, bt, tproj);
    finstats_kernel<<<1, 256, 0, stream>>>(statsH, statsE, gnh_ms, gne_ms,
                                           gnh_w, gnh_b, gne_w, gne_b, SBh, SBe);
    hfinal_kernel<<<(NN * HD / 4 + 255) / 256, 256, 0, stream>>>(feat, batch, SBh, hout);
    efinal_kernel<<<NE / ETILE2, 256, 0, stream>>>(ehat, g8, noise, WoT, WeT, be, bo,
                                                   SBe, tproj, ln_w, ln_b, eout);
}

// Round 9
// 979.674 us; speedup vs baseline: 1.9221x; 1.0294x over previous
//
#include <hip/hip_runtime.h>

#define NN 50000
#define NE 400000
#define HD 128
#define ND 64
#define GG 16
#define EPSV 1e-5f
#define ETILE 64
#define ETILE2 128

#define SLEN (2 * GG * HD + GG)   // 4112 floats: [sum 2048 | sumsq 2048 | cnt 16]
#define PSTRIDE 4352              // partial-set stride (floats), non-pow2
#define EP 256                    // estats stage-1 blocks
#define HP 256                    // hstats stage-1 blocks

typedef unsigned short u16;
typedef unsigned int   u32;
typedef unsigned char  u8;
typedef __attribute__((__ext_vector_type__(8))) __bf16 bf16x8;
typedef __attribute__((__ext_vector_type__(4))) float  f32x4;

__device__ __forceinline__ float us2f(u16 u) { return __uint_as_float(((u32)u) << 16); }
__device__ __forceinline__ u16 f2us(float f) {
    u32 u = __float_as_uint(f);
    u += 0x7fffu + ((u >> 16) & 1u);   // RNE
    return (u16)(u >> 16);
}
__device__ __forceinline__ float sigmoidf_(float x) { return 1.f / (1.f + __expf(-x)); }

// accumulate x into register-resident per-graph slots via wave-uniform scalar switch
#define ACC_CASE(G) case G: s[G] += x; z[G] = fmaf(x, x, z[G]); cn[G] += cinc; break;
#define ACC_SWITCH(g) switch (g) { \
    ACC_CASE(0) ACC_CASE(1) ACC_CASE(2) ACC_CASE(3) ACC_CASE(4) ACC_CASE(5) \
    ACC_CASE(6) ACC_CASE(7) ACC_CASE(8) ACC_CASE(9) ACC_CASE(10) ACC_CASE(11) \
    ACC_CASE(12) ACC_CASE(13) ACC_CASE(14) ACC_CASE(15) default: break; }

// ---------------------------------------------------------------------------
// K0a: Wep = We @ Wp  [64x128], bep = be @ Wp + bp   (grid=16, Wp in LDS)
// ---------------------------------------------------------------------------
__global__ __launch_bounds__(256) void wep_kernel(
    const float* __restrict__ We, const float* __restrict__ Wp,
    const float* __restrict__ be, const float* __restrict__ bp,
    float* __restrict__ Wep, float* __restrict__ bep)
{
    __shared__ float wp[HD][HD];      // 64 KB
    const int t = threadIdx.x;
    for (int i = t; i < HD * HD; i += 256) wp[i >> 7][i & 127] = Wp[i];
    __syncthreads();
    const int c = t & 127;
    for (int r = blockIdx.x * 4 + (t >> 7); r < (blockIdx.x + 1) * 4 && r < ND; r += 2) {
        float a = 0.f;
        for (int k = 0; k < HD; ++k) a = fmaf(We[r * HD + k], wp[k][c], a);
        Wep[r * HD + c] = a;
    }
    if (blockIdx.x == 0 && t < HD) {
        float a = bp[t];
        for (int k = 0; k < HD; ++k) a = fmaf(be[k], wp[k][t], a);
        bep[t] = a;
    }
}

// ---------------------------------------------------------------------------
// K0e: all weight transposes in ONE launch. grid=(64,7).
// ---------------------------------------------------------------------------
__global__ __launch_bounds__(256) void prep_all_kernel(
    const float* __restrict__ Wq, const float* __restrict__ Wr,
    const float* __restrict__ Wv, const float* __restrict__ Wu,
    const float* __restrict__ Wo, const float* __restrict__ Wep,
    const float* __restrict__ We,
    u16* __restrict__ WqT, u16* __restrict__ WrT, u16* __restrict__ WvT,
    u16* __restrict__ WuT, u16* __restrict__ WoT, u16* __restrict__ WepT,
    u16* __restrict__ WeT)
{
    const float* in; u16* out; int K;
    switch (blockIdx.y) {
        case 0: in = Wq;  out = WqT;  K = HD; break;
        case 1: in = Wr;  out = WrT;  K = HD; break;
        case 2: in = Wv;  out = WvT;  K = HD; break;
        case 3: in = Wu;  out = WuT;  K = HD; break;
        case 4: in = Wo;  out = WoT;  K = HD; break;
        case 5: in = Wep; out = WepT; K = ND; break;
        default: in = We; out = WeT;  K = ND; break;
    }
    int idx = blockIdx.x * 256 + threadIdx.x;
    if (idx >= K * HD) return;
    int k = idx >> 7, n = idx & 127;
    out[n * K + k] = f2us(in[idx]);
}

// ---------------------------------------------------------------------------
// K0b: degree histogram
// ---------------------------------------------------------------------------
__global__ __launch_bounds__(256) void hist_kernel(
    const int* __restrict__ srcArr, u32* __restrict__ deg)
{
    int e = blockIdx.x * 256 + threadIdx.x;
    if (e >= NE) return;
    atomicAdd(&deg[srcArr[e]], 1u);
}

// ---------------------------------------------------------------------------
// K0c: exclusive prefix sum of deg[NN] -> start[NN+1]   (1 block, 1024 thr)
// ---------------------------------------------------------------------------
#define SCAN_C 49   // 1024*49 = 50176 >= NN
__global__ __launch_bounds__(1024) void scan_kernel(
    const u32* __restrict__ deg, int* __restrict__ start)
{
    __shared__ u32 sums[1024];
    const int t = threadIdx.x;
    const int i0 = t * SCAN_C;
    u32 tot = 0;
    for (int j = 0; j < SCAN_C; ++j) { int i = i0 + j; if (i < NN) tot += deg[i]; }
    sums[t] = tot;
    __syncthreads();
    for (int off = 1; off < 1024; off <<= 1) {
        u32 v = (t >= off) ? sums[t - off] : 0u;
        __syncthreads();
        sums[t] += v;
        __syncthreads();
    }
    u32 run = (t == 0) ? 0u : sums[t - 1];
    for (int j = 0; j < SCAN_C; ++j) {
        int i = i0 + j;
        if (i < NN) { start[i] = (int)run; run += deg[i]; }
    }
    if (t == 1023) start[NN] = (int)run;   // == NE
}

// ---------------------------------------------------------------------------
// K0d: scatter edges into CSR order + materialize src/dst/g8 in CSR order
// ---------------------------------------------------------------------------
__global__ __launch_bounds__(256) void scatter_kernel(
    const int* __restrict__ srcArr, const int* __restrict__ dstArr,
    const int* __restrict__ batch, const int* __restrict__ start,
    u32* __restrict__ cnt2, int* __restrict__ perm,
    int* __restrict__ src_csr, int* __restrict__ dst_csr,
    u8* __restrict__ g8csr)
{
    int e = blockIdx.x * 256 + threadIdx.x;
    if (e >= NE) return;
    int s = srcArr[e];
    u32 pos = atomicAdd(&cnt2[s], 1u);
    int j = start[s] + (int)pos;
    perm[j] = e;
    src_csr[j] = s;
    dst_csr[j] = dstArr[e];
    g8csr[j] = (u8)batch[s];
}

// ---------------------------------------------------------------------------
// K1: MFMA: fq/fr/fv = feat @ {Wq,Wr,Wv} + b (bf16); fu32 = feat@Wu + bu (f32)
// ---------------------------------------------------------------------------
__global__ __launch_bounds__(256) void proj4_kernel(
    const float* __restrict__ feat,
    const u16* __restrict__ WqT, const u16* __restrict__ WrT,
    const u16* __restrict__ WvT, const u16* __restrict__ WuT,
    const float* __restrict__ bq, const float* __restrict__ br,
    const float* __restrict__ bv, const float* __restrict__ bu,
    u16* __restrict__ fq, u16* __restrict__ fr, u16* __restrict__ fv,
    float* __restrict__ fu32)
{
    __shared__ __align__(16) u16 As[ETILE * HD];   // 16 KB, XOR-swizzled
    const int t = threadIdx.x;
    const int rbase = blockIdx.x * ETILE;
    #pragma unroll
    for (int i = 0; i < 16; ++i) {
        int idx2 = t + i * 256;            // bf16-pair index
        int row = idx2 >> 6, p = idx2 & 63;
        int grow = rbase + row;
        float2 v = make_float2(0.f, 0.f);
        if (grow < NN) v = *reinterpret_cast<const float2*>(&feat[(size_t)grow * HD + p * 2]);
        u32 pk = (u32)f2us(v.x) | ((u32)f2us(v.y) << 16);
        int off = (row * 256 + p * 4) ^ ((row & 7) << 4);
        *reinterpret_cast<u32*>(reinterpret_cast<char*>(As) + off) = pk;
    }
    __syncthreads();
    const int w = t >> 6, lane = t & 63;
    const int rt = w * 16, l15 = lane & 15, kg = lane >> 4;
    const int lrow = rt + l15;
    bf16x8 afr[4];
    #pragma unroll
    for (int kk = 0; kk < 4; ++kk) {
        int off = (lrow * 256 + (kk * 32 + kg * 8) * 2) ^ ((lrow & 7) << 4);
        afr[kk] = *reinterpret_cast<const bf16x8*>(reinterpret_cast<const char*>(As) + off);
    }
    const u16* WTs[4] = {WqT, WrT, WvT, WuT};
    const float* Bs2[4] = {bq, br, bv, bu};
    u16* Os[3] = {fq, fr, fv};
    #pragma unroll
    for (int m = 0; m < 4; ++m) {
        f32x4 acc[8];
        #pragma unroll
        for (int nt = 0; nt < 8; ++nt) { acc[nt][0]=0.f; acc[nt][1]=0.f; acc[nt][2]=0.f; acc[nt][3]=0.f; }
        const u16* W = WTs[m];
        #pragma unroll
        for (int nt = 0; nt < 8; ++nt) {
            #pragma unroll
            for (int kk = 0; kk < 4; ++kk) {
                bf16x8 b = *reinterpret_cast<const bf16x8*>(&W[(nt * 16 + l15) * HD + kk * 32 + kg * 8]);
                acc[nt] = __builtin_amdgcn_mfma_f32_16x16x32_bf16(afr[kk], b, acc[nt], 0, 0, 0);
            }
        }
        #pragma unroll
        for (int nt = 0; nt < 8; ++nt) {
            int gcol = nt * 16 + l15;
            float bias = Bs2[m][gcol];
            #pragma unroll
            for (int i = 0; i < 4; ++i) {
                int grow = rbase + rt + kg * 4 + i;
                if (grow < NN) {
                    float v = acc[nt][i] + bias;
                    if (m < 3) Os[m][(size_t)grow * HD + gcol] = f2us(v);
                    else       fu32[(size_t)grow * HD + gcol] = v;
                }
            }
        }
    }
}

// ---------------------------------------------------------------------------
// K3: MFMA (CSR order): ehat_csr[j] = noise[perm[j]]@Wep + bep
//                                   + fq[src_csr[j]] + fr[dst_csr[j]]
//     No LDS; per-lane A-fragment gather (row = one 256 B noise row).
// ---------------------------------------------------------------------------
__global__ __launch_bounds__(256) void ehat_kernel(
    const float* __restrict__ noise, const u16* __restrict__ WepT,
    const float* __restrict__ bep,
    const u16* __restrict__ fq, const u16* __restrict__ fr,
    const int* __restrict__ perm, const int* __restrict__ src_csr,
    const int* __restrict__ dst_csr,
    u16* __restrict__ ehat_csr)
{
    const int t = threadIdx.x;
    const int rbase = blockIdx.x * ETILE;
    const int w = t >> 6, lane = t & 63;
    const int rt = w * 16, l15 = lane & 15, kg = lane >> 4;
    const int jl = rbase + rt + l15;
    const int el = perm[jl];
    u32 an[2][4];
    #pragma unroll
    for (int kk = 0; kk < 2; ++kk) {
        const int c = kk * 32 + kg * 8;
        float4 n0 = *reinterpret_cast<const float4*>(&noise[(size_t)el * ND + c]);
        float4 n1 = *reinterpret_cast<const float4*>(&noise[(size_t)el * ND + c + 4]);
        an[kk][0] = (u32)f2us(n0.x) | ((u32)f2us(n0.y) << 16);
        an[kk][1] = (u32)f2us(n0.z) | ((u32)f2us(n0.w) << 16);
        an[kk][2] = (u32)f2us(n1.x) | ((u32)f2us(n1.y) << 16);
        an[kk][3] = (u32)f2us(n1.z) | ((u32)f2us(n1.w) << 16);
    }
    f32x4 acc[8];
    #pragma unroll
    for (int nt = 0; nt < 8; ++nt) {
        float b = bep[nt * 16 + l15];
        acc[nt][0] = b; acc[nt][1] = b; acc[nt][2] = b; acc[nt][3] = b;
    }
    #pragma unroll
    for (int nt = 0; nt < 8; ++nt) {
        #pragma unroll
        for (int kk = 0; kk < 2; ++kk) {
            bf16x8 b = *reinterpret_cast<const bf16x8*>(&WepT[(nt * 16 + l15) * ND + kk * 32 + kg * 8]);
            acc[nt] = __builtin_amdgcn_mfma_f32_16x16x32_bf16(
                *reinterpret_cast<const bf16x8*>(an[kk]), b, acc[nt], 0, 0, 0);
        }
    }
    #pragma unroll
    for (int i = 0; i < 4; ++i) {
        int jrow = rbase + rt + kg * 4 + i;
        int s = src_csr[jrow], d = dst_csr[jrow];
        #pragma unroll
        for (int nt = 0; nt < 8; ++nt) {
            int gcol = nt * 16 + l15;
            float v = acc[nt][i]
                    + us2f(fq[(size_t)s * HD + gcol]) + us2f(fr[(size_t)d * HD + gcol]);
            ehat_csr[(size_t)jrow * HD + gcol] = f2us(v);
        }
    }
}

// ---------------------------------------------------------------------------
// K3b: x[node] = fu32[node] + sum_{j in [start[n],start[n+1])}
//               sigmoid(ehat_csr[j]) * fv[dst_csr[j]]   — sequential ehat!
// ---------------------------------------------------------------------------
__global__ __launch_bounds__(256) void aggr_kernel(
    const u16* __restrict__ ehat_csr, const u16* __restrict__ fv,
    const int* __restrict__ dst_csr, const int* __restrict__ start,
    float* __restrict__ xout)
{
    const int w = threadIdx.x >> 6, lane = threadIdx.x & 63;
    const int c0 = lane * 2;
    for (int node = blockIdx.x * 4 + w; node < NN; node += gridDim.x * 4) {
        int s0 = start[node], s1 = start[node + 1];
        float2 uv = *reinterpret_cast<const float2*>(&xout[(size_t)node * HD + c0]);
        float a0 = 0.f, a1 = 0.f;
        for (int j = s0; j < s1; ++j) {
            int d = dst_csr[j];
            u32 ev = *reinterpret_cast<const u32*>(&ehat_csr[(size_t)j * HD + c0]);
            u32 vv = *reinterpret_cast<const u32*>(&fv[(size_t)d * HD + c0]);
            a0 = fmaf(sigmoidf_(us2f((u16)ev)),         us2f((u16)vv),         a0);
            a1 = fmaf(sigmoidf_(us2f((u16)(ev >> 16))), us2f((u16)(vv >> 16)), a1);
        }
        *reinterpret_cast<float2*>(&xout[(size_t)node * HD + c0]) =
            make_float2(a0 + uv.x, a1 + uv.y);
    }
}

// ---------------------------------------------------------------------------
// K4: per-graph sum/sumsq of x (batch sorted -> register accum, no atomics)
// ---------------------------------------------------------------------------
__global__ __launch_bounds__(256) void hstats_part_kernel(
    const float* __restrict__ xout, const int* __restrict__ batch,
    float* __restrict__ hpart)
{
    __shared__ float sm[2 * GG * HD];
    __shared__ float smc[2 * GG];
    const int t = threadIdx.x;
    const int c = t & 127, half = t >> 7;
    const int chunk = (NN + HP - 1) / HP;
    const int rstart = blockIdx.x * chunk;
    const int rend = min(NN, rstart + chunk);
    const float cinc = (c == 0) ? 1.f : 0.f;
    float s[GG], z[GG], cn[GG];
    #pragma unroll
    for (int g = 0; g < GG; ++g) { s[g] = 0.f; z[g] = 0.f; cn[g] = 0.f; }
    for (int row = rstart + half; row < rend; row += 2) {
        int g = __builtin_amdgcn_readfirstlane(batch[row]);
        float x = xout[(size_t)row * HD + c];
        ACC_SWITCH(g)
    }
    #pragma unroll
    for (int g = 0; g < GG; ++g) sm[(half * GG + g) * HD + c] = s[g];
    if (c == 0) {
        #pragma unroll
        for (int g = 0; g < GG; ++g) smc[half * GG + g] = cn[g];
    }
    __syncthreads();
    float* dst = hpart + (size_t)blockIdx.x * PSTRIDE;
    for (int j = t; j < GG * HD; j += 256) dst[j] = sm[j] + sm[GG * HD + j];
    if (t < GG) dst[2 * GG * HD + t] = smc[t] + smc[GG + t];
    __syncthreads();
    #pragma unroll
    for (int g = 0; g < GG; ++g) sm[(half * GG + g) * HD + c] = z[g];
    __syncthreads();
    for (int j = t; j < GG * HD; j += 256) dst[GG * HD + j] = sm[j] + sm[GG * HD + j];
}

// ---------------------------------------------------------------------------
// K5: per-graph sum/sumsq of ehat_csr (g = g8csr[j], wave-uniform & sorted)
// ---------------------------------------------------------------------------
__global__ __launch_bounds__(512) void estats_part_kernel(
    const u16* __restrict__ ehat_csr, const u8* __restrict__ g8csr,
    float* __restrict__ epart)
{
    __shared__ float sm[4 * GG * HD];
    __shared__ float smc[4 * GG];
    const int t = threadIdx.x;
    const int c = t & 127, q = t >> 7;
    const int chunk = (NE + EP - 1) / EP;
    const int rstart = blockIdx.x * chunk;
    const int rend = min(NE, rstart + chunk);
    const float cinc = (c == 0) ? 1.f : 0.f;
    float s[GG], z[GG], cn[GG];
    #pragma unroll
    for (int g = 0; g < GG; ++g) { s[g] = 0.f; z[g] = 0.f; cn[g] = 0.f; }
    for (int row = rstart + q; row < rend; row += 4) {
        int g = __builtin_amdgcn_readfirstlane((int)g8csr[row]);
        float x = us2f(ehat_csr[(size_t)row * HD + c]);
        ACC_SWITCH(g)
    }
    #pragma unroll
    for (int g = 0; g < GG; ++g) sm[(q * GG + g) * HD + c] = s[g];
    if (c == 0) {
        #pragma unroll
        for (int g = 0; g < GG; ++g) smc[q * GG + g] = cn[g];
    }
    __syncthreads();
    float* dst = epart + (size_t)blockIdx.x * PSTRIDE;
    for (int j = t; j < GG * HD; j += 512)
        dst[j] = sm[j] + sm[2048 + j] + sm[4096 + j] + sm[6144 + j];
    if (t < GG) dst[2 * GG * HD + t] = smc[t] + smc[GG + t] + smc[2 * GG + t] + smc[3 * GG + t];
    __syncthreads();
    #pragma unroll
    for (int g = 0; g < GG; ++g) sm[(q * GG + g) * HD + c] = z[g];
    __syncthreads();
    for (int j = t; j < GG * HD; j += 512)
        dst[GG * HD + j] = sm[j] + sm[2048 + j] + sm[4096 + j] + sm[6144 + j];
}

// ---------------------------------------------------------------------------
// K5b: chunked partial-slice reduce
// ---------------------------------------------------------------------------
__global__ __launch_bounds__(256) void reduce_part_kernel(
    const float* __restrict__ part, int P, int csz, float* __restrict__ out)
{
    int j = blockIdx.x * 256 + threadIdx.x;
    if (j >= SLEN) return;
    int p0 = blockIdx.y * csz;
    int p1 = min(P, p0 + csz);
    float a = 0.f;
    for (int p = p0; p < p1; ++p) a += part[(size_t)p * PSTRIDE + j];
    out[(size_t)blockIdx.y * PSTRIDE + j] = a;
}

// ---------------------------------------------------------------------------
// K6: stats -> packed scale/bias tables:
//     SB[g][c] = {S, B} interleaved; gn_relu(x) = max(S*x + B, 0)
// ---------------------------------------------------------------------------
__global__ __launch_bounds__(256) void finstats_kernel(
    const float* __restrict__ statsH, const float* __restrict__ statsE,
    const float* __restrict__ gnh_ms, const float* __restrict__ gne_ms,
    const float* __restrict__ gnh_w, const float* __restrict__ gnh_b,
    const float* __restrict__ gne_w, const float* __restrict__ gne_b,
    float* __restrict__ SBh, float* __restrict__ SBe)
{
    for (int i = threadIdx.x; i < GG * HD; i += 256) {
        int g = i >> 7, c = i & 127;
        {
            float cnt = fmaxf(statsH[4096 + g], 1.f);
            float mean = statsH[i] / cnt;
            float ex2 = statsH[2048 + i] / cnt;
            float off = mean * gnh_ms[c];
            float var = ex2 - 2.f * off * mean + off * off;
            float S = gnh_w[c] * rsqrtf(var + EPSV);
            SBh[2 * i]     = S;
            SBh[2 * i + 1] = gnh_b[c] - off * S;
        }
        {
            float cnt = fmaxf(statsE[4096 + g], 1.f);
            float mean = statsE[i] / cnt;
            float ex2 = statsE[2048 + i] / cnt;
            float off = mean * gne_ms[c];
            float var = ex2 - 2.f * off * mean + off * off;
            float S = gne_w[c] * rsqrtf(var + EPSV);
            SBe[2 * i]     = S;
            SBe[2 * i + 1] = gne_b[c] - off * S;
        }
    }
}

// ---------------------------------------------------------------------------
// K7: tproj = relu(time_emb) @ Wt + bt   [16 x 128]
// ---------------------------------------------------------------------------
__global__ __launch_bounds__(256) void tproj_kernel(
    const float* __restrict__ time_emb, const float* __restrict__ Wt,
    const float* __restrict__ bt, float* __restrict__ tproj)
{
    __shared__ float te[GG][HD];
    const int t = threadIdx.x;
    for (int i = t; i < GG * HD; i += 256) te[i >> 7][i & 127] = fmaxf(time_emb[i], 0.f);
    __syncthreads();
    const int c = t & 127, rb = t >> 7;
    float acc[8];
    #pragma unroll
    for (int j = 0; j < 8; ++j) acc[j] = 0.f;
    for (int k = 0; k < HD; ++k) {
        float wv = Wt[k * HD + c];
        #pragma unroll
        for (int j = 0; j < 8; ++j) acc[j] = fmaf(te[rb + 2 * j][k], wv, acc[j]);
    }
    float b = bt[c];
    #pragma unroll
    for (int j = 0; j < 8; ++j) tproj[(rb + 2 * j) * HD + c] = acc[j] + b;
}

// ---------------------------------------------------------------------------
// K8: h = features + max(S*x+B, 0);  x lives in hout (in-place)
// ---------------------------------------------------------------------------
__global__ __launch_bounds__(256) void hfinal_kernel(
    const float* __restrict__ feat, const int* __restrict__ batch,
    const float* __restrict__ SBh, float* hout_x)
{
    int i = blockIdx.x * 256 + threadIdx.x;
    size_t base = (size_t)i * 4;
    if (base >= (size_t)NN * HD) return;
    int row = (int)(base >> 7), c0 = (int)(base & 127);
    int g = batch[row];
    float4 fe = *reinterpret_cast<const float4*>(&feat[base]);
    float4 xv = *reinterpret_cast<const float4*>(&hout_x[base]);
    float4 sb0 = *reinterpret_cast<const float4*>(&SBh[(size_t)(g * HD + c0) * 2]);
    float4 sb1 = *reinterpret_cast<const float4*>(&SBh[(size_t)(g * HD + c0 + 2) * 2]);
    float4 ou;
    ou.x = fe.x + fmaxf(fmaf(xv.x, sb0.x, sb0.y), 0.f);
    ou.y = fe.y + fmaxf(fmaf(xv.y, sb0.z, sb0.w), 0.f);
    ou.z = fe.z + fmaxf(fmaf(xv.z, sb1.x, sb1.y), 0.f);
    ou.w = fe.w + fmaxf(fmaf(xv.w, sb1.z, sb1.w), 0.f);
    *reinterpret_cast<float4*>(&hout_x[base]) = ou;
}

// ---------------------------------------------------------------------------
// K9: MFMA (CSR order): e[perm[j]] = noise[perm[j]]@We + be
//       + silu(LN(max(S*ehat_csr[j]+B,0) + tproj[g])) @ Wo + bo
//     g is ~wave-uniform in CSR order -> table loads become L1 broadcasts.
// ---------------------------------------------------------------------------
__global__ __launch_bounds__(256) void efinal_kernel(
    const u16* __restrict__ ehat_csr, const u8* __restrict__ g8csr,
    const float* __restrict__ noise, const int* __restrict__ perm,
    const u16* __restrict__ WoT, const u16* __restrict__ WeT,
    const float* __restrict__ be, const float* __restrict__ bo,
    const float* __restrict__ SBe, const float* __restrict__ tproj,
    const float* __restrict__ ln_w, const float* __restrict__ ln_b,
    float* __restrict__ eout)
{
    const int t = threadIdx.x;
    const int rbase = blockIdx.x * ETILE2;
    const int w = t >> 6, lane = t & 63;
    const int l15 = lane & 15, kg = lane >> 4;
    const int rt = w * 32;

    u32 aw[2][4][4];
    u32 an[2][2][4];
    int prow[2][4];
    #pragma unroll
    for (int tile = 0; tile < 2; ++tile) {
        const int jl = rbase + rt + tile * 16 + l15;
        const int el = perm[jl];
        const int g = g8csr[jl];
        #pragma unroll
        for (int i = 0; i < 4; ++i) prow[tile][i] = perm[rbase + rt + tile * 16 + kg * 4 + i];
        float v[4][8];
        float lsum = 0.f;
        #pragma unroll
        for (int kk = 0; kk < 4; ++kk) {
            const int c = kk * 32 + kg * 8;
            uint4 ev = *reinterpret_cast<const uint4*>(&ehat_csr[(size_t)jl * HD + c]);
            const u32 wds[4] = {ev.x, ev.y, ev.z, ev.w};
            #pragma unroll
            for (int p = 0; p < 4; ++p) {
                const int c2 = c + p * 2;
                float x0 = us2f((u16)wds[p]);
                float x1 = us2f((u16)(wds[p] >> 16));
                float4 sb = *reinterpret_cast<const float4*>(&SBe[(size_t)(g * HD + c2) * 2]);
                float2 tp = *reinterpret_cast<const float2*>(&tproj[g * HD + c2]);
                float a0 = fmaxf(fmaf(x0, sb.x, sb.y), 0.f) + tp.x;
                float a1 = fmaxf(fmaf(x1, sb.z, sb.w), 0.f) + tp.y;
                v[kk][p * 2]     = a0;
                v[kk][p * 2 + 1] = a1;
                lsum += a0 + a1;
            }
        }
        lsum += __shfl_xor(lsum, 16, 64);
        lsum += __shfl_xor(lsum, 32, 64);
        float mu = lsum * (1.f / 128.f);
        float sq = 0.f;
        #pragma unroll
        for (int kk = 0; kk < 4; ++kk)
            #pragma unroll
            for (int j = 0; j < 8; ++j) { float d = v[kk][j] - mu; sq = fmaf(d, d, sq); }
        sq += __shfl_xor(sq, 16, 64);
        sq += __shfl_xor(sq, 32, 64);
        float rstd = rsqrtf(sq * (1.f / 128.f) + EPSV);
        #pragma unroll
        for (int kk = 0; kk < 4; ++kk) {
            const int c = kk * 32 + kg * 8;
            #pragma unroll
            for (int p = 0; p < 4; ++p) {
                const int c2 = c + p * 2;
                float2 lw = *reinterpret_cast<const float2*>(&ln_w[c2]);
                float2 lb = *reinterpret_cast<const float2*>(&ln_b[c2]);
                float l0 = (v[kk][p * 2]     - mu) * rstd * lw.x + lb.x;
                float l1 = (v[kk][p * 2 + 1] - mu) * rstd * lw.y + lb.y;
                float s0 = l0 * sigmoidf_(l0);
                float s1 = l1 * sigmoidf_(l1);
                aw[tile][kk][p] = (u32)f2us(s0) | ((u32)f2us(s1) << 16);
            }
        }
        #pragma unroll
        for (int kk = 0; kk < 2; ++kk) {
            const int c = kk * 32 + kg * 8;
            float4 n0 = *reinterpret_cast<const float4*>(&noise[(size_t)el * ND + c]);
            float4 n1 = *reinterpret_cast<const float4*>(&noise[(size_t)el * ND + c + 4]);
            an[tile][kk][0] = (u32)f2us(n0.x) | ((u32)f2us(n0.y) << 16);
            an[tile][kk][1] = (u32)f2us(n0.z) | ((u32)f2us(n0.w) << 16);
            an[tile][kk][2] = (u32)f2us(n1.x) | ((u32)f2us(n1.y) << 16);
            an[tile][kk][3] = (u32)f2us(n1.z) | ((u32)f2us(n1.w) << 16);
        }
    }

    // MFMA: each B fragment feeds both row-tiles
    f32x4 acc[2][8];
    #pragma unroll
    for (int nt = 0; nt < 8; ++nt) {
        int gcol = nt * 16 + l15;
        float bsum = bo[gcol] + be[gcol];
        #pragma unroll
        for (int i = 0; i < 4; ++i) { acc[0][nt][i] = bsum; acc[1][nt][i] = bsum; }
    }
    #pragma unroll
    for (int nt = 0; nt < 8; ++nt) {
        #pragma unroll
        for (int kk = 0; kk < 4; ++kk) {
            bf16x8 b = *reinterpret_cast<const bf16x8*>(&WoT[(nt * 16 + l15) * HD + kk * 32 + kg * 8]);
            acc[0][nt] = __builtin_amdgcn_mfma_f32_16x16x32_bf16(
                *reinterpret_cast<const bf16x8*>(aw[0][kk]), b, acc[0][nt], 0, 0, 0);
            acc[1][nt] = __builtin_amdgcn_mfma_f32_16x16x32_bf16(
                *reinterpret_cast<const bf16x8*>(aw[1][kk]), b, acc[1][nt], 0, 0, 0);
        }
        #pragma unroll
        for (int kk = 0; kk < 2; ++kk) {
            bf16x8 b = *reinterpret_cast<const bf16x8*>(&WeT[(nt * 16 + l15) * ND + kk * 32 + kg * 8]);
            acc[0][nt] = __builtin_amdgcn_mfma_f32_16x16x32_bf16(
                *reinterpret_cast<const bf16x8*>(an[0][kk]), b, acc[0][nt], 0, 0, 0);
            acc[1][nt] = __builtin_amdgcn_mfma_f32_16x16x32_bf16(
                *reinterpret_cast<const bf16x8*>(an[1][kk]), b, acc[1][nt], 0, 0, 0);
        }
    }
    #pragma unroll
    for (int tile = 0; tile < 2; ++tile) {
        #pragma unroll
        for (int nt = 0; nt < 8; ++nt) {
            int gcol = nt * 16 + l15;
            #pragma unroll
            for (int i = 0; i < 4; ++i) {
                eout[(size_t)prow[tile][i] * HD + gcol] = acc[tile][nt][i];
            }
        }
    }
}

// ---------------------------------------------------------------------------
extern "C" void kernel_launch(void* const* d_in, const int* in_sizes, int n_in,
                              void* d_out, int out_size, void* d_ws, size_t ws_size,
                              hipStream_t stream)
{
    const float* feat     = (const float*)d_in[0];
    const int*   eidx     = (const int*)d_in[1];
    const float* noise    = (const float*)d_in[2];
    const float* time_emb = (const float*)d_in[3];
    const int*   batch    = (const int*)d_in[4];
    const float* We = (const float*)d_in[5],  *be = (const float*)d_in[6];
    const float* Wp = (const float*)d_in[7],  *bp = (const float*)d_in[8];
    const float* Wq = (const float*)d_in[9],  *bq = (const float*)d_in[10];
    const float* Wr = (const float*)d_in[11], *br = (const float*)d_in[12];
    const float* Wu = (const float*)d_in[13], *bu = (const float*)d_in[14];
    const float* Wv = (const float*)d_in[15], *bv = (const float*)d_in[16];
    const float* gnh_w = (const float*)d_in[17], *gnh_b = (const float*)d_in[18], *gnh_ms = (const float*)d_in[19];
    const float* gne_w = (const float*)d_in[20], *gne_b = (const float*)d_in[21], *gne_ms = (const float*)d_in[22];
    const float* Wt = (const float*)d_in[23], *bt = (const float*)d_in[24];
    const float* ln_w = (const float*)d_in[25], *ln_b = (const float*)d_in[26];
    const float* Wo = (const float*)d_in[27], *bo = (const float*)d_in[28];

    const int* srcArr = eidx;
    const int* dstArr = eidx + NE;

    float* hout = (float*)d_out;                    // [N,H] f32 — holds fu32, then x, then h
    float* eout = hout + (size_t)NN * HD;           // [E,H] f32 — final e

    char* ws = (char*)d_ws;
    size_t off = 0;
    auto take = [&](size_t bytes) -> char* {
        char* p = ws + off;
        off = (off + bytes + 255) & ~(size_t)255;
        return p;
    };
    u16* ehat = (u16*)take((size_t)NE * HD * 2);    // 102.4 MB (CSR order)
    u16* fq = (u16*)take((size_t)NN * HD * 2);      // 12.8 MB
    u16* fr = (u16*)take((size_t)NN * HD * 2);
    u16* fv = (u16*)take((size_t)NN * HD * 2);
    u8*  g8csr = (u8*)take((size_t)NE);
    u32* deg  = (u32*)take((size_t)2 * NN * 4);     // deg[NN] + cnt2[NN], one memset
    u32* cnt2 = deg + NN;
    int* start = (int*)take((size_t)(NN + 1) * 4);
    int* perm  = (int*)take((size_t)NE * 4);
    int* src_csr = (int*)take((size_t)NE * 4);      // 1.6 MB
    int* dst_csr = (int*)take((size_t)NE * 4);      // 1.6 MB
    float* Wep = (float*)take((size_t)ND * HD * 4);
    float* bep = (float*)take((size_t)HD * 4);
    u16* WqT = (u16*)take((size_t)HD * HD * 2);     // transposed bf16 weights
    u16* WrT = (u16*)take((size_t)HD * HD * 2);
    u16* WvT = (u16*)take((size_t)HD * HD * 2);
    u16* WuT = (u16*)take((size_t)HD * HD * 2);
    u16* WoT = (u16*)take((size_t)HD * HD * 2);
    u16* WepT = (u16*)take((size_t)HD * ND * 2);
    u16* WeT  = (u16*)take((size_t)HD * ND * 2);
    float* statsH = (float*)take((size_t)PSTRIDE * 4);
    float* statsE = (float*)take((size_t)PSTRIDE * 4);
    float* tproj  = (float*)take((size_t)GG * HD * 4);
    float* SBh    = (float*)take((size_t)GG * HD * 8);   // {S,B} interleaved
    float* SBe    = (float*)take((size_t)GG * HD * 8);
    float* epart  = (float*)take((size_t)EP * PSTRIDE * 4);   // 4.5 MB
    float* hpart  = (float*)take((size_t)HP * PSTRIDE * 4);   // 4.5 MB
    float* etmp   = (float*)take((size_t)8 * PSTRIDE * 4);
    float* htmp   = (float*)take((size_t)8 * PSTRIDE * 4);
    // total ~156.1 MB — under the ~167.7 MB budget (R3 pass / R4 fail bound)

    hipMemsetAsync(deg, 0, (size_t)2 * NN * 4, stream);

    wep_kernel<<<16, 256, 0, stream>>>(We, Wp, be, bp, Wep, bep);
    prep_all_kernel<<<dim3(64, 7), 256, 0, stream>>>(Wq, Wr, Wv, Wu, Wo, Wep, We,
                                                     WqT, WrT, WvT, WuT, WoT, WepT, WeT);
    hist_kernel<<<(NE + 255) / 256, 256, 0, stream>>>(srcArr, deg);
    scan_kernel<<<1, 1024, 0, stream>>>(deg, start);
    scatter_kernel<<<(NE + 255) / 256, 256, 0, stream>>>(srcArr, dstArr, batch, start,
                                                         cnt2, perm, src_csr, dst_csr, g8csr);
    proj4_kernel<<<(NN + ETILE - 1) / ETILE, 256, 0, stream>>>(
        feat, WqT, WrT, WvT, WuT, bq, br, bv, bu, fq, fr, fv, hout);
    ehat_kernel<<<NE / ETILE, 256, 0, stream>>>(noise, WepT, bep, fq, fr,
                                                perm, src_csr, dst_csr, ehat);
    aggr_kernel<<<2048, 256, 0, stream>>>(ehat, fv, dst_csr, start, hout);
    hstats_part_kernel<<<HP, 256, 0, stream>>>(hout, batch, hpart);
    estats_part_kernel<<<EP, 512, 0, stream>>>(ehat, g8csr, epart);
    {
        dim3 gA((SLEN + 255) / 256, 8);
        reduce_part_kernel<<<gA, 256, 0, stream>>>(hpart, HP, HP / 8, htmp);
        reduce_part_kernel<<<gA, 256, 0, stream>>>(epart, EP, EP / 8, etmp);
        dim3 gB((SLEN + 255) / 256, 1);
        reduce_part_kernel<<<gB, 256, 0, stream>>>(htmp, 8, 8, statsH);
        reduce_part_kernel<<<gB, 256, 0, stream>>>(etmp, 8, 8, statsE);
    }
    tproj_kernel<<<1, 256, 0, stream>>>(time_emb, Wt, bt, tproj);
    finstats_kernel<<<1, 256, 0, stream>>>(statsH, statsE, gnh_ms, gne_ms,
                                           gnh_w, gnh_b, gne_w, gne_b, SBh, SBe);
    hfinal_kernel<<<(NN * HD / 4 + 255) / 256, 256, 0, stream>>>(feat, batch, SBh, hout);
    efinal_kernel<<<NE / ETILE2, 256, 0, stream>>>(ehat, g8csr, noise, perm, WoT, WeT,
                                                   be, bo, SBe, tproj, ln_w, ln_b, eout);
}

// Round 10
// 784.150 us; speedup vs baseline: 2.4014x; 1.2493x over previous
//
#include <hip/hip_runtime.h>

#define NN 50000
#define NE 400000
#define HD 128
#define ND 64
#define GG 16
#define EPSV 1e-5f
#define ETILE 64
#define ETILE2 128

#define SLEN (2 * GG * HD + GG)   // 4112 floats: [sum 2048 | sumsq 2048 | cnt 16]
#define PSTRIDE 4352              // partial-set stride (floats), non-pow2
#define EP 512                    // estats stage-1 blocks
#define HP 256                    // hstats stage-1 blocks

typedef unsigned short u16;
typedef unsigned int   u32;
typedef unsigned char  u8;
typedef __attribute__((__ext_vector_type__(8))) __bf16 bf16x8;
typedef __attribute__((__ext_vector_type__(4))) float  f32x4;

__device__ __forceinline__ float us2f(u16 u) { return __uint_as_float(((u32)u) << 16); }
__device__ __forceinline__ u16 f2us(float f) {
    u32 u = __float_as_uint(f);
    u += 0x7fffu + ((u >> 16) & 1u);   // RNE
    return (u16)(u >> 16);
}
__device__ __forceinline__ float sigmoidf_(float x) { return 1.f / (1.f + __expf(-x)); }

// ---------------------------------------------------------------------------
// K0a: Wep = We @ Wp  [64x128], bep = be @ Wp + bp   (grid=16, Wp in LDS)
// ---------------------------------------------------------------------------
__global__ __launch_bounds__(256) void wep_kernel(
    const float* __restrict__ We, const float* __restrict__ Wp,
    const float* __restrict__ be, const float* __restrict__ bp,
    float* __restrict__ Wep, float* __restrict__ bep)
{
    __shared__ float wp[HD][HD];      // 64 KB
    const int t = threadIdx.x;
    for (int i = t; i < HD * HD; i += 256) wp[i >> 7][i & 127] = Wp[i];
    __syncthreads();
    const int c = t & 127;
    for (int r = blockIdx.x * 4 + (t >> 7); r < (blockIdx.x + 1) * 4 && r < ND; r += 2) {
        float a = 0.f;
        for (int k = 0; k < HD; ++k) a = fmaf(We[r * HD + k], wp[k][c], a);
        Wep[r * HD + c] = a;
    }
    if (blockIdx.x == 0 && t < HD) {
        float a = bp[t];
        for (int k = 0; k < HD; ++k) a = fmaf(be[k], wp[k][t], a);
        bep[t] = a;
    }
}

// ---------------------------------------------------------------------------
// K0e: all weight transposes in ONE launch. grid=(64,7).
// ---------------------------------------------------------------------------
__global__ __launch_bounds__(256) void prep_all_kernel(
    const float* __restrict__ Wq, const float* __restrict__ Wr,
    const float* __restrict__ Wv, const float* __restrict__ Wu,
    const float* __restrict__ Wo, const float* __restrict__ Wep,
    const float* __restrict__ We,
    u16* __restrict__ WqT, u16* __restrict__ WrT, u16* __restrict__ WvT,
    u16* __restrict__ WuT, u16* __restrict__ WoT, u16* __restrict__ WepT,
    u16* __restrict__ WeT)
{
    const float* in; u16* out; int K;
    switch (blockIdx.y) {
        case 0: in = Wq;  out = WqT;  K = HD; break;
        case 1: in = Wr;  out = WrT;  K = HD; break;
        case 2: in = Wv;  out = WvT;  K = HD; break;
        case 3: in = Wu;  out = WuT;  K = HD; break;
        case 4: in = Wo;  out = WoT;  K = HD; break;
        case 5: in = Wep; out = WepT; K = ND; break;
        default: in = We; out = WeT;  K = ND; break;
    }
    int idx = blockIdx.x * 256 + threadIdx.x;
    if (idx >= K * HD) return;
    int k = idx >> 7, n = idx & 127;
    out[n * K + k] = f2us(in[idx]);
}

// ---------------------------------------------------------------------------
// K0b: degree histogram
// ---------------------------------------------------------------------------
__global__ __launch_bounds__(256) void hist_kernel(
    const int* __restrict__ srcArr, u32* __restrict__ deg)
{
    int e = blockIdx.x * 256 + threadIdx.x;
    if (e >= NE) return;
    atomicAdd(&deg[srcArr[e]], 1u);
}

// ---------------------------------------------------------------------------
// K0c: exclusive prefix sum of deg[NN] -> start[NN+1]   (1 block, 1024 thr)
// ---------------------------------------------------------------------------
#define SCAN_C 49   // 1024*49 = 50176 >= NN
__global__ __launch_bounds__(1024) void scan_kernel(
    const u32* __restrict__ deg, int* __restrict__ start)
{
    __shared__ u32 sums[1024];
    const int t = threadIdx.x;
    const int i0 = t * SCAN_C;
    u32 tot = 0;
    for (int j = 0; j < SCAN_C; ++j) { int i = i0 + j; if (i < NN) tot += deg[i]; }
    sums[t] = tot;
    __syncthreads();
    for (int off = 1; off < 1024; off <<= 1) {
        u32 v = (t >= off) ? sums[t - off] : 0u;
        __syncthreads();
        sums[t] += v;
        __syncthreads();
    }
    u32 run = (t == 0) ? 0u : sums[t - 1];
    for (int j = 0; j < SCAN_C; ++j) {
        int i = i0 + j;
        if (i < NN) { start[i] = (int)run; run += deg[i]; }
    }
    if (t == 1023) start[NN] = (int)run;   // == NE
}

// ---------------------------------------------------------------------------
// K0d: scatter edges into CSR order + materialize src/dst/g8 in CSR order
// ---------------------------------------------------------------------------
__global__ __launch_bounds__(256) void scatter_kernel(
    const int* __restrict__ srcArr, const int* __restrict__ dstArr,
    const int* __restrict__ batch, const int* __restrict__ start,
    u32* __restrict__ cnt2, int* __restrict__ perm,
    int* __restrict__ src_csr, int* __restrict__ dst_csr,
    u8* __restrict__ g8csr)
{
    int e = blockIdx.x * 256 + threadIdx.x;
    if (e >= NE) return;
    int s = srcArr[e];
    u32 pos = atomicAdd(&cnt2[s], 1u);
    int j = start[s] + (int)pos;
    perm[j] = e;
    src_csr[j] = s;
    dst_csr[j] = dstArr[e];
    g8csr[j] = (u8)batch[s];
}

// ---------------------------------------------------------------------------
// K1: MFMA: fq/fr/fv = feat @ {Wq,Wr,Wv} + b (bf16); fu32 = feat@Wu + bu (f32)
// ---------------------------------------------------------------------------
__global__ __launch_bounds__(256) void proj4_kernel(
    const float* __restrict__ feat,
    const u16* __restrict__ WqT, const u16* __restrict__ WrT,
    const u16* __restrict__ WvT, const u16* __restrict__ WuT,
    const float* __restrict__ bq, const float* __restrict__ br,
    const float* __restrict__ bv, const float* __restrict__ bu,
    u16* __restrict__ fq, u16* __restrict__ fr, u16* __restrict__ fv,
    float* __restrict__ fu32)
{
    __shared__ __align__(16) u16 As[ETILE * HD];   // 16 KB, XOR-swizzled
    const int t = threadIdx.x;
    const int rbase = blockIdx.x * ETILE;
    #pragma unroll
    for (int i = 0; i < 16; ++i) {
        int idx2 = t + i * 256;            // bf16-pair index
        int row = idx2 >> 6, p = idx2 & 63;
        int grow = rbase + row;
        float2 v = make_float2(0.f, 0.f);
        if (grow < NN) v = *reinterpret_cast<const float2*>(&feat[(size_t)grow * HD + p * 2]);
        u32 pk = (u32)f2us(v.x) | ((u32)f2us(v.y) << 16);
        int off = (row * 256 + p * 4) ^ ((row & 7) << 4);
        *reinterpret_cast<u32*>(reinterpret_cast<char*>(As) + off) = pk;
    }
    __syncthreads();
    const int w = t >> 6, lane = t & 63;
    const int rt = w * 16, l15 = lane & 15, kg = lane >> 4;
    const int lrow = rt + l15;
    bf16x8 afr[4];
    #pragma unroll
    for (int kk = 0; kk < 4; ++kk) {
        int off = (lrow * 256 + (kk * 32 + kg * 8) * 2) ^ ((lrow & 7) << 4);
        afr[kk] = *reinterpret_cast<const bf16x8*>(reinterpret_cast<const char*>(As) + off);
    }
    const u16* WTs[4] = {WqT, WrT, WvT, WuT};
    const float* Bs2[4] = {bq, br, bv, bu};
    u16* Os[3] = {fq, fr, fv};
    #pragma unroll
    for (int m = 0; m < 4; ++m) {
        f32x4 acc[8];
        #pragma unroll
        for (int nt = 0; nt < 8; ++nt) { acc[nt][0]=0.f; acc[nt][1]=0.f; acc[nt][2]=0.f; acc[nt][3]=0.f; }
        const u16* W = WTs[m];
        #pragma unroll
        for (int nt = 0; nt < 8; ++nt) {
            #pragma unroll
            for (int kk = 0; kk < 4; ++kk) {
                bf16x8 b = *reinterpret_cast<const bf16x8*>(&W[(nt * 16 + l15) * HD + kk * 32 + kg * 8]);
                acc[nt] = __builtin_amdgcn_mfma_f32_16x16x32_bf16(afr[kk], b, acc[nt], 0, 0, 0);
            }
        }
        #pragma unroll
        for (int nt = 0; nt < 8; ++nt) {
            int gcol = nt * 16 + l15;
            float bias = Bs2[m][gcol];
            #pragma unroll
            for (int i = 0; i < 4; ++i) {
                int grow = rbase + rt + kg * 4 + i;
                if (grow < NN) {
                    float v = acc[nt][i] + bias;
                    if (m < 3) Os[m][(size_t)grow * HD + gcol] = f2us(v);
                    else       fu32[(size_t)grow * HD + gcol] = v;
                }
            }
        }
    }
}

// ---------------------------------------------------------------------------
// K3: MFMA (CSR order): ehat_csr[j] = noise[perm[j]]@Wep + bep
//                                   + fq[src_csr[j]] + fr[dst_csr[j]]
// ---------------------------------------------------------------------------
__global__ __launch_bounds__(256) void ehat_kernel(
    const float* __restrict__ noise, const u16* __restrict__ WepT,
    const float* __restrict__ bep,
    const u16* __restrict__ fq, const u16* __restrict__ fr,
    const int* __restrict__ perm, const int* __restrict__ src_csr,
    const int* __restrict__ dst_csr,
    u16* __restrict__ ehat_csr)
{
    const int t = threadIdx.x;
    const int rbase = blockIdx.x * ETILE;
    const int w = t >> 6, lane = t & 63;
    const int rt = w * 16, l15 = lane & 15, kg = lane >> 4;
    const int jl = rbase + rt + l15;
    const int el = perm[jl];
    u32 an[2][4];
    #pragma unroll
    for (int kk = 0; kk < 2; ++kk) {
        const int c = kk * 32 + kg * 8;
        float4 n0 = *reinterpret_cast<const float4*>(&noise[(size_t)el * ND + c]);
        float4 n1 = *reinterpret_cast<const float4*>(&noise[(size_t)el * ND + c + 4]);
        an[kk][0] = (u32)f2us(n0.x) | ((u32)f2us(n0.y) << 16);
        an[kk][1] = (u32)f2us(n0.z) | ((u32)f2us(n0.w) << 16);
        an[kk][2] = (u32)f2us(n1.x) | ((u32)f2us(n1.y) << 16);
        an[kk][3] = (u32)f2us(n1.z) | ((u32)f2us(n1.w) << 16);
    }
    f32x4 acc[8];
    #pragma unroll
    for (int nt = 0; nt < 8; ++nt) {
        float b = bep[nt * 16 + l15];
        acc[nt][0] = b; acc[nt][1] = b; acc[nt][2] = b; acc[nt][3] = b;
    }
    #pragma unroll
    for (int nt = 0; nt < 8; ++nt) {
        #pragma unroll
        for (int kk = 0; kk < 2; ++kk) {
            bf16x8 b = *reinterpret_cast<const bf16x8*>(&WepT[(nt * 16 + l15) * ND + kk * 32 + kg * 8]);
            acc[nt] = __builtin_amdgcn_mfma_f32_16x16x32_bf16(
                *reinterpret_cast<const bf16x8*>(an[kk]), b, acc[nt], 0, 0, 0);
        }
    }
    #pragma unroll
    for (int i = 0; i < 4; ++i) {
        int jrow = rbase + rt + kg * 4 + i;
        int s = src_csr[jrow], d = dst_csr[jrow];
        #pragma unroll
        for (int nt = 0; nt < 8; ++nt) {
            int gcol = nt * 16 + l15;
            float v = acc[nt][i]
                    + us2f(fq[(size_t)s * HD + gcol]) + us2f(fr[(size_t)d * HD + gcol]);
            ehat_csr[(size_t)jrow * HD + gcol] = f2us(v);
        }
    }
}

// ---------------------------------------------------------------------------
// K3b: x[node] = fu32[node] + sum_{j in [start[n],start[n+1])}
//               sigmoid(ehat_csr[j]) * fv[dst_csr[j]]   — sequential ehat!
// ---------------------------------------------------------------------------
__global__ __launch_bounds__(256) void aggr_kernel(
    const u16* __restrict__ ehat_csr, const u16* __restrict__ fv,
    const int* __restrict__ dst_csr, const int* __restrict__ start,
    float* __restrict__ xout)
{
    const int w = threadIdx.x >> 6, lane = threadIdx.x & 63;
    const int c0 = lane * 2;
    for (int node = blockIdx.x * 4 + w; node < NN; node += gridDim.x * 4) {
        int s0 = start[node], s1 = start[node + 1];
        float2 uv = *reinterpret_cast<const float2*>(&xout[(size_t)node * HD + c0]);
        float a0 = 0.f, a1 = 0.f;
        for (int j = s0; j < s1; ++j) {
            int d = dst_csr[j];
            u32 ev = *reinterpret_cast<const u32*>(&ehat_csr[(size_t)j * HD + c0]);
            u32 vv = *reinterpret_cast<const u32*>(&fv[(size_t)d * HD + c0]);
            a0 = fmaf(sigmoidf_(us2f((u16)ev)),         us2f((u16)vv),         a0);
            a1 = fmaf(sigmoidf_(us2f((u16)(ev >> 16))), us2f((u16)(vv >> 16)), a1);
        }
        *reinterpret_cast<float2*>(&xout[(size_t)node * HD + c0]) =
            make_float2(a0 + uv.x, a1 + uv.y);
    }
}

// ---------------------------------------------------------------------------
// K4: per-graph sum/sumsq of x. batch is SORTED -> running accumulator per
//     thread (8 cols, float4 loads), flush to LDS atomics only on g-change.
// ---------------------------------------------------------------------------
__global__ __launch_bounds__(256) void hstats_part_kernel(
    const float* __restrict__ xout, const int* __restrict__ batch,
    float* __restrict__ hpart)
{
    __shared__ float sm[SLEN];   // [sum 2048 | sumsq 2048 | cnt 16]
    const int t = threadIdx.x;
    for (int i = t; i < SLEN; i += 256) sm[i] = 0.f;
    __syncthreads();
    const int cg = t & 15, rq = t >> 4;   // 8 cols/thread, 16 rows/iter
    const int c8 = cg * 8;
    const int chunk = (NN + HP - 1) / HP;
    const int rstart = blockIdx.x * chunk;
    const int rend = min(NN, rstart + chunk);
    float s0[8], z0[8];
    #pragma unroll
    for (int p = 0; p < 8; ++p) { s0[p] = 0.f; z0[p] = 0.f; }
    float cn = 0.f;
    int curg = -1;
    for (int row = rstart + rq; row < rend; row += 16) {
        int g = batch[row];
        if (g != curg) {
            if (curg >= 0) {
                #pragma unroll
                for (int p = 0; p < 8; ++p) {
                    unsafeAtomicAdd(&sm[curg * HD + c8 + p], s0[p]);
                    unsafeAtomicAdd(&sm[2048 + curg * HD + c8 + p], z0[p]);
                    s0[p] = 0.f; z0[p] = 0.f;
                }
                if (cg == 0) { unsafeAtomicAdd(&sm[4096 + curg], cn); }
                cn = 0.f;
            }
            curg = g;
        }
        float4 xa = *reinterpret_cast<const float4*>(&xout[(size_t)row * HD + c8]);
        float4 xb = *reinterpret_cast<const float4*>(&xout[(size_t)row * HD + c8 + 4]);
        const float xs8[8] = {xa.x, xa.y, xa.z, xa.w, xb.x, xb.y, xb.z, xb.w};
        #pragma unroll
        for (int p = 0; p < 8; ++p) { s0[p] += xs8[p]; z0[p] = fmaf(xs8[p], xs8[p], z0[p]); }
        cn += (cg == 0) ? 1.f : 0.f;
    }
    if (curg >= 0) {
        #pragma unroll
        for (int p = 0; p < 8; ++p) {
            unsafeAtomicAdd(&sm[curg * HD + c8 + p], s0[p]);
            unsafeAtomicAdd(&sm[2048 + curg * HD + c8 + p], z0[p]);
        }
        if (cg == 0) { unsafeAtomicAdd(&sm[4096 + curg], cn); }
    }
    __syncthreads();
    float* dst = hpart + (size_t)blockIdx.x * PSTRIDE;
    for (int i = t; i < SLEN; i += 256) dst[i] = sm[i];
}

// ---------------------------------------------------------------------------
// K5: per-graph sum/sumsq of ehat_csr. g8csr is SORTED (CSR order) ->
//     running accumulator per thread (8 cols, uint4 bf16x8 loads), flush
//     to LDS atomics only on g-change (~1-2 flushes per thread).
// ---------------------------------------------------------------------------
__global__ __launch_bounds__(512) void estats_part_kernel(
    const u16* __restrict__ ehat_csr, const u8* __restrict__ g8csr,
    float* __restrict__ epart)
{
    __shared__ float sm[SLEN];
    const int t = threadIdx.x;
    for (int i = t; i < SLEN; i += 512) sm[i] = 0.f;
    __syncthreads();
    const int cg = t & 15, rq = t >> 4;   // 8 cols/thread, 32 rows/iter
    const int c8 = cg * 8;
    const int chunk = (NE + EP - 1) / EP;
    const int rstart = blockIdx.x * chunk;
    const int rend = min(NE, rstart + chunk);
    float s0[8], z0[8];
    #pragma unroll
    for (int p = 0; p < 8; ++p) { s0[p] = 0.f; z0[p] = 0.f; }
    float cn = 0.f;
    int curg = -1;
    for (int row = rstart + rq; row < rend; row += 32) {
        int g = (int)g8csr[row];
        if (g != curg) {
            if (curg >= 0) {
                #pragma unroll
                for (int p = 0; p < 8; ++p) {
                    unsafeAtomicAdd(&sm[curg * HD + c8 + p], s0[p]);
                    unsafeAtomicAdd(&sm[2048 + curg * HD + c8 + p], z0[p]);
                    s0[p] = 0.f; z0[p] = 0.f;
                }
                if (cg == 0) { unsafeAtomicAdd(&sm[4096 + curg], cn); }
                cn = 0.f;
            }
            curg = g;
        }
        uint4 ev = *reinterpret_cast<const uint4*>(&ehat_csr[(size_t)row * HD + c8]);
        const u32 wds[4] = {ev.x, ev.y, ev.z, ev.w};
        #pragma unroll
        for (int p2 = 0; p2 < 4; ++p2) {
            float x0 = us2f((u16)wds[p2]);
            float x1 = us2f((u16)(wds[p2] >> 16));
            s0[2 * p2]     += x0; z0[2 * p2]     = fmaf(x0, x0, z0[2 * p2]);
            s0[2 * p2 + 1] += x1; z0[2 * p2 + 1] = fmaf(x1, x1, z0[2 * p2 + 1]);
        }
        cn += (cg == 0) ? 1.f : 0.f;
    }
    if (curg >= 0) {
        #pragma unroll
        for (int p = 0; p < 8; ++p) {
            unsafeAtomicAdd(&sm[curg * HD + c8 + p], s0[p]);
            unsafeAtomicAdd(&sm[2048 + curg * HD + c8 + p], z0[p]);
        }
        if (cg == 0) { unsafeAtomicAdd(&sm[4096 + curg], cn); }
    }
    __syncthreads();
    float* dst = epart + (size_t)blockIdx.x * PSTRIDE;
    for (int i = t; i < SLEN; i += 512) dst[i] = sm[i];
}

// ---------------------------------------------------------------------------
// K5b: chunked partial-slice reduce
// ---------------------------------------------------------------------------
__global__ __launch_bounds__(256) void reduce_part_kernel(
    const float* __restrict__ part, int P, int csz, float* __restrict__ out)
{
    int j = blockIdx.x * 256 + threadIdx.x;
    if (j >= SLEN) return;
    int p0 = blockIdx.y * csz;
    int p1 = min(P, p0 + csz);
    float a = 0.f;
    for (int p = p0; p < p1; ++p) a += part[(size_t)p * PSTRIDE + j];
    out[(size_t)blockIdx.y * PSTRIDE + j] = a;
}

// ---------------------------------------------------------------------------
// K6: stats -> packed scale/bias tables:
//     SB[g][c] = {S, B} interleaved; gn_relu(x) = max(S*x + B, 0)
// ---------------------------------------------------------------------------
__global__ __launch_bounds__(256) void finstats_kernel(
    const float* __restrict__ statsH, const float* __restrict__ statsE,
    const float* __restrict__ gnh_ms, const float* __restrict__ gne_ms,
    const float* __restrict__ gnh_w, const float* __restrict__ gnh_b,
    const float* __restrict__ gne_w, const float* __restrict__ gne_b,
    float* __restrict__ SBh, float* __restrict__ SBe)
{
    for (int i = threadIdx.x; i < GG * HD; i += 256) {
        int g = i >> 7, c = i & 127;
        {
            float cnt = fmaxf(statsH[4096 + g], 1.f);
            float mean = statsH[i] / cnt;
            float ex2 = statsH[2048 + i] / cnt;
            float off = mean * gnh_ms[c];
            float var = ex2 - 2.f * off * mean + off * off;
            float S = gnh_w[c] * rsqrtf(var + EPSV);
            SBh[2 * i]     = S;
            SBh[2 * i + 1] = gnh_b[c] - off * S;
        }
        {
            float cnt = fmaxf(statsE[4096 + g], 1.f);
            float mean = statsE[i] / cnt;
            float ex2 = statsE[2048 + i] / cnt;
            float off = mean * gne_ms[c];
            float var = ex2 - 2.f * off * mean + off * off;
            float S = gne_w[c] * rsqrtf(var + EPSV);
            SBe[2 * i]     = S;
            SBe[2 * i + 1] = gne_b[c] - off * S;
        }
    }
}

// ---------------------------------------------------------------------------
// K7: tproj = relu(time_emb) @ Wt + bt   [16 x 128]
// ---------------------------------------------------------------------------
__global__ __launch_bounds__(256) void tproj_kernel(
    const float* __restrict__ time_emb, const float* __restrict__ Wt,
    const float* __restrict__ bt, float* __restrict__ tproj)
{
    __shared__ float te[GG][HD];
    const int t = threadIdx.x;
    for (int i = t; i < GG * HD; i += 256) te[i >> 7][i & 127] = fmaxf(time_emb[i], 0.f);
    __syncthreads();
    const int c = t & 127, rb = t >> 7;
    float acc[8];
    #pragma unroll
    for (int j = 0; j < 8; ++j) acc[j] = 0.f;
    for (int k = 0; k < HD; ++k) {
        float wv = Wt[k * HD + c];
        #pragma unroll
        for (int j = 0; j < 8; ++j) acc[j] = fmaf(te[rb + 2 * j][k], wv, acc[j]);
    }
    float b = bt[c];
    #pragma unroll
    for (int j = 0; j < 8; ++j) tproj[(rb + 2 * j) * HD + c] = acc[j] + b;
}

// ---------------------------------------------------------------------------
// K8: h = features + max(S*x+B, 0);  x lives in hout (in-place)
// ---------------------------------------------------------------------------
__global__ __launch_bounds__(256) void hfinal_kernel(
    const float* __restrict__ feat, const int* __restrict__ batch,
    const float* __restrict__ SBh, float* hout_x)
{
    int i = blockIdx.x * 256 + threadIdx.x;
    size_t base = (size_t)i * 4;
    if (base >= (size_t)NN * HD) return;
    int row = (int)(base >> 7), c0 = (int)(base & 127);
    int g = batch[row];
    float4 fe = *reinterpret_cast<const float4*>(&feat[base]);
    float4 xv = *reinterpret_cast<const float4*>(&hout_x[base]);
    float4 sb0 = *reinterpret_cast<const float4*>(&SBh[(size_t)(g * HD + c0) * 2]);
    float4 sb1 = *reinterpret_cast<const float4*>(&SBh[(size_t)(g * HD + c0 + 2) * 2]);
    float4 ou;
    ou.x = fe.x + fmaxf(fmaf(xv.x, sb0.x, sb0.y), 0.f);
    ou.y = fe.y + fmaxf(fmaf(xv.y, sb0.z, sb0.w), 0.f);
    ou.z = fe.z + fmaxf(fmaf(xv.z, sb1.x, sb1.y), 0.f);
    ou.w = fe.w + fmaxf(fmaf(xv.w, sb1.z, sb1.w), 0.f);
    *reinterpret_cast<float4*>(&hout_x[base]) = ou;
}

// ---------------------------------------------------------------------------
// K9: MFMA (CSR order): e[perm[j]] = noise[perm[j]]@We + be
//       + silu(LN(max(S*ehat_csr[j]+B,0) + tproj[g])) @ Wo + bo
// ---------------------------------------------------------------------------
__global__ __launch_bounds__(256) void efinal_kernel(
    const u16* __restrict__ ehat_csr, const u8* __restrict__ g8csr,
    const float* __restrict__ noise, const int* __restrict__ perm,
    const u16* __restrict__ WoT, const u16* __restrict__ WeT,
    const float* __restrict__ be, const float* __restrict__ bo,
    const float* __restrict__ SBe, const float* __restrict__ tproj,
    const float* __restrict__ ln_w, const float* __restrict__ ln_b,
    float* __restrict__ eout)
{
    const int t = threadIdx.x;
    const int rbase = blockIdx.x * ETILE2;
    const int w = t >> 6, lane = t & 63;
    const int l15 = lane & 15, kg = lane >> 4;
    const int rt = w * 32;

    u32 aw[2][4][4];
    u32 an[2][2][4];
    int prow[2][4];
    #pragma unroll
    for (int tile = 0; tile < 2; ++tile) {
        const int jl = rbase + rt + tile * 16 + l15;
        const int el = perm[jl];
        const int g = g8csr[jl];
        #pragma unroll
        for (int i = 0; i < 4; ++i) prow[tile][i] = perm[rbase + rt + tile * 16 + kg * 4 + i];
        float v[4][8];
        float lsum = 0.f;
        #pragma unroll
        for (int kk = 0; kk < 4; ++kk) {
            const int c = kk * 32 + kg * 8;
            uint4 ev = *reinterpret_cast<const uint4*>(&ehat_csr[(size_t)jl * HD + c]);
            const u32 wds[4] = {ev.x, ev.y, ev.z, ev.w};
            #pragma unroll
            for (int p = 0; p < 4; ++p) {
                const int c2 = c + p * 2;
                float x0 = us2f((u16)wds[p]);
                float x1 = us2f((u16)(wds[p] >> 16));
                float4 sb = *reinterpret_cast<const float4*>(&SBe[(size_t)(g * HD + c2) * 2]);
                float2 tp = *reinterpret_cast<const float2*>(&tproj[g * HD + c2]);
                float a0 = fmaxf(fmaf(x0, sb.x, sb.y), 0.f) + tp.x;
                float a1 = fmaxf(fmaf(x1, sb.z, sb.w), 0.f) + tp.y;
                v[kk][p * 2]     = a0;
                v[kk][p * 2 + 1] = a1;
                lsum += a0 + a1;
            }
        }
        lsum += __shfl_xor(lsum, 16, 64);
        lsum += __shfl_xor(lsum, 32, 64);
        float mu = lsum * (1.f / 128.f);
        float sq = 0.f;
        #pragma unroll
        for (int kk = 0; kk < 4; ++kk)
            #pragma unroll
            for (int j = 0; j < 8; ++j) { float d = v[kk][j] - mu; sq = fmaf(d, d, sq); }
        sq += __shfl_xor(sq, 16, 64);
        sq += __shfl_xor(sq, 32, 64);
        float rstd = rsqrtf(sq * (1.f / 128.f) + EPSV);
        #pragma unroll
        for (int kk = 0; kk < 4; ++kk) {
            const int c = kk * 32 + kg * 8;
            #pragma unroll
            for (int p = 0; p < 4; ++p) {
                const int c2 = c + p * 2;
                float2 lw = *reinterpret_cast<const float2*>(&ln_w[c2]);
                float2 lb = *reinterpret_cast<const float2*>(&ln_b[c2]);
                float l0 = (v[kk][p * 2]     - mu) * rstd * lw.x + lb.x;
                float l1 = (v[kk][p * 2 + 1] - mu) * rstd * lw.y + lb.y;
                float s0 = l0 * sigmoidf_(l0);
                float s1 = l1 * sigmoidf_(l1);
                aw[tile][kk][p] = (u32)f2us(s0) | ((u32)f2us(s1) << 16);
            }
        }
        #pragma unroll
        for (int kk = 0; kk < 2; ++kk) {
            const int c = kk * 32 + kg * 8;
            float4 n0 = *reinterpret_cast<const float4*>(&noise[(size_t)el * ND + c]);
            float4 n1 = *reinterpret_cast<const float4*>(&noise[(size_t)el * ND + c + 4]);
            an[tile][kk][0] = (u32)f2us(n0.x) | ((u32)f2us(n0.y) << 16);
            an[tile][kk][1] = (u32)f2us(n0.z) | ((u32)f2us(n0.w) << 16);
            an[tile][kk][2] = (u32)f2us(n1.x) | ((u32)f2us(n1.y) << 16);
            an[tile][kk][3] = (u32)f2us(n1.z) | ((u32)f2us(n1.w) << 16);
        }
    }

    // MFMA: each B fragment feeds both row-tiles
    f32x4 acc[2][8];
    #pragma unroll
    for (int nt = 0; nt < 8; ++nt) {
        int gcol = nt * 16 + l15;
        float bsum = bo[gcol] + be[gcol];
        #pragma unroll
        for (int i = 0; i < 4; ++i) { acc[0][nt][i] = bsum; acc[1][nt][i] = bsum; }
    }
    #pragma unroll
    for (int nt = 0; nt < 8; ++nt) {
        #pragma unroll
        for (int kk = 0; kk < 4; ++kk) {
            bf16x8 b = *reinterpret_cast<const bf16x8*>(&WoT[(nt * 16 + l15) * HD + kk * 32 + kg * 8]);
            acc[0][nt] = __builtin_amdgcn_mfma_f32_16x16x32_bf16(
                *reinterpret_cast<const bf16x8*>(aw[0][kk]), b, acc[0][nt], 0, 0, 0);
            acc[1][nt] = __builtin_amdgcn_mfma_f32_16x16x32_bf16(
                *reinterpret_cast<const bf16x8*>(aw[1][kk]), b, acc[1][nt], 0, 0, 0);
        }
        #pragma unroll
        for (int kk = 0; kk < 2; ++kk) {
            bf16x8 b = *reinterpret_cast<const bf16x8*>(&WeT[(nt * 16 + l15) * ND + kk * 32 + kg * 8]);
            acc[0][nt] = __builtin_amdgcn_mfma_f32_16x16x32_bf16(
                *reinterpret_cast<const bf16x8*>(an[0][kk]), b, acc[0][nt], 0, 0, 0);
            acc[1][nt] = __builtin_amdgcn_mfma_f32_16x16x32_bf16(
                *reinterpret_cast<const bf16x8*>(an[1][kk]), b, acc[1][nt], 0, 0, 0);
        }
    }
    #pragma unroll
    for (int tile = 0; tile < 2; ++tile) {
        #pragma unroll
        for (int nt = 0; nt < 8; ++nt) {
            int gcol = nt * 16 + l15;
            #pragma unroll
            for (int i = 0; i < 4; ++i) {
                eout[(size_t)prow[tile][i] * HD + gcol] = acc[tile][nt][i];
            }
        }
    }
}

// ---------------------------------------------------------------------------
extern "C" void kernel_launch(void* const* d_in, const int* in_sizes, int n_in,
                              void* d_out, int out_size, void* d_ws, size_t ws_size,
                              hipStream_t stream)
{
    const float* feat     = (const float*)d_in[0];
    const int*   eidx     = (const int*)d_in[1];
    const float* noise    = (const float*)d_in[2];
    const float* time_emb = (const float*)d_in[3];
    const int*   batch    = (const int*)d_in[4];
    const float* We = (const float*)d_in[5],  *be = (const float*)d_in[6];
    const float* Wp = (const float*)d_in[7],  *bp = (const float*)d_in[8];
    const float* Wq = (const float*)d_in[9],  *bq = (const float*)d_in[10];
    const float* Wr = (const float*)d_in[11], *br = (const float*)d_in[12];
    const float* Wu = (const float*)d_in[13], *bu = (const float*)d_in[14];
    const float* Wv = (const float*)d_in[15], *bv = (const float*)d_in[16];
    const float* gnh_w = (const float*)d_in[17], *gnh_b = (const float*)d_in[18], *gnh_ms = (const float*)d_in[19];
    const float* gne_w = (const float*)d_in[20], *gne_b = (const float*)d_in[21], *gne_ms = (const float*)d_in[22];
    const float* Wt = (const float*)d_in[23], *bt = (const float*)d_in[24];
    const float* ln_w = (const float*)d_in[25], *ln_b = (const float*)d_in[26];
    const float* Wo = (const float*)d_in[27], *bo = (const float*)d_in[28];

    const int* srcArr = eidx;
    const int* dstArr = eidx + NE;

    float* hout = (float*)d_out;                    // [N,H] f32 — holds fu32, then x, then h
    float* eout = hout + (size_t)NN * HD;           // [E,H] f32 — final e

    char* ws = (char*)d_ws;
    size_t off = 0;
    auto take = [&](size_t bytes) -> char* {
        char* p = ws + off;
        off = (off + bytes + 255) & ~(size_t)255;
        return p;
    };
    u16* ehat = (u16*)take((size_t)NE * HD * 2);    // 102.4 MB (CSR order)
    u16* fq = (u16*)take((size_t)NN * HD * 2);      // 12.8 MB
    u16* fr = (u16*)take((size_t)NN * HD * 2);
    u16* fv = (u16*)take((size_t)NN * HD * 2);
    u8*  g8csr = (u8*)take((size_t)NE);
    u32* deg  = (u32*)take((size_t)2 * NN * 4);     // deg[NN] + cnt2[NN], one memset
    u32* cnt2 = deg + NN;
    int* start = (int*)take((size_t)(NN + 1) * 4);
    int* perm  = (int*)take((size_t)NE * 4);
    int* src_csr = (int*)take((size_t)NE * 4);      // 1.6 MB
    int* dst_csr = (int*)take((size_t)NE * 4);      // 1.6 MB
    float* Wep = (float*)take((size_t)ND * HD * 4);
    float* bep = (float*)take((size_t)HD * 4);
    u16* WqT = (u16*)take((size_t)HD * HD * 2);     // transposed bf16 weights
    u16* WrT = (u16*)take((size_t)HD * HD * 2);
    u16* WvT = (u16*)take((size_t)HD * HD * 2);
    u16* WuT = (u16*)take((size_t)HD * HD * 2);
    u16* WoT = (u16*)take((size_t)HD * HD * 2);
    u16* WepT = (u16*)take((size_t)HD * ND * 2);
    u16* WeT  = (u16*)take((size_t)HD * ND * 2);
    float* statsH = (float*)take((size_t)PSTRIDE * 4);
    float* statsE = (float*)take((size_t)PSTRIDE * 4);
    float* tproj  = (float*)take((size_t)GG * HD * 4);
    float* SBh    = (float*)take((size_t)GG * HD * 8);   // {S,B} interleaved
    float* SBe    = (float*)take((size_t)GG * HD * 8);
    float* epart  = (float*)take((size_t)EP * PSTRIDE * 4);   // 8.9 MB
    float* hpart  = (float*)take((size_t)HP * PSTRIDE * 4);   // 4.5 MB
    float* etmp   = (float*)take((size_t)8 * PSTRIDE * 4);
    float* htmp   = (float*)take((size_t)8 * PSTRIDE * 4);
    // total ~160.6 MB — under the ~167.7 MB budget (R3 pass / R4 fail bound)

    hipMemsetAsync(deg, 0, (size_t)2 * NN * 4, stream);

    wep_kernel<<<16, 256, 0, stream>>>(We, Wp, be, bp, Wep, bep);
    prep_all_kernel<<<dim3(64, 7), 256, 0, stream>>>(Wq, Wr, Wv, Wu, Wo, Wep, We,
                                                     WqT, WrT, WvT, WuT, WoT, WepT, WeT);
    hist_kernel<<<(NE + 255) / 256, 256, 0, stream>>>(srcArr, deg);
    scan_kernel<<<1, 1024, 0, stream>>>(deg, start);
    scatter_kernel<<<(NE + 255) / 256, 256, 0, stream>>>(srcArr, dstArr, batch, start,
                                                         cnt2, perm, src_csr, dst_csr, g8csr);
    proj4_kernel<<<(NN + ETILE - 1) / ETILE, 256, 0, stream>>>(
        feat, WqT, WrT, WvT, WuT, bq, br, bv, bu, fq, fr, fv, hout);
    ehat_kernel<<<NE / ETILE, 256, 0, stream>>>(noise, WepT, bep, fq, fr,
                                                perm, src_csr, dst_csr, ehat);
    aggr_kernel<<<2048, 256, 0, stream>>>(ehat, fv, dst_csr, start, hout);
    hstats_part_kernel<<<HP, 256, 0, stream>>>(hout, batch, hpart);
    estats_part_kernel<<<EP, 512, 0, stream>>>(ehat, g8csr, epart);
    {
        dim3 gA((SLEN + 255) / 256, 8);
        reduce_part_kernel<<<gA, 256, 0, stream>>>(hpart, HP, HP / 8, htmp);
        reduce_part_kernel<<<gA, 256, 0, stream>>>(epart, EP, EP / 8, etmp);
        dim3 gB((SLEN + 255) / 256, 1);
        reduce_part_kernel<<<gB, 256, 0, stream>>>(htmp, 8, 8, statsH);
        reduce_part_kernel<<<gB, 256, 0, stream>>>(etmp, 8, 8, statsE);
    }
    tproj_kernel<<<1, 256, 0, stream>>>(time_emb, Wt, bt, tproj);
    finstats_kernel<<<1, 256, 0, stream>>>(statsH, statsE, gnh_ms, gne_ms,
                                           gnh_w, gnh_b, gne_w, gne_b, SBh, SBe);
    hfinal_kernel<<<(NN * HD / 4 + 255) / 256, 256, 0, stream>>>(feat, batch, SBh, hout);
    efinal_kernel<<<NE / ETILE2, 256, 0, stream>>>(ehat, g8csr, noise, perm, WoT, WeT,
                                                   be, bo, SBe, tproj, ln_w, ln_b, eout);
}

// Round 11
// 764.884 us; speedup vs baseline: 2.4619x; 1.0252x over previous
//
#include <hip/hip_runtime.h>

#define NN 50000
#define NE 400000
#define HD 128
#define ND 64
#define GG 16
#define EPSV 1e-5f
#define ETILE 64
#define ETILE2 128

#define SLEN (2 * GG * HD + GG)   // 4112 floats: [sum 2048 | sumsq 2048 | cnt 16]
#define PSTRIDE 4352              // partial-set stride (floats), non-pow2
#define EP 512                    // estats stage-1 blocks
#define HP 256                    // hstats stage-1 blocks

typedef unsigned short u16;
typedef unsigned int   u32;
typedef unsigned char  u8;
typedef __attribute__((__ext_vector_type__(8))) __bf16 bf16x8;
typedef __attribute__((__ext_vector_type__(4))) float  f32x4;

__device__ __forceinline__ float us2f(u16 u) { return __uint_as_float(((u32)u) << 16); }
__device__ __forceinline__ u16 f2us(float f) {
    u32 u = __float_as_uint(f);
    u += 0x7fffu + ((u >> 16) & 1u);   // RNE
    return (u16)(u >> 16);
}
__device__ __forceinline__ float sigmoidf_(float x) { return 1.f / (1.f + __expf(-x)); }

// ---------------------------------------------------------------------------
// K0a: Wep = We @ Wp  [64x128], bep = be @ Wp + bp   (grid=16, Wp in LDS)
// ---------------------------------------------------------------------------
__global__ __launch_bounds__(256) void wep_kernel(
    const float* __restrict__ We, const float* __restrict__ Wp,
    const float* __restrict__ be, const float* __restrict__ bp,
    float* __restrict__ Wep, float* __restrict__ bep)
{
    __shared__ float wp[HD][HD];      // 64 KB
    const int t = threadIdx.x;
    for (int i = t; i < HD * HD; i += 256) wp[i >> 7][i & 127] = Wp[i];
    __syncthreads();
    const int c = t & 127;
    for (int r = blockIdx.x * 4 + (t >> 7); r < (blockIdx.x + 1) * 4 && r < ND; r += 2) {
        float a = 0.f;
        for (int k = 0; k < HD; ++k) a = fmaf(We[r * HD + k], wp[k][c], a);
        Wep[r * HD + c] = a;
    }
    if (blockIdx.x == 0 && t < HD) {
        float a = bp[t];
        for (int k = 0; k < HD; ++k) a = fmaf(be[k], wp[k][t], a);
        bep[t] = a;
    }
}

// ---------------------------------------------------------------------------
// K0e: all weight transposes in ONE launch. grid=(64,7).
// ---------------------------------------------------------------------------
__global__ __launch_bounds__(256) void prep_all_kernel(
    const float* __restrict__ Wq, const float* __restrict__ Wr,
    const float* __restrict__ Wv, const float* __restrict__ Wu,
    const float* __restrict__ Wo, const float* __restrict__ Wep,
    const float* __restrict__ We,
    u16* __restrict__ WqT, u16* __restrict__ WrT, u16* __restrict__ WvT,
    u16* __restrict__ WuT, u16* __restrict__ WoT, u16* __restrict__ WepT,
    u16* __restrict__ WeT)
{
    const float* in; u16* out; int K;
    switch (blockIdx.y) {
        case 0: in = Wq;  out = WqT;  K = HD; break;
        case 1: in = Wr;  out = WrT;  K = HD; break;
        case 2: in = Wv;  out = WvT;  K = HD; break;
        case 3: in = Wu;  out = WuT;  K = HD; break;
        case 4: in = Wo;  out = WoT;  K = HD; break;
        case 5: in = Wep; out = WepT; K = ND; break;
        default: in = We; out = WeT;  K = ND; break;
    }
    int idx = blockIdx.x * 256 + threadIdx.x;
    if (idx >= K * HD) return;
    int k = idx >> 7, n = idx & 127;
    out[n * K + k] = f2us(in[idx]);
}

// ---------------------------------------------------------------------------
// K0b: degree histogram
// ---------------------------------------------------------------------------
__global__ __launch_bounds__(256) void hist_kernel(
    const int* __restrict__ srcArr, u32* __restrict__ deg)
{
    int e = blockIdx.x * 256 + threadIdx.x;
    if (e >= NE) return;
    atomicAdd(&deg[srcArr[e]], 1u);
}

// ---------------------------------------------------------------------------
// K0c: exclusive prefix sum of deg[NN] -> start[NN+1]   (1 block, 1024 thr)
// ---------------------------------------------------------------------------
#define SCAN_C 49   // 1024*49 = 50176 >= NN
__global__ __launch_bounds__(1024) void scan_kernel(
    const u32* __restrict__ deg, int* __restrict__ start)
{
    __shared__ u32 sums[1024];
    const int t = threadIdx.x;
    const int i0 = t * SCAN_C;
    u32 tot = 0;
    for (int j = 0; j < SCAN_C; ++j) { int i = i0 + j; if (i < NN) tot += deg[i]; }
    sums[t] = tot;
    __syncthreads();
    for (int off = 1; off < 1024; off <<= 1) {
        u32 v = (t >= off) ? sums[t - off] : 0u;
        __syncthreads();
        sums[t] += v;
        __syncthreads();
    }
    u32 run = (t == 0) ? 0u : sums[t - 1];
    for (int j = 0; j < SCAN_C; ++j) {
        int i = i0 + j;
        if (i < NN) { start[i] = (int)run; run += deg[i]; }
    }
    if (t == 1023) start[NN] = (int)run;   // == NE
}

// ---------------------------------------------------------------------------
// K0d: scatter edges into CSR order + materialize src/dst/g8 in CSR order
// ---------------------------------------------------------------------------
__global__ __launch_bounds__(256) void scatter_kernel(
    const int* __restrict__ srcArr, const int* __restrict__ dstArr,
    const int* __restrict__ batch, const int* __restrict__ start,
    u32* __restrict__ cnt2, int* __restrict__ perm,
    int* __restrict__ src_csr, int* __restrict__ dst_csr,
    u8* __restrict__ g8csr)
{
    int e = blockIdx.x * 256 + threadIdx.x;
    if (e >= NE) return;
    int s = srcArr[e];
    u32 pos = atomicAdd(&cnt2[s], 1u);
    int j = start[s] + (int)pos;
    perm[j] = e;
    src_csr[j] = s;
    dst_csr[j] = dstArr[e];
    g8csr[j] = (u8)batch[s];
}

// ---------------------------------------------------------------------------
// K1: MFMA: fq/fr/fv = feat @ {Wq,Wr,Wv} + b (bf16); fu32 = feat@Wu + bu (f32)
// ---------------------------------------------------------------------------
__global__ __launch_bounds__(256) void proj4_kernel(
    const float* __restrict__ feat,
    const u16* __restrict__ WqT, const u16* __restrict__ WrT,
    const u16* __restrict__ WvT, const u16* __restrict__ WuT,
    const float* __restrict__ bq, const float* __restrict__ br,
    const float* __restrict__ bv, const float* __restrict__ bu,
    u16* __restrict__ fq, u16* __restrict__ fr, u16* __restrict__ fv,
    float* __restrict__ fu32)
{
    __shared__ __align__(16) u16 As[ETILE * HD];   // 16 KB, XOR-swizzled
    const int t = threadIdx.x;
    const int rbase = blockIdx.x * ETILE;
    #pragma unroll
    for (int i = 0; i < 16; ++i) {
        int idx2 = t + i * 256;            // bf16-pair index
        int row = idx2 >> 6, p = idx2 & 63;
        int grow = rbase + row;
        float2 v = make_float2(0.f, 0.f);
        if (grow < NN) v = *reinterpret_cast<const float2*>(&feat[(size_t)grow * HD + p * 2]);
        u32 pk = (u32)f2us(v.x) | ((u32)f2us(v.y) << 16);
        int off = (row * 256 + p * 4) ^ ((row & 7) << 4);
        *reinterpret_cast<u32*>(reinterpret_cast<char*>(As) + off) = pk;
    }
    __syncthreads();
    const int w = t >> 6, lane = t & 63;
    const int rt = w * 16, l15 = lane & 15, kg = lane >> 4;
    const int lrow = rt + l15;
    bf16x8 afr[4];
    #pragma unroll
    for (int kk = 0; kk < 4; ++kk) {
        int off = (lrow * 256 + (kk * 32 + kg * 8) * 2) ^ ((lrow & 7) << 4);
        afr[kk] = *reinterpret_cast<const bf16x8*>(reinterpret_cast<const char*>(As) + off);
    }
    const u16* WTs[4] = {WqT, WrT, WvT, WuT};
    const float* Bs2[4] = {bq, br, bv, bu};
    u16* Os[3] = {fq, fr, fv};
    #pragma unroll
    for (int m = 0; m < 4; ++m) {
        f32x4 acc[8];
        #pragma unroll
        for (int nt = 0; nt < 8; ++nt) { acc[nt][0]=0.f; acc[nt][1]=0.f; acc[nt][2]=0.f; acc[nt][3]=0.f; }
        const u16* W = WTs[m];
        #pragma unroll
        for (int nt = 0; nt < 8; ++nt) {
            #pragma unroll
            for (int kk = 0; kk < 4; ++kk) {
                bf16x8 b = *reinterpret_cast<const bf16x8*>(&W[(nt * 16 + l15) * HD + kk * 32 + kg * 8]);
                acc[nt] = __builtin_amdgcn_mfma_f32_16x16x32_bf16(afr[kk], b, acc[nt], 0, 0, 0);
            }
        }
        #pragma unroll
        for (int nt = 0; nt < 8; ++nt) {
            int gcol = nt * 16 + l15;
            float bias = Bs2[m][gcol];
            #pragma unroll
            for (int i = 0; i < 4; ++i) {
                int grow = rbase + rt + kg * 4 + i;
                if (grow < NN) {
                    float v = acc[nt][i] + bias;
                    if (m < 3) Os[m][(size_t)grow * HD + gcol] = f2us(v);
                    else       fu32[(size_t)grow * HD + gcol] = v;
                }
            }
        }
    }
}

// ---------------------------------------------------------------------------
// K3: MFMA (CSR order): ehat_csr[j] = noise[perm[j]]@Wep + bep
//                                   + fq[src_csr[j]] + fr[dst_csr[j]]
// ---------------------------------------------------------------------------
__global__ __launch_bounds__(256) void ehat_kernel(
    const float* __restrict__ noise, const u16* __restrict__ WepT,
    const float* __restrict__ bep,
    const u16* __restrict__ fq, const u16* __restrict__ fr,
    const int* __restrict__ perm, const int* __restrict__ src_csr,
    const int* __restrict__ dst_csr,
    u16* __restrict__ ehat_csr)
{
    const int t = threadIdx.x;
    const int rbase = blockIdx.x * ETILE;
    const int w = t >> 6, lane = t & 63;
    const int rt = w * 16, l15 = lane & 15, kg = lane >> 4;
    const int jl = rbase + rt + l15;
    const int el = perm[jl];
    u32 an[2][4];
    #pragma unroll
    for (int kk = 0; kk < 2; ++kk) {
        const int c = kk * 32 + kg * 8;
        float4 n0 = *reinterpret_cast<const float4*>(&noise[(size_t)el * ND + c]);
        float4 n1 = *reinterpret_cast<const float4*>(&noise[(size_t)el * ND + c + 4]);
        an[kk][0] = (u32)f2us(n0.x) | ((u32)f2us(n0.y) << 16);
        an[kk][1] = (u32)f2us(n0.z) | ((u32)f2us(n0.w) << 16);
        an[kk][2] = (u32)f2us(n1.x) | ((u32)f2us(n1.y) << 16);
        an[kk][3] = (u32)f2us(n1.z) | ((u32)f2us(n1.w) << 16);
    }
    f32x4 acc[8];
    #pragma unroll
    for (int nt = 0; nt < 8; ++nt) {
        float b = bep[nt * 16 + l15];
        acc[nt][0] = b; acc[nt][1] = b; acc[nt][2] = b; acc[nt][3] = b;
    }
    #pragma unroll
    for (int nt = 0; nt < 8; ++nt) {
        #pragma unroll
        for (int kk = 0; kk < 2; ++kk) {
            bf16x8 b = *reinterpret_cast<const bf16x8*>(&WepT[(nt * 16 + l15) * ND + kk * 32 + kg * 8]);
            acc[nt] = __builtin_amdgcn_mfma_f32_16x16x32_bf16(
                *reinterpret_cast<const bf16x8*>(an[kk]), b, acc[nt], 0, 0, 0);
        }
    }
    #pragma unroll
    for (int i = 0; i < 4; ++i) {
        int jrow = rbase + rt + kg * 4 + i;
        int s = src_csr[jrow], d = dst_csr[jrow];
        #pragma unroll
        for (int nt = 0; nt < 8; ++nt) {
            int gcol = nt * 16 + l15;
            float v = acc[nt][i]
                    + us2f(fq[(size_t)s * HD + gcol]) + us2f(fr[(size_t)d * HD + gcol]);
            ehat_csr[(size_t)jrow * HD + gcol] = f2us(v);
        }
    }
}

// ---------------------------------------------------------------------------
// K3b: x[node] = fu32[node] + sum_{j in [start[n],start[n+1])}
//               sigmoid(ehat_csr[j]) * fv[dst_csr[j]]   — sequential ehat!
// ---------------------------------------------------------------------------
__global__ __launch_bounds__(256) void aggr_kernel(
    const u16* __restrict__ ehat_csr, const u16* __restrict__ fv,
    const int* __restrict__ dst_csr, const int* __restrict__ start,
    float* __restrict__ xout)
{
    const int w = threadIdx.x >> 6, lane = threadIdx.x & 63;
    const int c0 = lane * 2;
    for (int node = blockIdx.x * 4 + w; node < NN; node += gridDim.x * 4) {
        int s0 = start[node], s1 = start[node + 1];
        float2 uv = *reinterpret_cast<const float2*>(&xout[(size_t)node * HD + c0]);
        float a0 = 0.f, a1 = 0.f;
        for (int j = s0; j < s1; ++j) {
            int d = dst_csr[j];
            u32 ev = *reinterpret_cast<const u32*>(&ehat_csr[(size_t)j * HD + c0]);
            u32 vv = *reinterpret_cast<const u32*>(&fv[(size_t)d * HD + c0]);
            a0 = fmaf(sigmoidf_(us2f((u16)ev)),         us2f((u16)vv),         a0);
            a1 = fmaf(sigmoidf_(us2f((u16)(ev >> 16))), us2f((u16)(vv >> 16)), a1);
        }
        *reinterpret_cast<float2*>(&xout[(size_t)node * HD + c0]) =
            make_float2(a0 + uv.x, a1 + uv.y);
    }
}

// ---------------------------------------------------------------------------
// K4: per-graph sum/sumsq of x. batch is SORTED -> running accumulator per
//     thread (8 cols, float4 loads), flush to LDS atomics only on g-change.
// ---------------------------------------------------------------------------
__global__ __launch_bounds__(256) void hstats_part_kernel(
    const float* __restrict__ xout, const int* __restrict__ batch,
    float* __restrict__ hpart)
{
    __shared__ float sm[SLEN];   // [sum 2048 | sumsq 2048 | cnt 16]
    const int t = threadIdx.x;
    for (int i = t; i < SLEN; i += 256) sm[i] = 0.f;
    __syncthreads();
    const int cg = t & 15, rq = t >> 4;   // 8 cols/thread, 16 rows/iter
    const int c8 = cg * 8;
    const int chunk = (NN + HP - 1) / HP;
    const int rstart = blockIdx.x * chunk;
    const int rend = min(NN, rstart + chunk);
    float s0[8], z0[8];
    #pragma unroll
    for (int p = 0; p < 8; ++p) { s0[p] = 0.f; z0[p] = 0.f; }
    float cn = 0.f;
    int curg = -1;
    for (int row = rstart + rq; row < rend; row += 16) {
        int g = batch[row];
        if (g != curg) {
            if (curg >= 0) {
                #pragma unroll
                for (int p = 0; p < 8; ++p) {
                    unsafeAtomicAdd(&sm[curg * HD + c8 + p], s0[p]);
                    unsafeAtomicAdd(&sm[2048 + curg * HD + c8 + p], z0[p]);
                    s0[p] = 0.f; z0[p] = 0.f;
                }
                if (cg == 0) { unsafeAtomicAdd(&sm[4096 + curg], cn); }
                cn = 0.f;
            }
            curg = g;
        }
        float4 xa = *reinterpret_cast<const float4*>(&xout[(size_t)row * HD + c8]);
        float4 xb = *reinterpret_cast<const float4*>(&xout[(size_t)row * HD + c8 + 4]);
        const float xs8[8] = {xa.x, xa.y, xa.z, xa.w, xb.x, xb.y, xb.z, xb.w};
        #pragma unroll
        for (int p = 0; p < 8; ++p) { s0[p] += xs8[p]; z0[p] = fmaf(xs8[p], xs8[p], z0[p]); }
        cn += (cg == 0) ? 1.f : 0.f;
    }
    if (curg >= 0) {
        #pragma unroll
        for (int p = 0; p < 8; ++p) {
            unsafeAtomicAdd(&sm[curg * HD + c8 + p], s0[p]);
            unsafeAtomicAdd(&sm[2048 + curg * HD + c8 + p], z0[p]);
        }
        if (cg == 0) { unsafeAtomicAdd(&sm[4096 + curg], cn); }
    }
    __syncthreads();
    float* dst = hpart + (size_t)blockIdx.x * PSTRIDE;
    for (int i = t; i < SLEN; i += 256) dst[i] = sm[i];
}

// ---------------------------------------------------------------------------
// K5: per-graph sum/sumsq of ehat_csr. g8csr is SORTED (CSR order) ->
//     running accumulator per thread (8 cols, uint4 bf16x8 loads), flush
//     to LDS atomics only on g-change (~1-2 flushes per thread).
// ---------------------------------------------------------------------------
__global__ __launch_bounds__(512) void estats_part_kernel(
    const u16* __restrict__ ehat_csr, const u8* __restrict__ g8csr,
    float* __restrict__ epart)
{
    __shared__ float sm[SLEN];
    const int t = threadIdx.x;
    for (int i = t; i < SLEN; i += 512) sm[i] = 0.f;
    __syncthreads();
    const int cg = t & 15, rq = t >> 4;   // 8 cols/thread, 32 rows/iter
    const int c8 = cg * 8;
    const int chunk = (NE + EP - 1) / EP;
    const int rstart = blockIdx.x * chunk;
    const int rend = min(NE, rstart + chunk);
    float s0[8], z0[8];
    #pragma unroll
    for (int p = 0; p < 8; ++p) { s0[p] = 0.f; z0[p] = 0.f; }
    float cn = 0.f;
    int curg = -1;
    for (int row = rstart + rq; row < rend; row += 32) {
        int g = (int)g8csr[row];
        if (g != curg) {
            if (curg >= 0) {
                #pragma unroll
                for (int p = 0; p < 8; ++p) {
                    unsafeAtomicAdd(&sm[curg * HD + c8 + p], s0[p]);
                    unsafeAtomicAdd(&sm[2048 + curg * HD + c8 + p], z0[p]);
                    s0[p] = 0.f; z0[p] = 0.f;
                }
                if (cg == 0) { unsafeAtomicAdd(&sm[4096 + curg], cn); }
                cn = 0.f;
            }
            curg = g;
        }
        uint4 ev = *reinterpret_cast<const uint4*>(&ehat_csr[(size_t)row * HD + c8]);
        const u32 wds[4] = {ev.x, ev.y, ev.z, ev.w};
        #pragma unroll
        for (int p2 = 0; p2 < 4; ++p2) {
            float x0 = us2f((u16)wds[p2]);
            float x1 = us2f((u16)(wds[p2] >> 16));
            s0[2 * p2]     += x0; z0[2 * p2]     = fmaf(x0, x0, z0[2 * p2]);
            s0[2 * p2 + 1] += x1; z0[2 * p2 + 1] = fmaf(x1, x1, z0[2 * p2 + 1]);
        }
        cn += (cg == 0) ? 1.f : 0.f;
    }
    if (curg >= 0) {
        #pragma unroll
        for (int p = 0; p < 8; ++p) {
            unsafeAtomicAdd(&sm[curg * HD + c8 + p], s0[p]);
            unsafeAtomicAdd(&sm[2048 + curg * HD + c8 + p], z0[p]);
        }
        if (cg == 0) { unsafeAtomicAdd(&sm[4096 + curg], cn); }
    }
    __syncthreads();
    float* dst = epart + (size_t)blockIdx.x * PSTRIDE;
    for (int i = t; i < SLEN; i += 512) dst[i] = sm[i];
}

// ---------------------------------------------------------------------------
// K5b: chunked partial-slice reduce
// ---------------------------------------------------------------------------
__global__ __launch_bounds__(256) void reduce_part_kernel(
    const float* __restrict__ part, int P, int csz, float* __restrict__ out)
{
    int j = blockIdx.x * 256 + threadIdx.x;
    if (j >= SLEN) return;
    int p0 = blockIdx.y * csz;
    int p1 = min(P, p0 + csz);
    float a = 0.f;
    for (int p = p0; p < p1; ++p) a += part[(size_t)p * PSTRIDE + j];
    out[(size_t)blockIdx.y * PSTRIDE + j] = a;
}

// ---------------------------------------------------------------------------
// K6: stats -> packed scale/bias tables + packed LN table + fused bias:
//     SB[g][c] = {S, B} interleaved; gn_relu(x) = max(S*x + B, 0)
//     LNWB[cp] = {lw[2cp], lb[2cp], lw[2cp+1], lb[2cp+1]}
//     bsum[c]  = be[c] + bo[c]
// ---------------------------------------------------------------------------
__global__ __launch_bounds__(256) void finstats_kernel(
    const float* __restrict__ statsH, const float* __restrict__ statsE,
    const float* __restrict__ gnh_ms, const float* __restrict__ gne_ms,
    const float* __restrict__ gnh_w, const float* __restrict__ gnh_b,
    const float* __restrict__ gne_w, const float* __restrict__ gne_b,
    const float* __restrict__ ln_w, const float* __restrict__ ln_b,
    const float* __restrict__ be, const float* __restrict__ bo,
    float* __restrict__ SBh, float* __restrict__ SBe,
    float* __restrict__ LNWB, float* __restrict__ bsum)
{
    const int t = threadIdx.x;
    if (t < 64) {
        LNWB[4 * t]     = ln_w[2 * t];
        LNWB[4 * t + 1] = ln_b[2 * t];
        LNWB[4 * t + 2] = ln_w[2 * t + 1];
        LNWB[4 * t + 3] = ln_b[2 * t + 1];
    }
    if (t >= 64 && t < 192) bsum[t - 64] = be[t - 64] + bo[t - 64];
    for (int i = t; i < GG * HD; i += 256) {
        int g = i >> 7, c = i & 127;
        {
            float cnt = fmaxf(statsH[4096 + g], 1.f);
            float mean = statsH[i] / cnt;
            float ex2 = statsH[2048 + i] / cnt;
            float off = mean * gnh_ms[c];
            float var = ex2 - 2.f * off * mean + off * off;
            float S = gnh_w[c] * rsqrtf(var + EPSV);
            SBh[2 * i]     = S;
            SBh[2 * i + 1] = gnh_b[c] - off * S;
        }
        {
            float cnt = fmaxf(statsE[4096 + g], 1.f);
            float mean = statsE[i] / cnt;
            float ex2 = statsE[2048 + i] / cnt;
            float off = mean * gne_ms[c];
            float var = ex2 - 2.f * off * mean + off * off;
            float S = gne_w[c] * rsqrtf(var + EPSV);
            SBe[2 * i]     = S;
            SBe[2 * i + 1] = gne_b[c] - off * S;
        }
    }
}

// ---------------------------------------------------------------------------
// K7: tproj = relu(time_emb) @ Wt + bt   [16 x 128]
// ---------------------------------------------------------------------------
__global__ __launch_bounds__(256) void tproj_kernel(
    const float* __restrict__ time_emb, const float* __restrict__ Wt,
    const float* __restrict__ bt, float* __restrict__ tproj)
{
    __shared__ float te[GG][HD];
    const int t = threadIdx.x;
    for (int i = t; i < GG * HD; i += 256) te[i >> 7][i & 127] = fmaxf(time_emb[i], 0.f);
    __syncthreads();
    const int c = t & 127, rb = t >> 7;
    float acc[8];
    #pragma unroll
    for (int j = 0; j < 8; ++j) acc[j] = 0.f;
    for (int k = 0; k < HD; ++k) {
        float wv = Wt[k * HD + c];
        #pragma unroll
        for (int j = 0; j < 8; ++j) acc[j] = fmaf(te[rb + 2 * j][k], wv, acc[j]);
    }
    float b = bt[c];
    #pragma unroll
    for (int j = 0; j < 8; ++j) tproj[(rb + 2 * j) * HD + c] = acc[j] + b;
}

// ---------------------------------------------------------------------------
// K8: h = features + max(S*x+B, 0);  x lives in hout (in-place)
// ---------------------------------------------------------------------------
__global__ __launch_bounds__(256) void hfinal_kernel(
    const float* __restrict__ feat, const int* __restrict__ batch,
    const float* __restrict__ SBh, float* hout_x)
{
    int i = blockIdx.x * 256 + threadIdx.x;
    size_t base = (size_t)i * 4;
    if (base >= (size_t)NN * HD) return;
    int row = (int)(base >> 7), c0 = (int)(base & 127);
    int g = batch[row];
    float4 fe = *reinterpret_cast<const float4*>(&feat[base]);
    float4 xv = *reinterpret_cast<const float4*>(&hout_x[base]);
    float4 sb0 = *reinterpret_cast<const float4*>(&SBh[(size_t)(g * HD + c0) * 2]);
    float4 sb1 = *reinterpret_cast<const float4*>(&SBh[(size_t)(g * HD + c0 + 2) * 2]);
    float4 ou;
    ou.x = fe.x + fmaxf(fmaf(xv.x, sb0.x, sb0.y), 0.f);
    ou.y = fe.y + fmaxf(fmaf(xv.y, sb0.z, sb0.w), 0.f);
    ou.z = fe.z + fmaxf(fmaf(xv.z, sb1.x, sb1.y), 0.f);
    ou.w = fe.w + fmaxf(fmaf(xv.w, sb1.z, sb1.w), 0.f);
    *reinterpret_cast<float4*>(&hout_x[base]) = ou;
}

// ---------------------------------------------------------------------------
// K9: MFMA (CSR order): e[perm[j]] = noise[perm[j]]@We
//       + silu(LN(max(S*ehat_csr[j]+B,0) + tproj[g])) @ Wo + (be+bo)
//     nt-halved accumulator (32 live instead of 64) for occupancy.
// ---------------------------------------------------------------------------
__global__ __launch_bounds__(256) void efinal_kernel(
    const u16* __restrict__ ehat_csr, const u8* __restrict__ g8csr,
    const float* __restrict__ noise, const int* __restrict__ perm,
    const u16* __restrict__ WoT, const u16* __restrict__ WeT,
    const float* __restrict__ bsum,
    const float* __restrict__ SBe, const float* __restrict__ tproj,
    const float* __restrict__ LNWB,
    float* __restrict__ eout)
{
    const int t = threadIdx.x;
    const int rbase = blockIdx.x * ETILE2;
    const int w = t >> 6, lane = t & 63;
    const int l15 = lane & 15, kg = lane >> 4;
    const int rt = w * 32;

    u32 aw[2][4][4];
    u32 an[2][2][4];
    #pragma unroll
    for (int tile = 0; tile < 2; ++tile) {
        const int jl = rbase + rt + tile * 16 + l15;
        const int el = perm[jl];
        const int g = g8csr[jl];
        float v[4][8];
        float lsum = 0.f;
        #pragma unroll
        for (int kk = 0; kk < 4; ++kk) {
            const int c = kk * 32 + kg * 8;
            uint4 ev = *reinterpret_cast<const uint4*>(&ehat_csr[(size_t)jl * HD + c]);
            const u32 wds[4] = {ev.x, ev.y, ev.z, ev.w};
            #pragma unroll
            for (int p = 0; p < 4; ++p) {
                const int c2 = c + p * 2;
                float x0 = us2f((u16)wds[p]);
                float x1 = us2f((u16)(wds[p] >> 16));
                float4 sb = *reinterpret_cast<const float4*>(&SBe[(size_t)(g * HD + c2) * 2]);
                float2 tp = *reinterpret_cast<const float2*>(&tproj[g * HD + c2]);
                float a0 = fmaxf(fmaf(x0, sb.x, sb.y), 0.f) + tp.x;
                float a1 = fmaxf(fmaf(x1, sb.z, sb.w), 0.f) + tp.y;
                v[kk][p * 2]     = a0;
                v[kk][p * 2 + 1] = a1;
                lsum += a0 + a1;
            }
        }
        lsum += __shfl_xor(lsum, 16, 64);
        lsum += __shfl_xor(lsum, 32, 64);
        float mu = lsum * (1.f / 128.f);
        float sq = 0.f;
        #pragma unroll
        for (int kk = 0; kk < 4; ++kk)
            #pragma unroll
            for (int j = 0; j < 8; ++j) { float d = v[kk][j] - mu; sq = fmaf(d, d, sq); }
        sq += __shfl_xor(sq, 16, 64);
        sq += __shfl_xor(sq, 32, 64);
        float rstd = rsqrtf(sq * (1.f / 128.f) + EPSV);
        #pragma unroll
        for (int kk = 0; kk < 4; ++kk) {
            #pragma unroll
            for (int p = 0; p < 4; ++p) {
                float4 lnwb = *reinterpret_cast<const float4*>(&LNWB[(kk * 16 + kg * 4 + p) * 4]);
                float l0 = (v[kk][p * 2]     - mu) * rstd * lnwb.x + lnwb.y;
                float l1 = (v[kk][p * 2 + 1] - mu) * rstd * lnwb.z + lnwb.w;
                float s0 = l0 * sigmoidf_(l0);
                float s1 = l1 * sigmoidf_(l1);
                aw[tile][kk][p] = (u32)f2us(s0) | ((u32)f2us(s1) << 16);
            }
        }
        #pragma unroll
        for (int kk = 0; kk < 2; ++kk) {
            const int c = kk * 32 + kg * 8;
            float4 n0 = *reinterpret_cast<const float4*>(&noise[(size_t)el * ND + c]);
            float4 n1 = *reinterpret_cast<const float4*>(&noise[(size_t)el * ND + c + 4]);
            an[tile][kk][0] = (u32)f2us(n0.x) | ((u32)f2us(n0.y) << 16);
            an[tile][kk][1] = (u32)f2us(n0.z) | ((u32)f2us(n0.w) << 16);
            an[tile][kk][2] = (u32)f2us(n1.x) | ((u32)f2us(n1.y) << 16);
            an[tile][kk][3] = (u32)f2us(n1.z) | ((u32)f2us(n1.w) << 16);
        }
    }

    // prow for scattered stores (loaded once, 8 regs)
    int prow[2][4];
    #pragma unroll
    for (int tile = 0; tile < 2; ++tile)
        #pragma unroll
        for (int i = 0; i < 4; ++i)
            prow[tile][i] = perm[rbase + rt + tile * 16 + kg * 4 + i];

    // MFMA in two nt-halves: live acc = 2 tiles x 4 nt x 4 = 32 regs
    #pragma unroll
    for (int h = 0; h < 2; ++h) {
        f32x4 acc[2][4];
        #pragma unroll
        for (int q = 0; q < 4; ++q) {
            int gcol = (h * 4 + q) * 16 + l15;
            float bs = bsum[gcol];
            #pragma unroll
            for (int i = 0; i < 4; ++i) { acc[0][q][i] = bs; acc[1][q][i] = bs; }
        }
        #pragma unroll
        for (int q = 0; q < 4; ++q) {
            int nt = h * 4 + q;
            #pragma unroll
            for (int kk = 0; kk < 4; ++kk) {
                bf16x8 b = *reinterpret_cast<const bf16x8*>(&WoT[(nt * 16 + l15) * HD + kk * 32 + kg * 8]);
                acc[0][q] = __builtin_amdgcn_mfma_f32_16x16x32_bf16(
                    *reinterpret_cast<const bf16x8*>(aw[0][kk]), b, acc[0][q], 0, 0, 0);
                acc[1][q] = __builtin_amdgcn_mfma_f32_16x16x32_bf16(
                    *reinterpret_cast<const bf16x8*>(aw[1][kk]), b, acc[1][q], 0, 0, 0);
            }
            #pragma unroll
            for (int kk = 0; kk < 2; ++kk) {
                bf16x8 b = *reinterpret_cast<const bf16x8*>(&WeT[(nt * 16 + l15) * ND + kk * 32 + kg * 8]);
                acc[0][q] = __builtin_amdgcn_mfma_f32_16x16x32_bf16(
                    *reinterpret_cast<const bf16x8*>(an[0][kk]), b, acc[0][q], 0, 0, 0);
                acc[1][q] = __builtin_amdgcn_mfma_f32_16x16x32_bf16(
                    *reinterpret_cast<const bf16x8*>(an[1][kk]), b, acc[1][q], 0, 0, 0);
            }
        }
        #pragma unroll
        for (int tile = 0; tile < 2; ++tile) {
            #pragma unroll
            for (int q = 0; q < 4; ++q) {
                int gcol = (h * 4 + q) * 16 + l15;
                #pragma unroll
                for (int i = 0; i < 4; ++i) {
                    eout[(size_t)prow[tile][i] * HD + gcol] = acc[tile][q][i];
                }
            }
        }
    }
}

// ---------------------------------------------------------------------------
extern "C" void kernel_launch(void* const* d_in, const int* in_sizes, int n_in,
                              void* d_out, int out_size, void* d_ws, size_t ws_size,
                              hipStream_t stream)
{
    const float* feat     = (const float*)d_in[0];
    const int*   eidx     = (const int*)d_in[1];
    const float* noise    = (const float*)d_in[2];
    const float* time_emb = (const float*)d_in[3];
    const int*   batch    = (const int*)d_in[4];
    const float* We = (const float*)d_in[5],  *be = (const float*)d_in[6];
    const float* Wp = (const float*)d_in[7],  *bp = (const float*)d_in[8];
    const float* Wq = (const float*)d_in[9],  *bq = (const float*)d_in[10];
    const float* Wr = (const float*)d_in[11], *br = (const float*)d_in[12];
    const float* Wu = (const float*)d_in[13], *bu = (const float*)d_in[14];
    const float* Wv = (const float*)d_in[15], *bv = (const float*)d_in[16];
    const float* gnh_w = (const float*)d_in[17], *gnh_b = (const float*)d_in[18], *gnh_ms = (const float*)d_in[19];
    const float* gne_w = (const float*)d_in[20], *gne_b = (const float*)d_in[21], *gne_ms = (const float*)d_in[22];
    const float* Wt = (const float*)d_in[23], *bt = (const float*)d_in[24];
    const float* ln_w = (const float*)d_in[25], *ln_b = (const float*)d_in[26];
    const float* Wo = (const float*)d_in[27], *bo = (const float*)d_in[28];

    const int* srcArr = eidx;
    const int* dstArr = eidx + NE;

    float* hout = (float*)d_out;                    // [N,H] f32 — holds fu32, then x, then h
    float* eout = hout + (size_t)NN * HD;           // [E,H] f32 — final e

    char* ws = (char*)d_ws;
    size_t off = 0;
    auto take = [&](size_t bytes) -> char* {
        char* p = ws + off;
        off = (off + bytes + 255) & ~(size_t)255;
        return p;
    };
    u16* ehat = (u16*)take((size_t)NE * HD * 2);    // 102.4 MB (CSR order)
    u16* fq = (u16*)take((size_t)NN * HD * 2);      // 12.8 MB
    u16* fr = (u16*)take((size_t)NN * HD * 2);
    u16* fv = (u16*)take((size_t)NN * HD * 2);
    u8*  g8csr = (u8*)take((size_t)NE);
    u32* deg  = (u32*)take((size_t)2 * NN * 4);     // deg[NN] + cnt2[NN], one memset
    u32* cnt2 = deg + NN;
    int* start = (int*)take((size_t)(NN + 1) * 4);
    int* perm  = (int*)take((size_t)NE * 4);
    int* src_csr = (int*)take((size_t)NE * 4);      // 1.6 MB
    int* dst_csr = (int*)take((size_t)NE * 4);      // 1.6 MB
    float* Wep = (float*)take((size_t)ND * HD * 4);
    float* bep = (float*)take((size_t)HD * 4);
    u16* WqT = (u16*)take((size_t)HD * HD * 2);     // transposed bf16 weights
    u16* WrT = (u16*)take((size_t)HD * HD * 2);
    u16* WvT = (u16*)take((size_t)HD * HD * 2);
    u16* WuT = (u16*)take((size_t)HD * HD * 2);
    u16* WoT = (u16*)take((size_t)HD * HD * 2);
    u16* WepT = (u16*)take((size_t)HD * ND * 2);
    u16* WeT  = (u16*)take((size_t)HD * ND * 2);
    float* statsH = (float*)take((size_t)PSTRIDE * 4);
    float* statsE = (float*)take((size_t)PSTRIDE * 4);
    float* tproj  = (float*)take((size_t)GG * HD * 4);
    float* SBh    = (float*)take((size_t)GG * HD * 8);   // {S,B} interleaved
    float* SBe    = (float*)take((size_t)GG * HD * 8);
    float* LNWB   = (float*)take((size_t)64 * 4 * 4);    // {lw,lb} pairs
    float* bsum   = (float*)take((size_t)HD * 4);        // be+bo
    float* epart  = (float*)take((size_t)EP * PSTRIDE * 4);   // 8.9 MB
    float* hpart  = (float*)take((size_t)HP * PSTRIDE * 4);   // 4.5 MB
    float* etmp   = (float*)take((size_t)8 * PSTRIDE * 4);
    float* htmp   = (float*)take((size_t)8 * PSTRIDE * 4);
    // total ~160.6 MB — under the ~167.7 MB budget (R3 pass / R4 fail bound)

    hipMemsetAsync(deg, 0, (size_t)2 * NN * 4, stream);

    wep_kernel<<<16, 256, 0, stream>>>(We, Wp, be, bp, Wep, bep);
    prep_all_kernel<<<dim3(64, 7), 256, 0, stream>>>(Wq, Wr, Wv, Wu, Wo, Wep, We,
                                                     WqT, WrT, WvT, WuT, WoT, WepT, WeT);
    hist_kernel<<<(NE + 255) / 256, 256, 0, stream>>>(srcArr, deg);
    scan_kernel<<<1, 1024, 0, stream>>>(deg, start);
    scatter_kernel<<<(NE + 255) / 256, 256, 0, stream>>>(srcArr, dstArr, batch, start,
                                                         cnt2, perm, src_csr, dst_csr, g8csr);
    proj4_kernel<<<(NN + ETILE - 1) / ETILE, 256, 0, stream>>>(
        feat, WqT, WrT, WvT, WuT, bq, br, bv, bu, fq, fr, fv, hout);
    ehat_kernel<<<NE / ETILE, 256, 0, stream>>>(noise, WepT, bep, fq, fr,
                                                perm, src_csr, dst_csr, ehat);
    aggr_kernel<<<2048, 256, 0, stream>>>(ehat, fv, dst_csr, start, hout);
    hstats_part_kernel<<<HP, 256, 0, stream>>>(hout, batch, hpart);
    estats_part_kernel<<<EP, 512, 0, stream>>>(ehat, g8csr, epart);
    {
        dim3 gA((SLEN + 255) / 256, 8);
        reduce_part_kernel<<<gA, 256, 0, stream>>>(hpart, HP, HP / 8, htmp);
        reduce_part_kernel<<<gA, 256, 0, stream>>>(epart, EP, EP / 8, etmp);
        dim3 gB((SLEN + 255) / 256, 1);
        reduce_part_kernel<<<gB, 256, 0, stream>>>(htmp, 8, 8, statsH);
        reduce_part_kernel<<<gB, 256, 0, stream>>>(etmp, 8, 8, statsE);
    }
    tproj_kernel<<<1, 256, 0, stream>>>(time_emb, Wt, bt, tproj);
    finstats_kernel<<<1, 256, 0, stream>>>(statsH, statsE, gnh_ms, gne_ms,
                                           gnh_w, gnh_b, gne_w, gne_b,
                                           ln_w, ln_b, be, bo,
                                           SBh, SBe, LNWB, bsum);
    hfinal_kernel<<<(NN * HD / 4 + 255) / 256, 256, 0, stream>>>(feat, batch, SBh, hout);
    efinal_kernel<<<NE / ETILE2, 256, 0, stream>>>(ehat, g8csr, noise, perm, WoT, WeT,
                                                   bsum, SBe, tproj, LNWB, eout);
}